// Round 4
// baseline (2342.721 us; speedup 1.0000x reference)
//
#include <hip/hip_runtime.h>
#include <math.h>

#define B     64
#define NCAP  64
#define LV    197
#define LT    32
#define C     512
#define NSP   196
#define NKEEP 98
#define HID   102
#define KEEPED 49

// Workspace layout (float element offsets). Total used: 26,297,152 floats = 105.2 MB
// (previous rounds proved ws_size >= 26,698,560 floats).
#define OFF_INV     0                         // B*LV            = 12608
#define OFF_ATTNX   12608                     // B*NSP           = 12544
#define OFF_WSMAT   25152                     // B*NSP*KEEPED    = 614656
#define OFF_CAPN    639808                    // NCAP*LT*C       = 1048576  (capn/qi2t/qt2i MUST stay contiguous)
#define OFF_QI2T    1688384                   // NCAP*LT*C
#define OFF_QT2I    2736960                   // NCAP*LT*C
#define OFF_GLOT    3785536                   // C*NCAP          = 32768
#define OFF_ATTNY   3818304                   // B*NSP*NCAP      = 802816
#define OFF_RW      4621120                   // 4096*196 floats = 802816 (kept -> -1, else weight)
#define OFF_GP      5423936                   // 4096*98*52      = 20873216 (P rows in kept-s-order, stride 52)

__device__ __forceinline__ float gelu_exact(float x) {
    return 0.5f * x * (1.f + erff(x * 0.70710678118654752f));
}

// ---------------------------------------------------------------- img row norms
__global__ __launch_bounds__(64) void k_img_norm(const float* __restrict__ img,
                                                 float* __restrict__ inv_img) {
    int r = blockIdx.x, t = threadIdx.x;
    const float* row = img + (size_t)r * C;
    float ss = 0.f;
    for (int c = t; c < C; c += 64) { float v = row[c]; ss += v * v; }
    for (int o = 32; o > 0; o >>= 1) ss += __shfl_down(ss, o);
    if (t == 0) inv_img[r] = 1.f / fmaxf(sqrtf(ss), 1e-12f);
}

// ---------------------------------------------------------------- caption norms
__global__ __launch_bounds__(64) void k_cap_norm(const float* __restrict__ cap,
                                                 float* __restrict__ capn,
                                                 float* __restrict__ gloT) {
    int i = blockIdx.x, tt = blockIdx.y, t = threadIdx.x;
    const float* row = cap + ((size_t)i * LT + tt) * C;
    float v[8]; float ss = 0.f;
#pragma unroll
    for (int q = 0; q < 8; ++q) { v[q] = row[t + 64 * q]; ss += v[q] * v[q]; }
    for (int o = 32; o > 0; o >>= 1) ss += __shfl_down(ss, o);
    ss = __shfl(ss, 0);
    float inv = 1.f / fmaxf(sqrtf(ss), 1e-12f);
    float* orow = capn + ((size_t)i * LT + tt) * C;
#pragma unroll
    for (int q = 0; q < 8; ++q) {
        float n = v[q] * inv;
        orow[t + 64 * q] = n;
        if (tt == 0) gloT[(t + 64 * q) * NCAP + i] = n;
    }
}

// ---------------------------------------------------------------- qi2t / qt2i projections
__global__ __launch_bounds__(256) void k_qproj(const float* __restrict__ capn,
                                               const float* __restrict__ wi2t,
                                               const float* __restrict__ bi2t,
                                               const float* __restrict__ wt2i,
                                               const float* __restrict__ bt2i,
                                               float* __restrict__ qi2t,
                                               float* __restrict__ qt2i) {
    int i = blockIdx.x, tg = blockIdx.y, t = threadIdx.x;
    __shared__ __align__(16) float xr[8][C];
    const float* base = capn + ((size_t)i * LT + tg * 8) * C;
    for (int f = t; f < 8 * C; f += 256) xr[f >> 9][f & 511] = base[f];
    __syncthreads();
    int j0 = t, j1 = t + 256;
    for (int mtx = 0; mtx < 2; ++mtx) {
        const float* W  = mtx ? wt2i : wi2t;
        const float* bb = mtx ? bt2i : bi2t;
        float* Q        = mtx ? qt2i : qi2t;
        float a0[8], a1[8];
        float bj0 = bb[j0], bj1 = bb[j1];
#pragma unroll
        for (int r = 0; r < 8; ++r) { a0[r] = bj0; a1[r] = bj1; }
        for (int c = 0; c < C; ++c) {
            float w0 = W[c * C + j0], w1v = W[c * C + j1];
#pragma unroll
            for (int r = 0; r < 8; ++r) {
                a0[r] += xr[r][c] * w0;
                a1[r] += xr[r][c] * w1v;
            }
        }
#pragma unroll
        for (int r = 0; r < 8; ++r) {
            Q[((size_t)i * LT + tg * 8 + r) * C + j0] = a0[r];
            Q[((size_t)i * LT + tg * 8 + r) * C + j1] = a1[r];
        }
    }
}

// ---------------------------------------------------------------- LN -> w1 -> gelu -> w2 + attn_x
__global__ __launch_bounds__(256) void k_img_row(const float* __restrict__ img,
                                                 const float* __restrict__ inv_img,
                                                 const float* __restrict__ gamw,
                                                 const float* __restrict__ betw,
                                                 const float* __restrict__ w1,
                                                 const float* __restrict__ b1,
                                                 const float* __restrict__ w2,
                                                 const float* __restrict__ b2,
                                                 const float* __restrict__ scale_p,
                                                 float* __restrict__ attn_x,
                                                 float* __restrict__ WsM) {
    int b = blockIdx.x, s0 = blockIdx.y * 8, t = threadIdx.x;
    int R = NSP - s0; if (R > 8) R = 8;
    __shared__ __align__(16) float lnr[8][C];
    __shared__ float HH[8][HID + 2];
    __shared__ float redm[8][3];

    int g = t >> 5, lane = t & 31;
    if (g < R) {
        const float* row = img + ((size_t)b * LV + 1 + s0 + g) * C;
        const float* cls = img + (size_t)b * LV * C;
        float sm = 0.f, ss = 0.f, dd = 0.f;
        for (int c = lane; c < C; c += 32) {
            float v = row[c];
            sm += v; ss += v * v; dd += v * cls[c];
            lnr[g][c] = v;
        }
        for (int o = 16; o > 0; o >>= 1) {
            sm += __shfl_down(sm, o, 32);
            ss += __shfl_down(ss, o, 32);
            dd += __shfl_down(dd, o, 32);
        }
        if (lane == 0) { redm[g][0] = sm; redm[g][1] = ss; redm[g][2] = dd; }
    }
    __syncthreads();
    for (int f = t; f < R * C; f += 256) {
        int rr = f >> 9, c = f & 511;
        float mean = redm[rr][0] * (1.f / C);
        float var  = redm[rr][1] * (1.f / C) - mean * mean;
        float rstd = 1.f / sqrtf(var + 1e-5f);
        lnr[rr][c] = (lnr[rr][c] - mean) * rstd * gamw[c] + betw[c];
    }
    if (t < R) {
        float inv0 = inv_img[b * LV];
        float invs = inv_img[b * LV + 1 + s0 + t];
        attn_x[b * NSP + s0 + t] = redm[t][2] * inv0 * invs;
    }
    __syncthreads();
    if (t < HID) {
        float acc[8];
#pragma unroll
        for (int r = 0; r < 8; ++r) acc[r] = b1[t];
        for (int c = 0; c < C; ++c) {
            float w = w1[c * HID + t];
#pragma unroll
            for (int r = 0; r < 8; ++r) acc[r] += lnr[r][c] * w;
        }
#pragma unroll
        for (int r = 0; r < 8; ++r) HH[r][t] = gelu_exact(acc[r]);
    }
    __syncthreads();
    float scale = scale_p[0];
    if (t < 196) {
        int k = t % 49, rh = t / 49;
        for (int rr = rh; rr < 8; rr += 4) {
            if (rr < R) {
                float a = b2[k];
                for (int h = 0; h < HID; ++h) a += HH[rr][h] * w2[h * 49 + k];
                WsM[((size_t)b * NSP + s0 + rr) * 49 + k] = a * scale;
            }
        }
    }
}

// ---------------------------------------------------------------- attn_y
__global__ __launch_bounds__(64) void k_attn_y(const float* __restrict__ img,
                                               const float* __restrict__ inv_img,
                                               const float* __restrict__ gloT,
                                               float* __restrict__ attn_y) {
    int b = blockIdx.x, s0 = blockIdx.y * 8, t = threadIdx.x;
    int R = NSP - s0; if (R > 8) R = 8;
    __shared__ __align__(16) float xr[8][C];
    for (int rr = 0; rr < R; ++rr) {
        float inv = inv_img[b * LV + 1 + s0 + rr];
        const float* row = img + ((size_t)b * LV + 1 + s0 + rr) * C;
        for (int c = t; c < C; c += 64) xr[rr][c] = row[c] * inv;
    }
    __syncthreads();
    float acc[8] = {0, 0, 0, 0, 0, 0, 0, 0};
    for (int c4 = 0; c4 < C / 4; ++c4) {
        float g0 = gloT[(c4 * 4 + 0) * NCAP + t];
        float g1 = gloT[(c4 * 4 + 1) * NCAP + t];
        float g2 = gloT[(c4 * 4 + 2) * NCAP + t];
        float g3 = gloT[(c4 * 4 + 3) * NCAP + t];
#pragma unroll
        for (int r = 0; r < 8; ++r) {
            float4 xv = ((const float4*)xr[r])[c4];
            acc[r] += xv.x * g0 + xv.y * g1 + xv.z * g2 + xv.w * g3;
        }
    }
    for (int rr = 0; rr < R; ++rr)
        attn_y[((size_t)b * NSP + s0 + rr) * NCAP + t] = acc[rr];
}

// ---------------------------------------------------------------- per-pair prep
// Outputs: gRW[pair][s] = kept ? -1 : exp(score-m)  ;  gP rows in kept-s-order, stride 52.
__global__ __launch_bounds__(256) void k_prep(const float* __restrict__ attn_x,
                                              const float* __restrict__ attn_y,
                                              const float* __restrict__ WsM,
                                              float* __restrict__ gRW,
                                              float* __restrict__ gP) {
    int i = blockIdx.x, b = blockIdx.y, t = threadIdx.x;
    int pair = b * NCAP + i;
    int wu = t >> 6, lane = t & 63;
    __shared__ float scoreS[NSP];
    __shared__ int   keepL[NKEEP];     // kept tokens in s-order
    __shared__ float mk[KEEPED];
    __shared__ int   wcnt[4];
    __shared__ int   wbase[4];
    __shared__ float wmax[4];

    if (t < NSP) scoreS[t] = attn_x[b * NSP + t] + attn_y[(size_t)(b * NSP + t) * NCAP + i];
    __syncthreads();
    float sv = 0.f; int r = 999;
    if (t < NSP) {
        sv = scoreS[t];
        r = 0;
        for (int u = 0; u < NSP; ++u) {
            float o = scoreS[u];
            r += (o > sv) || (o == sv && u < t);
        }
    }
    bool kept = (t < NSP) && (r < NKEEP);
    // kept-order-by-s prefix via ballot
    unsigned long long mask = __ballot(kept);
    int lanep = __popcll(mask & ((1ull << lane) - 1ull));
    if (lane == 0) wcnt[wu] = __popcll(mask);
    // nonkeep max
    float nm = (t < NSP && !kept) ? sv : -1e30f;
    for (int o = 32; o > 0; o >>= 1) nm = fmaxf(nm, __shfl_down(nm, o));
    if (lane == 0) wmax[wu] = nm;
    __syncthreads();
    if (t == 0) {
        int s0 = 0;
#pragma unroll
        for (int w = 0; w < 4; ++w) { wbase[w] = s0; s0 += wcnt[w]; }
    }
    __syncthreads();
    float m = fmaxf(fmaxf(wmax[0], wmax[1]), fmaxf(wmax[2], wmax[3]));
    if (kept) keepL[wbase[wu] + lanep] = t;
    if (t < NSP) gRW[(size_t)pair * NSP + t] = kept ? -1.f : expf(sv - m);
    __syncthreads();
    if (t < KEEPED) {
        float m2 = -1e30f;
        for (int j = 0; j < NKEEP; ++j)
            m2 = fmaxf(m2, WsM[((size_t)b * NSP + keepL[j]) * KEEPED + t]);
        mk[t] = m2;
    }
    __syncthreads();
    float* Pm = gP + (size_t)pair * NKEEP * 52;
    for (int f = t; f < NKEEP * KEEPED; f += 256) {
        int j = f / KEEPED, k = f - j * KEEPED;
        Pm[j * 52 + k] = expf(WsM[((size_t)b * NSP + keepL[j]) * KEEPED + k] - mk[k]);
    }
}

// ---------------------------------------------------------------- main per-pair kernel
// Stream: kg=t>>7 owns 13 k, cx=t&127 owns cols 4cx..4cx+3. P via SMEM (s-ordered rows).
// U: qt=t>>4 owns q=3qt..3qt+2 (Q from global), lp=t&15 owns l=16lc+lp (S from LDS).
__global__ __launch_bounds__(512, 4) void k_main(const float* __restrict__ img,
                                                 const float* __restrict__ inv_img,
                                                 const float* __restrict__ gRW,
                                                 const float* __restrict__ gP,
                                                 const float* __restrict__ qbase,
                                                 const float* __restrict__ temp_p,
                                                 float* __restrict__ out) {
    int i = blockIdx.x, b = blockIdx.y, t = threadIdx.x;
    int pair = b * NCAP + i;
    int lane = t & 63;
    int wu = t >> 6;
    int kg = t >> 7;
    int cx = t & 127;
    int kb = kg * 13;
    int qt = t >> 4;          // 0..31
    int lp = t & 15;          // 0..15

    __shared__ __align__(16) float Sl[16 * 516];    // 33,024 B : sel_tok l-chunk [lp][c]
    __shared__ __align__(16) float ULDS[96 * 51];   // 19,584 B
    __shared__ __align__(16) float stash[2 * 512];  //  4,096 B : cls row, extra row (normalized)
    __shared__ float wpartA[8][16];
    __shared__ float wpartE[2];
    __shared__ float invA[KEEPED];
    __shared__ float scl[1];
    __shared__ float colM[51], colZ[51], rowM[32], rowZ[32];
    __shared__ float redw[8];

    const float* rwp  = gRW + (size_t)pair * NSP;
    const float* Pg   = gP + (size_t)pair * NKEEP * 52;
    const float* imgb = img + (size_t)b * LV * C;
    const float4* imgb4 = (const float4*)imgb;

    // stash normalized cls row
    {
        float invC = inv_img[b * LV];
        float4 cv = imgb4[cx];
        *(float4*)&stash[4 * cx] = make_float4(cv.x * invC, cv.y * invC, cv.z * invC, cv.w * invC);
    }

    // ---- unified stream over all 196 spatial rows
    float acc[13][4];
#pragma unroll
    for (int r = 0; r < 13; ++r) { acc[r][0] = 0.f; acc[r][1] = 0.f; acc[r][2] = 0.f; acc[r][3] = 0.f; }
    float e4[4] = {0.f, 0.f, 0.f, 0.f};
    {
        const float* pr = Pg;
        float pv[13];
#pragma unroll
        for (int r = 0; r < 13; ++r) pv[r] = pr[kb + r];
        float vcur = rwp[0];
        float4 b0 = imgb4[1 * 128 + cx];
        float4 b1 = imgb4[2 * 128 + cx];
        for (int s = 0; s < NSP; ++s) {
            float4 vc = b0; b0 = b1;
            int nr = (s + 3 <= 196) ? (s + 3) : 196;
            b1 = imgb4[(size_t)nr * 128 + cx];
            float vnext = rwp[s + 1];
            if (vcur < 0.f) {          // kept: P row = running counter (s-order)
                float pn[13];
#pragma unroll
                for (int r = 0; r < 13; ++r) pn[r] = pr[52 + kb + r];
#pragma unroll
                for (int r = 0; r < 13; ++r) {
                    acc[r][0] = fmaf(pv[r], vc.x, acc[r][0]);
                    acc[r][1] = fmaf(pv[r], vc.y, acc[r][1]);
                    acc[r][2] = fmaf(pv[r], vc.z, acc[r][2]);
                    acc[r][3] = fmaf(pv[r], vc.w, acc[r][3]);
                }
#pragma unroll
                for (int r = 0; r < 13; ++r) pv[r] = pn[r];
                pr += 52;
            } else {                   // nonkept: extra accumulation
                e4[0] = fmaf(vcur, vc.x, e4[0]);
                e4[1] = fmaf(vcur, vc.y, e4[1]);
                e4[2] = fmaf(vcur, vc.z, e4[2]);
                e4[3] = fmaf(vcur, vc.w, e4[3]);
            }
            vcur = vnext;
        }
    }

    // ---- norms
#pragma unroll
    for (int r = 0; r < 13; ++r) {
        float v = acc[r][0] * acc[r][0] + acc[r][1] * acc[r][1]
                + acc[r][2] * acc[r][2] + acc[r][3] * acc[r][3];
        for (int o = 32; o > 0; o >>= 1) v += __shfl_down(v, o);
        if (lane == 0) wpartA[wu][r] = v;
    }
    if (kg == 0) {                 // e4 duplicated across kg; count once
        float v = e4[0] * e4[0] + e4[1] * e4[1] + e4[2] * e4[2] + e4[3] * e4[3];
        for (int o = 32; o > 0; o >>= 1) v += __shfl_down(v, o);
        if (lane == 0) wpartE[wu] = v;
    }
    __syncthreads();
    if (t < KEEPED) {
        int g = t / 13, r = t - g * 13;
        float s = wpartA[2 * g][r] + wpartA[2 * g + 1][r];
        invA[t] = 1.f / fmaxf(sqrtf(s), 1e-12f);
    }
    if (t == KEEPED) scl[0] = 1.f / fmaxf(sqrtf(wpartE[0] + wpartE[1]), 1e-12f);
    __syncthreads();
    {
        float invE = scl[0];
#pragma unroll
        for (int r = 0; r < 13; ++r) {
            int k = kb + r;
            if (k < KEEPED) {
                float ia = invA[k];
                acc[r][0] *= ia; acc[r][1] *= ia; acc[r][2] *= ia; acc[r][3] *= ia;
            }
        }
        if (kg == 0)
            *(float4*)&stash[512 + 4 * cx] =
                make_float4(e4[0] * invE, e4[1] * invE, e4[2] * invE, e4[3] * invE);
    }

    // ---- Q row pointers (global, read per chunk; rows 0-31 capn, 32-63 qi2t, 64-95 qt2i)
    const float* Qb0; const float* Qb1; const float* Qb2;
    {
        int q0 = 3 * qt, q1 = q0 + 1, q2 = q0 + 2;
        int R0 = (q0 < 32) ? i * LT + q0 : (q0 < 64) ? 2048 + i * LT + q0 - 32 : 4096 + i * LT + q0 - 64;
        int R1 = (q1 < 32) ? i * LT + q1 : (q1 < 64) ? 2048 + i * LT + q1 - 32 : 4096 + i * LT + q1 - 64;
        int R2 = (q2 < 32) ? i * LT + q2 : (q2 < 64) ? 2048 + i * LT + q2 - 32 : 4096 + i * LT + q2 - 64;
        Qb0 = qbase + (size_t)R0 * C;
        Qb1 = qbase + (size_t)R1 * C;
        Qb2 = qbase + (size_t)R2 * C;
    }

    // ---- U in 4 l-chunks of 16
    for (int lc = 0; lc < 4; ++lc) {
        __syncthreads();   // previous chunk's compute done before rebuild
        // build Sl rows for l in [16lc, 16lc+16)
        if (kg == 0 && lc == 0)
            *(float4*)&Sl[0 * 516 + 4 * cx] = *(const float4*)&stash[4 * cx];
        if (kg == 0 && lc == 3)
            *(float4*)&Sl[2 * 516 + 4 * cx] = *(const float4*)&stash[512 + 4 * cx];
#pragma unroll
        for (int r = 0; r < 13; ++r) {
            int k = kb + r;
            int lo = k + 1 - 16 * lc;
            if (k < KEEPED && lo >= 0 && lo < 16)
                *(float4*)&Sl[lo * 516 + 4 * cx] =
                    make_float4(acc[r][0], acc[r][1], acc[r][2], acc[r][3]);
        }
        __syncthreads();
        float u0 = 0.f, u1 = 0.f, u2 = 0.f;
        const float* Srow = &Sl[lp * 516];
#pragma unroll 8
        for (int c = 0; c < C; c += 4) {
            float4 sv = *(const float4*)&Srow[c];
            float4 a0 = *(const float4*)&Qb0[c];
            float4 a1 = *(const float4*)&Qb1[c];
            float4 a2 = *(const float4*)&Qb2[c];
            u0 = fmaf(a0.x, sv.x, u0); u0 = fmaf(a0.y, sv.y, u0);
            u0 = fmaf(a0.z, sv.z, u0); u0 = fmaf(a0.w, sv.w, u0);
            u1 = fmaf(a1.x, sv.x, u1); u1 = fmaf(a1.y, sv.y, u1);
            u1 = fmaf(a1.z, sv.z, u1); u1 = fmaf(a1.w, sv.w, u1);
            u2 = fmaf(a2.x, sv.x, u2); u2 = fmaf(a2.y, sv.y, u2);
            u2 = fmaf(a2.z, sv.z, u2); u2 = fmaf(a2.w, sv.w, u2);
        }
        int l = 16 * lc + lp;
        if (l < 51) {
            ULDS[(3 * qt + 0) * 51 + l] = u0;
            ULDS[(3 * qt + 1) * 51 + l] = u1;
            ULDS[(3 * qt + 2) * 51 + l] = u2;
        }
    }
    __syncthreads();

    // ---- softmax stats
    float invT = 1.f / temp_p[0];
    if (t < 51) {
        float mm = -1e30f;
        for (int u = 0; u < LT; ++u) mm = fmaxf(mm, ULDS[(32 + u) * 51 + t] * invT);
        float z = 0.f;
        for (int u = 0; u < LT; ++u) z += expf(ULDS[(32 + u) * 51 + t] * invT - mm);
        colM[t] = mm; colZ[t] = 1.f / z;
    }
    if (t >= 64 && t < 96) {
        int u = t - 64;
        float mm = -1e30f;
        for (int l = 0; l < 51; ++l) mm = fmaxf(mm, ULDS[(64 + u) * 51 + l] * invT);
        float z = 0.f;
        for (int l = 0; l < 51; ++l) z += expf(ULDS[(64 + u) * 51 + l] * invT - mm);
        rowM[u] = mm; rowZ[u] = 1.f / z;
    }
    __syncthreads();

    // ---- final reduction
    float part = 0.f;
    for (int f = t; f < LT * 51; f += 512) {
        int u = f / 51, l = f - u * 51;
        float u0 = ULDS[u * 51 + l];
        float c2 = (u0 > 0.f) ? u0 : 0.1f * u0;
        float av = expf(ULDS[(32 + u) * 51 + l] * invT - colM[l]) * colZ[l];
        float bv = expf(ULDS[(64 + u) * 51 + l] * invT - rowM[u]) * rowZ[u];
        part += c2 * (av * (1.f / 51.f) + bv * (1.f / 32.f));
    }
    for (int o = 32; o > 0; o >>= 1) part += __shfl_down(part, o);
    if (lane == 0) redw[wu] = part;
    __syncthreads();
    if (t == 0) {
        float s = 0.f;
#pragma unroll
        for (int w2 = 0; w2 < 8; ++w2) s += redw[w2];
        out[b * NCAP + i] = s;
    }
}

extern "C" void kernel_launch(void* const* d_in, const int* in_sizes, int n_in,
                              void* d_out, int out_size, void* d_ws, size_t ws_size,
                              hipStream_t stream) {
    const float* img        = (const float*)d_in[0];
    const float* cap        = (const float*)d_in[1];
    const float* gamw       = (const float*)d_in[3];
    const float* betw       = (const float*)d_in[4];
    const float* w1         = (const float*)d_in[5];
    const float* b1         = (const float*)d_in[6];
    const float* w2         = (const float*)d_in[7];
    const float* b2         = (const float*)d_in[8];
    const float* aggr_scale = (const float*)d_in[9];
    const float* wi2t       = (const float*)d_in[10];
    const float* bi2t       = (const float*)d_in[11];
    const float* wt2i       = (const float*)d_in[12];
    const float* bt2i       = (const float*)d_in[13];
    const float* temp       = (const float*)d_in[14];
    float* out = (float*)d_out;

    float* ws      = (float*)d_ws;
    float* inv_img = ws + OFF_INV;
    float* attn_x  = ws + OFF_ATTNX;
    float* WsM     = ws + OFF_WSMAT;
    float* capn    = ws + OFF_CAPN;
    float* qi2t    = ws + OFF_QI2T;
    float* qt2i    = ws + OFF_QT2I;
    float* gloT    = ws + OFF_GLOT;
    float* attn_y  = ws + OFF_ATTNY;
    float* gRW     = ws + OFF_RW;
    float* gP      = ws + OFF_GP;

    k_img_norm<<<dim3(B * LV), dim3(64), 0, stream>>>(img, inv_img);
    k_cap_norm<<<dim3(NCAP, LT), dim3(64), 0, stream>>>(cap, capn, gloT);
    k_qproj<<<dim3(NCAP, 4), dim3(256), 0, stream>>>(capn, wi2t, bi2t, wt2i, bt2i, qi2t, qt2i);
    k_img_row<<<dim3(B, 25), dim3(256), 0, stream>>>(img, inv_img, gamw, betw, w1, b1, w2, b2,
                                                     aggr_scale, attn_x, WsM);
    k_attn_y<<<dim3(B, 25), dim3(64), 0, stream>>>(img, inv_img, gloT, attn_y);
    k_prep<<<dim3(NCAP, B), dim3(256), 0, stream>>>(attn_x, attn_y, WsM, gRW, gP);
    k_main<<<dim3(NCAP, B), dim3(512), 0, stream>>>(img, inv_img, gRW, gP, capn, temp, out);
}

// Round 5
// 1557.077 us; speedup vs baseline: 1.5046x; 1.5046x over previous
//
#include <hip/hip_runtime.h>
#include <math.h>

#define B     64
#define NCAP  64
#define LV    197
#define LT    32
#define C     512
#define NSP   196
#define NKEEP 98
#define HID   102
#define KEEPED 49

// Workspace layout (float element offsets). Total 26,698,560 floats = 106.8 MB (proven OK in R1-3).
#define OFF_INV     0                         // B*LV
#define OFF_ATTNX   12608                     // B*NSP
#define OFF_WSMAT   25152                     // B*NSP*KEEPED
#define OFF_CAPN    639808                    // NCAP*LT*C  (capn/qi2t/qt2i contiguous)
#define OFF_QI2T    1688384
#define OFF_QT2I    2736960
#define OFF_GLOT    3785536                   // C*NCAP
#define OFF_ATTNY   3818304                   // B*NSP*NCAP
#define OFF_KEEP    4621120                   // 4096*98 ints
#define OFF_NON     5022528                   // 4096*98 ints
#define OFF_PNK     5423936                   // 4096*98 floats
#define OFF_GP      5825344                   // 4096*98*52 floats

__device__ __forceinline__ float gelu_exact(float x) {
    return 0.5f * x * (1.f + erff(x * 0.70710678118654752f));
}

// ---------------------------------------------------------------- img row norms
__global__ __launch_bounds__(64) void k_img_norm(const float* __restrict__ img,
                                                 float* __restrict__ inv_img) {
    int r = blockIdx.x, t = threadIdx.x;
    const float* row = img + (size_t)r * C;
    float ss = 0.f;
    for (int c = t; c < C; c += 64) { float v = row[c]; ss += v * v; }
    for (int o = 32; o > 0; o >>= 1) ss += __shfl_down(ss, o);
    if (t == 0) inv_img[r] = 1.f / fmaxf(sqrtf(ss), 1e-12f);
}

// ---------------------------------------------------------------- caption norms
__global__ __launch_bounds__(64) void k_cap_norm(const float* __restrict__ cap,
                                                 float* __restrict__ capn,
                                                 float* __restrict__ gloT) {
    int i = blockIdx.x, tt = blockIdx.y, t = threadIdx.x;
    const float* row = cap + ((size_t)i * LT + tt) * C;
    float v[8]; float ss = 0.f;
#pragma unroll
    for (int q = 0; q < 8; ++q) { v[q] = row[t + 64 * q]; ss += v[q] * v[q]; }
    for (int o = 32; o > 0; o >>= 1) ss += __shfl_down(ss, o);
    ss = __shfl(ss, 0);
    float inv = 1.f / fmaxf(sqrtf(ss), 1e-12f);
    float* orow = capn + ((size_t)i * LT + tt) * C;
#pragma unroll
    for (int q = 0; q < 8; ++q) {
        float n = v[q] * inv;
        orow[t + 64 * q] = n;
        if (tt == 0) gloT[(t + 64 * q) * NCAP + i] = n;
    }
}

// ---------------------------------------------------------------- qi2t / qt2i projections
__global__ __launch_bounds__(256) void k_qproj(const float* __restrict__ capn,
                                               const float* __restrict__ wi2t,
                                               const float* __restrict__ bi2t,
                                               const float* __restrict__ wt2i,
                                               const float* __restrict__ bt2i,
                                               float* __restrict__ qi2t,
                                               float* __restrict__ qt2i) {
    int i = blockIdx.x, tg = blockIdx.y, t = threadIdx.x;
    __shared__ __align__(16) float xr[8][C];
    const float* base = capn + ((size_t)i * LT + tg * 8) * C;
    for (int f = t; f < 8 * C; f += 256) xr[f >> 9][f & 511] = base[f];
    __syncthreads();
    int j0 = t, j1 = t + 256;
    for (int mtx = 0; mtx < 2; ++mtx) {
        const float* W  = mtx ? wt2i : wi2t;
        const float* bb = mtx ? bt2i : bi2t;
        float* Q        = mtx ? qt2i : qi2t;
        float a0[8], a1[8];
        float bj0 = bb[j0], bj1 = bb[j1];
#pragma unroll
        for (int r = 0; r < 8; ++r) { a0[r] = bj0; a1[r] = bj1; }
        for (int c = 0; c < C; ++c) {
            float w0 = W[c * C + j0], w1v = W[c * C + j1];
#pragma unroll
            for (int r = 0; r < 8; ++r) {
                a0[r] += xr[r][c] * w0;
                a1[r] += xr[r][c] * w1v;
            }
        }
#pragma unroll
        for (int r = 0; r < 8; ++r) {
            Q[((size_t)i * LT + tg * 8 + r) * C + j0] = a0[r];
            Q[((size_t)i * LT + tg * 8 + r) * C + j1] = a1[r];
        }
    }
}

// ---------------------------------------------------------------- LN -> w1 -> gelu -> w2 + attn_x
__global__ __launch_bounds__(256) void k_img_row(const float* __restrict__ img,
                                                 const float* __restrict__ inv_img,
                                                 const float* __restrict__ gamw,
                                                 const float* __restrict__ betw,
                                                 const float* __restrict__ w1,
                                                 const float* __restrict__ b1,
                                                 const float* __restrict__ w2,
                                                 const float* __restrict__ b2,
                                                 const float* __restrict__ scale_p,
                                                 float* __restrict__ attn_x,
                                                 float* __restrict__ WsM) {
    int b = blockIdx.x, s0 = blockIdx.y * 8, t = threadIdx.x;
    int R = NSP - s0; if (R > 8) R = 8;
    __shared__ __align__(16) float lnr[8][C];
    __shared__ float HH[8][HID + 2];
    __shared__ float redm[8][3];

    int g = t >> 5, lane = t & 31;
    if (g < R) {
        const float* row = img + ((size_t)b * LV + 1 + s0 + g) * C;
        const float* cls = img + (size_t)b * LV * C;
        float sm = 0.f, ss = 0.f, dd = 0.f;
        for (int c = lane; c < C; c += 32) {
            float v = row[c];
            sm += v; ss += v * v; dd += v * cls[c];
            lnr[g][c] = v;
        }
        for (int o = 16; o > 0; o >>= 1) {
            sm += __shfl_down(sm, o, 32);
            ss += __shfl_down(ss, o, 32);
            dd += __shfl_down(dd, o, 32);
        }
        if (lane == 0) { redm[g][0] = sm; redm[g][1] = ss; redm[g][2] = dd; }
    }
    __syncthreads();
    for (int f = t; f < R * C; f += 256) {
        int rr = f >> 9, c = f & 511;
        float mean = redm[rr][0] * (1.f / C);
        float var  = redm[rr][1] * (1.f / C) - mean * mean;
        float rstd = 1.f / sqrtf(var + 1e-5f);
        lnr[rr][c] = (lnr[rr][c] - mean) * rstd * gamw[c] + betw[c];
    }
    if (t < R) {
        float inv0 = inv_img[b * LV];
        float invs = inv_img[b * LV + 1 + s0 + t];
        attn_x[b * NSP + s0 + t] = redm[t][2] * inv0 * invs;
    }
    __syncthreads();
    if (t < HID) {
        float acc[8];
#pragma unroll
        for (int r = 0; r < 8; ++r) acc[r] = b1[t];
        for (int c = 0; c < C; ++c) {
            float w = w1[c * HID + t];
#pragma unroll
            for (int r = 0; r < 8; ++r) acc[r] += lnr[r][c] * w;
        }
#pragma unroll
        for (int r = 0; r < 8; ++r) HH[r][t] = gelu_exact(acc[r]);
    }
    __syncthreads();
    float scale = scale_p[0];
    if (t < 196) {
        int k = t % 49, rh = t / 49;
        for (int rr = rh; rr < 8; rr += 4) {
            if (rr < R) {
                float a = b2[k];
                for (int h = 0; h < HID; ++h) a += HH[rr][h] * w2[h * 49 + k];
                WsM[((size_t)b * NSP + s0 + rr) * 49 + k] = a * scale;
            }
        }
    }
}

// ---------------------------------------------------------------- attn_y
__global__ __launch_bounds__(64) void k_attn_y(const float* __restrict__ img,
                                               const float* __restrict__ inv_img,
                                               const float* __restrict__ gloT,
                                               float* __restrict__ attn_y) {
    int b = blockIdx.x, s0 = blockIdx.y * 8, t = threadIdx.x;
    int R = NSP - s0; if (R > 8) R = 8;
    __shared__ __align__(16) float xr[8][C];
    for (int rr = 0; rr < R; ++rr) {
        float inv = inv_img[b * LV + 1 + s0 + rr];
        const float* row = img + ((size_t)b * LV + 1 + s0 + rr) * C;
        for (int c = t; c < C; c += 64) xr[rr][c] = row[c] * inv;
    }
    __syncthreads();
    float acc[8] = {0, 0, 0, 0, 0, 0, 0, 0};
    for (int c4 = 0; c4 < C / 4; ++c4) {
        float g0 = gloT[(c4 * 4 + 0) * NCAP + t];
        float g1 = gloT[(c4 * 4 + 1) * NCAP + t];
        float g2 = gloT[(c4 * 4 + 2) * NCAP + t];
        float g3 = gloT[(c4 * 4 + 3) * NCAP + t];
#pragma unroll
        for (int r = 0; r < 8; ++r) {
            float4 xv = ((const float4*)xr[r])[c4];
            acc[r] += xv.x * g0 + xv.y * g1 + xv.z * g2 + xv.w * g3;
        }
    }
    for (int rr = 0; rr < R; ++rr)
        attn_y[((size_t)b * NSP + s0 + rr) * NCAP + t] = acc[rr];
}

// ---------------------------------------------------------------- per-pair prep (round-3 version)
__global__ __launch_bounds__(256) void k_prep(const float* __restrict__ attn_x,
                                              const float* __restrict__ attn_y,
                                              const float* __restrict__ WsM,
                                              int* __restrict__ gKeep,
                                              int* __restrict__ gNon,
                                              float* __restrict__ gPnk,
                                              float* __restrict__ gP) {
    int i = blockIdx.x, b = blockIdx.y, t = threadIdx.x;
    int pair = b * NCAP + i;
    __shared__ float scoreS[NSP];
    __shared__ int   keepL[NKEEP];
    __shared__ int   nonL[NKEEP];
    __shared__ float snon[NKEEP];
    __shared__ float mk[KEEPED];
    __shared__ float bcast[1];

    if (t < NSP) scoreS[t] = attn_x[b * NSP + t] + attn_y[(size_t)(b * NSP + t) * NCAP + i];
    __syncthreads();
    if (t < NSP) {
        float sv = scoreS[t];
        int r = 0;
        for (int u = 0; u < NSP; ++u) {
            float o = scoreS[u];
            r += (o > sv) || (o == sv && u < t);
        }
        if (r < NKEEP) keepL[r] = t;
        else { nonL[r - NKEEP] = t; snon[r - NKEEP] = sv; }
    }
    __syncthreads();
    if (t == 0) {
        float m = -1e30f;
        for (int j = 0; j < NKEEP; ++j) m = fmaxf(m, snon[j]);
        bcast[0] = m;
    }
    __syncthreads();
    if (t < NKEEP) {
        gKeep[pair * NKEEP + t] = keepL[t];
        gNon[pair * NKEEP + t]  = nonL[t];
        gPnk[pair * NKEEP + t]  = expf(snon[t] - bcast[0]);
    }
    if (t < KEEPED) {
        float m2 = -1e30f;
        for (int j = 0; j < NKEEP; ++j)
            m2 = fmaxf(m2, WsM[((size_t)b * NSP + keepL[j]) * KEEPED + t]);
        mk[t] = m2;
    }
    __syncthreads();
    float* Pm = gP + (size_t)pair * NKEEP * 52;
    for (int f = t; f < NKEEP * KEEPED; f += 256) {
        int j = f / KEEPED, k = f - j * KEEPED;
        Pm[j * 52 + k] = expf(WsM[((size_t)b * NSP + keepL[j]) * KEEPED + k] - mk[k]);
    }
    for (int f = t; f < NKEEP * 3; f += 256) {     // zero 3-float pad per row
        int j = f / 3;
        Pm[j * 52 + KEEPED + (f % 3)] = 0.f;
    }
}

// ---------------------------------------------------------------- main per-pair kernel
// Stream: kg=t>>7 owns 13 k, cx=t&127 owns cols 4cx..4cx+3; P via 4x aligned b128 broadcast.
// U: qg=t>>4 owns q 3qg..3qg+2 (Qs LDS, per-chunk staged), lg=t&15 owns l in {lg,lg+16,lg+32,lg+48}.
__global__ __launch_bounds__(512, 2) void k_main(const float* __restrict__ img,
                                                 const float* __restrict__ inv_img,
                                                 const int* __restrict__ gKeep,
                                                 const int* __restrict__ gNon,
                                                 const float* __restrict__ gPnk,
                                                 const float* __restrict__ gP,
                                                 const float* __restrict__ capn,
                                                 const float* __restrict__ qi2t,
                                                 const float* __restrict__ qt2i,
                                                 const float* __restrict__ temp_p,
                                                 float* __restrict__ out) {
    int i = blockIdx.x, b = blockIdx.y, t = threadIdx.x;
    int pair = b * NCAP + i;
    int lane = t & 63;
    int wu = t >> 6;          // wave 0..7
    int kg = t >> 7;          // 0..3
    int cx = t & 127;         // col group
    int kb = 13 * kg;
    int qg = t >> 4;          // 0..31 (U phase)
    int lg = t & 15;          // 0..15 (U phase)

    // bufA: P-remap [98][64] (25.1 KB) in stream phase, Qs [96][68] (26.1 KB) in U phase.
    __shared__ __align__(16) float bufA[96 * 68];
    __shared__ __align__(16) float Sl[64 * 68];     // sel_tok chunk [l][c], 17.4 KB
    __shared__ __align__(16) float ULDS[96 * 51];   // 19.6 KB
    __shared__ float wpartA[8][16];
    __shared__ float wpartE[8];
    __shared__ float invA[KEEPED];
    __shared__ float scl[1];
    __shared__ float colM[51], colZ[51], rowM[32], rowZ[32];
    __shared__ float redw[8];

    const int*   keep = gKeep + pair * NKEEP;
    const int*   nonk = gNon + pair * NKEEP;
    const float* pnk  = gPnk + pair * NKEEP;
    const float* Pg   = gP + (size_t)pair * NKEEP * 52;
    const float* imgb = img + (size_t)b * LV * C;
    const float4* imgb4 = (const float4*)imgb;

    // ---- stage P into LDS, remapped so kg's 13 values are 16B-aligned: [j][16g+r]
    for (int f = t; f < NKEEP * 52; f += 512) {
        int j = f / 52, k = f - 52 * j;
        int g = k / 13, r = k - 13 * g;
        bufA[j * 64 + 16 * g + r] = Pg[f];
    }

    // ---- cls (normalized now; invC independent of this block's compute)
    float cls4[4];
    {
        float invC = inv_img[b * LV];
        float4 cv = imgb4[cx];
        cls4[0] = cv.x * invC; cls4[1] = cv.y * invC;
        cls4[2] = cv.z * invC; cls4[3] = cv.w * invC;
    }

    // ---- extra: softmax-weighted nonkeep sum (no LDS)
    float e4[4] = {0.f, 0.f, 0.f, 0.f};
    {
        int s2 = nonk[0];
        float4 v = imgb4[(size_t)(1 + s2) * 128 + cx];
        for (int j = 0; j < NKEEP; ++j) {
            float4 vc = v;
            if (j + 1 < NKEEP) { s2 = nonk[j + 1]; v = imgb4[(size_t)(1 + s2) * 128 + cx]; }
            float w = pnk[j];
            e4[0] = fmaf(w, vc.x, e4[0]); e4[1] = fmaf(w, vc.y, e4[1]);
            e4[2] = fmaf(w, vc.z, e4[2]); e4[3] = fmaf(w, vc.w, e4[3]);
        }
    }
    __syncthreads();   // P staged

    // ---- aggr: acc[r][d] += P[j][kb+r] * sel[j][4cx+d]; P as 4 uniform b128 reads
    float acc[13][4];
#pragma unroll
    for (int r = 0; r < 13; ++r) { acc[r][0] = 0.f; acc[r][1] = 0.f; acc[r][2] = 0.f; acc[r][3] = 0.f; }
    {
        int s2 = keep[0];
        float4 v = imgb4[(size_t)(1 + s2) * 128 + cx];
        for (int j = 0; j < NKEEP; ++j) {
            float4 vc = v;
            if (j + 1 < NKEEP) { s2 = keep[j + 1]; v = imgb4[(size_t)(1 + s2) * 128 + cx]; }
            const float4* pr = (const float4*)&bufA[j * 64 + 16 * kg];
            float4 p0 = pr[0], p1 = pr[1], p2 = pr[2], p3 = pr[3];
            float pv[13] = {p0.x, p0.y, p0.z, p0.w, p1.x, p1.y, p1.z, p1.w,
                            p2.x, p2.y, p2.z, p2.w, p3.x};
#pragma unroll
            for (int r = 0; r < 13; ++r) {
                acc[r][0] = fmaf(pv[r], vc.x, acc[r][0]);
                acc[r][1] = fmaf(pv[r], vc.y, acc[r][1]);
                acc[r][2] = fmaf(pv[r], vc.z, acc[r][2]);
                acc[r][3] = fmaf(pv[r], vc.w, acc[r][3]);
            }
        }
    }

    // ---- norms
#pragma unroll
    for (int r = 0; r < 13; ++r) {
        float v = acc[r][0] * acc[r][0] + acc[r][1] * acc[r][1]
                + acc[r][2] * acc[r][2] + acc[r][3] * acc[r][3];
        for (int o = 32; o > 0; o >>= 1) v += __shfl_down(v, o);
        if (lane == 0) wpartA[wu][r] = v;
    }
    if (kg == 0) {
        float v = e4[0] * e4[0] + e4[1] * e4[1] + e4[2] * e4[2] + e4[3] * e4[3];
        for (int o = 32; o > 0; o >>= 1) v += __shfl_down(v, o);
        if (lane == 0) wpartE[wu] = v;
    }
    __syncthreads();
    if (t < KEEPED) {
        int g = t / 13, r = t - g * 13;
        float s = wpartA[2 * g][r] + wpartA[2 * g + 1][r];
        invA[t] = 1.f / fmaxf(sqrtf(s), 1e-12f);
    }
    if (t == KEEPED) scl[0] = 1.f / fmaxf(sqrtf(wpartE[0] + wpartE[1]), 1e-12f);
    __syncthreads();
    {
        float invE = scl[0];
#pragma unroll
        for (int r = 0; r < 13; ++r) {
            int k = kb + r;
            if (k < KEEPED) {
                float ia = invA[k];
                acc[r][0] *= ia; acc[r][1] *= ia; acc[r][2] *= ia; acc[r][3] *= ia;
            }
        }
        e4[0] *= invE; e4[1] *= invE; e4[2] *= invE; e4[3] *= invE;
    }

    // ---- U = [capn; qi2t; qt2i](96 x C) @ sel_tok^T(C x 51), 8 c-chunks of 64
    float uacc[3][4];
#pragma unroll
    for (int qq = 0; qq < 3; ++qq) { uacc[qq][0] = 0.f; uacc[qq][1] = 0.f; uacc[qq][2] = 0.f; uacc[qq][3] = 0.f; }

    for (int m = 0; m < 8; ++m) {
        __syncthreads();   // previous chunk compute done
        // build Sl chunk from owners of these columns
        if ((cx >> 4) == m) {
            int c0 = (cx & 15) * 4;
#pragma unroll
            for (int d = 0; d < 4; ++d) {
                int col = c0 + d;
                if (kg == 0) Sl[0 * 68 + col] = cls4[d];
#pragma unroll
                for (int r = 0; r < 13; ++r) {
                    int k = kb + r;
                    if (k < KEEPED) Sl[(k + 1) * 68 + col] = acc[r][d];
                }
                if (kg == 3) Sl[50 * 68 + col] = e4[d];
            }
        }
        // stage Q chunk (96 rows x 16 float4), coalesced
        for (int f = t; f < 96 * 16; f += 512) {
            int q = f >> 4, cq = f & 15;
            const float* rp = (q < 32) ? (capn + ((size_t)i * LT + q) * C)
                            : (q < 64) ? (qi2t + ((size_t)i * LT + q - 32) * C)
                                       : (qt2i + ((size_t)i * LT + q - 64) * C);
            *(float4*)&bufA[q * 68 + 4 * cq] = *(const float4*)&rp[m * 64 + 4 * cq];
        }
        __syncthreads();
        // compute: per c-quad 7 LDS b128 + 48 fmac
#pragma unroll 4
        for (int cq = 0; cq < 64; cq += 4) {
            float4 s0 = *(const float4*)&Sl[(lg     ) * 68 + cq];
            float4 s1 = *(const float4*)&Sl[(lg + 16) * 68 + cq];
            float4 s2 = *(const float4*)&Sl[(lg + 32) * 68 + cq];
            float4 s3 = *(const float4*)&Sl[(lg + 48) * 68 + cq];
#pragma unroll
            for (int qq = 0; qq < 3; ++qq) {
                float4 qv = *(const float4*)&bufA[(3 * qg + qq) * 68 + cq];
                uacc[qq][0] = fmaf(qv.x, s0.x, fmaf(qv.y, s0.y, fmaf(qv.z, s0.z, fmaf(qv.w, s0.w, uacc[qq][0]))));
                uacc[qq][1] = fmaf(qv.x, s1.x, fmaf(qv.y, s1.y, fmaf(qv.z, s1.z, fmaf(qv.w, s1.w, uacc[qq][1]))));
                uacc[qq][2] = fmaf(qv.x, s2.x, fmaf(qv.y, s2.y, fmaf(qv.z, s2.z, fmaf(qv.w, s2.w, uacc[qq][2]))));
                uacc[qq][3] = fmaf(qv.x, s3.x, fmaf(qv.y, s3.y, fmaf(qv.z, s3.z, fmaf(qv.w, s3.w, uacc[qq][3]))));
            }
        }
    }
    __syncthreads();
    // ---- store U (l = lg + 16r)
#pragma unroll
    for (int qq = 0; qq < 3; ++qq) {
#pragma unroll
        for (int r = 0; r < 4; ++r) {
            int l = lg + 16 * r;
            if (l < 51) ULDS[(3 * qg + qq) * 51 + l] = uacc[qq][r];
        }
    }
    __syncthreads();

    // ---- softmax stats
    float invT = 1.f / temp_p[0];
    if (t < 51) {
        float mm = -1e30f;
        for (int u = 0; u < LT; ++u) mm = fmaxf(mm, ULDS[(32 + u) * 51 + t] * invT);
        float z = 0.f;
        for (int u = 0; u < LT; ++u) z += expf(ULDS[(32 + u) * 51 + t] * invT - mm);
        colM[t] = mm; colZ[t] = 1.f / z;
    }
    if (t >= 64 && t < 96) {
        int u = t - 64;
        float mm = -1e30f;
        for (int l = 0; l < 51; ++l) mm = fmaxf(mm, ULDS[(64 + u) * 51 + l] * invT);
        float z = 0.f;
        for (int l = 0; l < 51; ++l) z += expf(ULDS[(64 + u) * 51 + l] * invT - mm);
        rowM[u] = mm; rowZ[u] = 1.f / z;
    }
    __syncthreads();

    // ---- final reduction
    float part = 0.f;
    for (int f = t; f < LT * 51; f += 512) {
        int u = f / 51, l = f - u * 51;
        float u0 = ULDS[u * 51 + l];
        float c2 = (u0 > 0.f) ? u0 : 0.1f * u0;
        float av = expf(ULDS[(32 + u) * 51 + l] * invT - colM[l]) * colZ[l];
        float bv = expf(ULDS[(64 + u) * 51 + l] * invT - rowM[u]) * rowZ[u];
        part += c2 * (av * (1.f / 51.f) + bv * (1.f / 32.f));
    }
    for (int o = 32; o > 0; o >>= 1) part += __shfl_down(part, o);
    if (lane == 0) redw[wu] = part;
    __syncthreads();
    if (t == 0) {
        float s = 0.f;
#pragma unroll
        for (int w2 = 0; w2 < 8; ++w2) s += redw[w2];
        out[b * NCAP + i] = s;
    }
}

extern "C" void kernel_launch(void* const* d_in, const int* in_sizes, int n_in,
                              void* d_out, int out_size, void* d_ws, size_t ws_size,
                              hipStream_t stream) {
    const float* img        = (const float*)d_in[0];
    const float* cap        = (const float*)d_in[1];
    const float* gamw       = (const float*)d_in[3];
    const float* betw       = (const float*)d_in[4];
    const float* w1         = (const float*)d_in[5];
    const float* b1         = (const float*)d_in[6];
    const float* w2         = (const float*)d_in[7];
    const float* b2         = (const float*)d_in[8];
    const float* aggr_scale = (const float*)d_in[9];
    const float* wi2t       = (const float*)d_in[10];
    const float* bi2t       = (const float*)d_in[11];
    const float* wt2i       = (const float*)d_in[12];
    const float* bt2i       = (const float*)d_in[13];
    const float* temp       = (const float*)d_in[14];
    float* out = (float*)d_out;

    float* ws      = (float*)d_ws;
    float* inv_img = ws + OFF_INV;
    float* attn_x  = ws + OFF_ATTNX;
    float* WsM     = ws + OFF_WSMAT;
    float* capn    = ws + OFF_CAPN;
    float* qi2t    = ws + OFF_QI2T;
    float* qt2i    = ws + OFF_QT2I;
    float* gloT    = ws + OFF_GLOT;
    float* attn_y  = ws + OFF_ATTNY;
    int*   gKeep   = (int*)(ws + OFF_KEEP);
    int*   gNon    = (int*)(ws + OFF_NON);
    float* gPnk    = ws + OFF_PNK;
    float* gP      = ws + OFF_GP;

    k_img_norm<<<dim3(B * LV), dim3(64), 0, stream>>>(img, inv_img);
    k_cap_norm<<<dim3(NCAP, LT), dim3(64), 0, stream>>>(cap, capn, gloT);
    k_qproj<<<dim3(NCAP, 4), dim3(256), 0, stream>>>(capn, wi2t, bi2t, wt2i, bt2i, qi2t, qt2i);
    k_img_row<<<dim3(B, 25), dim3(256), 0, stream>>>(img, inv_img, gamw, betw, w1, b1, w2, b2,
                                                     aggr_scale, attn_x, WsM);
    k_attn_y<<<dim3(B, 25), dim3(64), 0, stream>>>(img, inv_img, gloT, attn_y);
    k_prep<<<dim3(NCAP, B), dim3(256), 0, stream>>>(attn_x, attn_y, WsM, gKeep, gNon, gPnk, gP);
    k_main<<<dim3(NCAP, B), dim3(512), 0, stream>>>(img, inv_img, gKeep, gNon, gPnk, gP,
                                                    capn, qi2t, qt2i, temp, out);
}

// Round 6
// 744.993 us; speedup vs baseline: 3.1446x; 2.0901x over previous
//
#include <hip/hip_runtime.h>
#include <math.h>

#define B     64
#define NCAP  64
#define LV    197
#define LT    32
#define C     512
#define NSP   196
#define NKEEP 98
#define HID   102
#define KEEPED 49

// Workspace layout (float element offsets). Total 19,407,680 floats = 77.6 MB (< proven 106.8 MB).
#define OFF_INV     0                         // B*LV
#define OFF_ATTNX   12608                     // B*NSP
#define OFF_WSMAT   25152                     // B*NSP*KEEPED
#define OFF_CAPN    639808                    // NCAP*LT*C (fp32, k_qproj input)
#define OFF_GLOT    1688384                   // C*NCAP
#define OFF_ATTNY   1721152                   // B*NSP*NCAP
#define OFF_KEEP    2523968                   // 4096*98 ints
#define OFF_NON     2925376                   // 4096*98 ints
#define OFF_PNK     3326784                   // 4096*98 floats
#define OFF_GPB     3728192                   // ushort 4096*98*52 (bf16 P, stride 52)
#define OFF_IMGT    14164800                  // ushort 64*512*224 (bf16 img^T, s-padded)
#define OFF_QBB     17834816                  // ushort 64*96*512 (bf16 [capn;qi2t;qt2i])

typedef unsigned int u32;
typedef unsigned short u16;
typedef __bf16 bf16x8 __attribute__((ext_vector_type(8)));
typedef float f32x4 __attribute__((ext_vector_type(4)));
typedef unsigned int uint4v __attribute__((ext_vector_type(4)));

__device__ __forceinline__ u16 f2bf(float f) {
    u32 u = __builtin_bit_cast(u32, f);
    return (u16)((u + 0x7FFFu + ((u >> 16) & 1u)) >> 16);
}
__device__ __forceinline__ bf16x8 ld_bf8(const u16* p) {
    uint4v v = *reinterpret_cast<const uint4v*>(p);
    return __builtin_bit_cast(bf16x8, v);
}

__device__ __forceinline__ float gelu_exact(float x) {
    return 0.5f * x * (1.f + erff(x * 0.70710678118654752f));
}

// ---------------------------------------------------------------- img row norms
__global__ __launch_bounds__(64) void k_img_norm(const float* __restrict__ img,
                                                 float* __restrict__ inv_img) {
    int r = blockIdx.x, t = threadIdx.x;
    const float* row = img + (size_t)r * C;
    float ss = 0.f;
    for (int c = t; c < C; c += 64) { float v = row[c]; ss += v * v; }
    for (int o = 32; o > 0; o >>= 1) ss += __shfl_down(ss, o);
    if (t == 0) inv_img[r] = 1.f / fmaxf(sqrtf(ss), 1e-12f);
}

// ---------------------------------------------------------------- img^T bf16 (s-padded to 224)
__global__ __launch_bounds__(256) void k_imgt(const float* __restrict__ img,
                                              u16* __restrict__ imgT) {
    int b = blockIdx.x, cg = blockIdx.y, t = threadIdx.x;
    __shared__ u16 Tl[64 * 224];
    for (int f = t; f < 64 * 27; f += 256) Tl[(f / 27) * 224 + 197 + (f % 27)] = 0;
    int cc = t & 63;
    for (int sb = t >> 6; sb < 197; sb += 4) {
        float v = img[((size_t)b * LV + sb) * C + cg * 64 + cc];
        Tl[cc * 224 + sb] = f2bf(v);
    }
    __syncthreads();
    const u32* Tu = (const u32*)Tl;
    u32* outp = (u32*)(imgT + ((size_t)b * 512 + cg * 64) * 224);
    for (int f = t; f < 64 * 112; f += 256) outp[f] = Tu[f];
}

// ---------------------------------------------------------------- caption norms (+ Qbb rows 0..31)
__global__ __launch_bounds__(64) void k_cap_norm(const float* __restrict__ cap,
                                                 float* __restrict__ capn,
                                                 float* __restrict__ gloT,
                                                 u16* __restrict__ Qbb) {
    int i = blockIdx.x, tt = blockIdx.y, t = threadIdx.x;
    const float* row = cap + ((size_t)i * LT + tt) * C;
    float v[8]; float ss = 0.f;
#pragma unroll
    for (int q = 0; q < 8; ++q) { v[q] = row[t + 64 * q]; ss += v[q] * v[q]; }
    for (int o = 32; o > 0; o >>= 1) ss += __shfl_down(ss, o);
    ss = __shfl(ss, 0);
    float inv = 1.f / fmaxf(sqrtf(ss), 1e-12f);
    float* orow = capn + ((size_t)i * LT + tt) * C;
    u16* qrow = Qbb + ((size_t)i * 96 + tt) * C;
#pragma unroll
    for (int q = 0; q < 8; ++q) {
        float n = v[q] * inv;
        orow[t + 64 * q] = n;
        qrow[t + 64 * q] = f2bf(n);
        if (tt == 0) gloT[(t + 64 * q) * NCAP + i] = n;
    }
}

// ---------------------------------------------------------------- qi2t / qt2i -> Qbb rows 32..95 (bf16)
__global__ __launch_bounds__(256) void k_qproj(const float* __restrict__ capn,
                                               const float* __restrict__ wi2t,
                                               const float* __restrict__ bi2t,
                                               const float* __restrict__ wt2i,
                                               const float* __restrict__ bt2i,
                                               u16* __restrict__ Qbb) {
    int i = blockIdx.x, tg = blockIdx.y, t = threadIdx.x;
    __shared__ __align__(16) float xr[8][C];
    const float* base = capn + ((size_t)i * LT + tg * 8) * C;
    for (int f = t; f < 8 * C; f += 256) xr[f >> 9][f & 511] = base[f];
    __syncthreads();
    int j0 = t, j1 = t + 256;
    for (int mtx = 0; mtx < 2; ++mtx) {
        const float* W  = mtx ? wt2i : wi2t;
        const float* bb = mtx ? bt2i : bi2t;
        float a0[8], a1[8];
        float bj0 = bb[j0], bj1 = bb[j1];
#pragma unroll
        for (int r = 0; r < 8; ++r) { a0[r] = bj0; a1[r] = bj1; }
        for (int c = 0; c < C; ++c) {
            float w0 = W[c * C + j0], w1v = W[c * C + j1];
#pragma unroll
            for (int r = 0; r < 8; ++r) {
                a0[r] += xr[r][c] * w0;
                a1[r] += xr[r][c] * w1v;
            }
        }
#pragma unroll
        for (int r = 0; r < 8; ++r) {
            u16* qr = Qbb + ((size_t)i * 96 + 32 + mtx * 32 + tg * 8 + r) * C;
            qr[j0] = f2bf(a0[r]);
            qr[j1] = f2bf(a1[r]);
        }
    }
}

// ---------------------------------------------------------------- LN -> w1 -> gelu -> w2 + attn_x
__global__ __launch_bounds__(256) void k_img_row(const float* __restrict__ img,
                                                 const float* __restrict__ inv_img,
                                                 const float* __restrict__ gamw,
                                                 const float* __restrict__ betw,
                                                 const float* __restrict__ w1,
                                                 const float* __restrict__ b1,
                                                 const float* __restrict__ w2,
                                                 const float* __restrict__ b2,
                                                 const float* __restrict__ scale_p,
                                                 float* __restrict__ attn_x,
                                                 float* __restrict__ WsM) {
    int b = blockIdx.x, s0 = blockIdx.y * 8, t = threadIdx.x;
    int R = NSP - s0; if (R > 8) R = 8;
    __shared__ __align__(16) float lnr[8][C];
    __shared__ float HH[8][HID + 2];
    __shared__ float redm[8][3];

    int g = t >> 5, lane = t & 31;
    if (g < R) {
        const float* row = img + ((size_t)b * LV + 1 + s0 + g) * C;
        const float* cls = img + (size_t)b * LV * C;
        float sm = 0.f, ss = 0.f, dd = 0.f;
        for (int c = lane; c < C; c += 32) {
            float v = row[c];
            sm += v; ss += v * v; dd += v * cls[c];
            lnr[g][c] = v;
        }
        for (int o = 16; o > 0; o >>= 1) {
            sm += __shfl_down(sm, o, 32);
            ss += __shfl_down(ss, o, 32);
            dd += __shfl_down(dd, o, 32);
        }
        if (lane == 0) { redm[g][0] = sm; redm[g][1] = ss; redm[g][2] = dd; }
    }
    __syncthreads();
    for (int f = t; f < R * C; f += 256) {
        int rr = f >> 9, c = f & 511;
        float mean = redm[rr][0] * (1.f / C);
        float var  = redm[rr][1] * (1.f / C) - mean * mean;
        float rstd = 1.f / sqrtf(var + 1e-5f);
        lnr[rr][c] = (lnr[rr][c] - mean) * rstd * gamw[c] + betw[c];
    }
    if (t < R) {
        float inv0 = inv_img[b * LV];
        float invs = inv_img[b * LV + 1 + s0 + t];
        attn_x[b * NSP + s0 + t] = redm[t][2] * inv0 * invs;
    }
    __syncthreads();
    if (t < HID) {
        float acc[8];
#pragma unroll
        for (int r = 0; r < 8; ++r) acc[r] = b1[t];
        for (int c = 0; c < C; ++c) {
            float w = w1[c * HID + t];
#pragma unroll
            for (int r = 0; r < 8; ++r) acc[r] += lnr[r][c] * w;
        }
#pragma unroll
        for (int r = 0; r < 8; ++r) HH[r][t] = gelu_exact(acc[r]);
    }
    __syncthreads();
    float scale = scale_p[0];
    if (t < 196) {
        int k = t % 49, rh = t / 49;
        for (int rr = rh; rr < 8; rr += 4) {
            if (rr < R) {
                float a = b2[k];
                for (int h = 0; h < HID; ++h) a += HH[rr][h] * w2[h * 49 + k];
                WsM[((size_t)b * NSP + s0 + rr) * 49 + k] = a * scale;
            }
        }
    }
}

// ---------------------------------------------------------------- attn_y
__global__ __launch_bounds__(64) void k_attn_y(const float* __restrict__ img,
                                               const float* __restrict__ inv_img,
                                               const float* __restrict__ gloT,
                                               float* __restrict__ attn_y) {
    int b = blockIdx.x, s0 = blockIdx.y * 8, t = threadIdx.x;
    int R = NSP - s0; if (R > 8) R = 8;
    __shared__ __align__(16) float xr[8][C];
    for (int rr = 0; rr < R; ++rr) {
        float inv = inv_img[b * LV + 1 + s0 + rr];
        const float* row = img + ((size_t)b * LV + 1 + s0 + rr) * C;
        for (int c = t; c < C; c += 64) xr[rr][c] = row[c] * inv;
    }
    __syncthreads();
    float acc[8] = {0, 0, 0, 0, 0, 0, 0, 0};
    for (int c4 = 0; c4 < C / 4; ++c4) {
        float g0 = gloT[(c4 * 4 + 0) * NCAP + t];
        float g1 = gloT[(c4 * 4 + 1) * NCAP + t];
        float g2 = gloT[(c4 * 4 + 2) * NCAP + t];
        float g3 = gloT[(c4 * 4 + 3) * NCAP + t];
#pragma unroll
        for (int r = 0; r < 8; ++r) {
            float4 xv = ((const float4*)xr[r])[c4];
            acc[r] += xv.x * g0 + xv.y * g1 + xv.z * g2 + xv.w * g3;
        }
    }
    for (int rr = 0; rr < R; ++rr)
        attn_y[((size_t)b * NSP + s0 + rr) * NCAP + t] = acc[rr];
}

// ---------------------------------------------------------------- per-pair prep (bf16 P out)
__global__ __launch_bounds__(256) void k_prep(const float* __restrict__ attn_x,
                                              const float* __restrict__ attn_y,
                                              const float* __restrict__ WsM,
                                              int* __restrict__ gKeep,
                                              int* __restrict__ gNon,
                                              float* __restrict__ gPnk,
                                              u16* __restrict__ gPb) {
    int i = blockIdx.x, b = blockIdx.y, t = threadIdx.x;
    int pair = b * NCAP + i;
    __shared__ float scoreS[NSP];
    __shared__ int   keepL[NKEEP];
    __shared__ int   nonL[NKEEP];
    __shared__ float snon[NKEEP];
    __shared__ float mk[KEEPED];
    __shared__ float bcast[1];

    if (t < NSP) scoreS[t] = attn_x[b * NSP + t] + attn_y[(size_t)(b * NSP + t) * NCAP + i];
    __syncthreads();
    if (t < NSP) {
        float sv = scoreS[t];
        int r = 0;
        for (int u = 0; u < NSP; ++u) {
            float o = scoreS[u];
            r += (o > sv) || (o == sv && u < t);
        }
        if (r < NKEEP) keepL[r] = t;
        else { nonL[r - NKEEP] = t; snon[r - NKEEP] = sv; }
    }
    __syncthreads();
    if (t == 0) {
        float m = -1e30f;
        for (int j = 0; j < NKEEP; ++j) m = fmaxf(m, snon[j]);
        bcast[0] = m;
    }
    __syncthreads();
    if (t < NKEEP) {
        gKeep[pair * NKEEP + t] = keepL[t];
        gNon[pair * NKEEP + t]  = nonL[t];
        gPnk[pair * NKEEP + t]  = expf(snon[t] - bcast[0]);
    }
    if (t < KEEPED) {
        float m2 = -1e30f;
        for (int j = 0; j < NKEEP; ++j)
            m2 = fmaxf(m2, WsM[((size_t)b * NSP + keepL[j]) * KEEPED + t]);
        mk[t] = m2;
    }
    __syncthreads();
    u16* Pm = gPb + (size_t)pair * NKEEP * 52;
    for (int f = t; f < NKEEP * KEEPED; f += 256) {
        int j = f / KEEPED, k = f - j * KEEPED;
        Pm[j * 52 + k] = f2bf(expf(WsM[((size_t)b * NSP + keepL[j]) * KEEPED + k] - mk[k]));
    }
}

// ---------------------------------------------------------------- main per-pair kernel: two MFMA GEMMs
// Phase 1: T(51x512) = Pfull(51x224 bf16 LDS) @ imgT(224x512 bf16 global); row-norm -> Tn bf16 LDS.
// Phase 2: U(96x64) = Qbb(96x512 bf16 global) @ Tn^T; softmax epilogue.
__global__ __launch_bounds__(512, 4) void k_main(const int* __restrict__ gKeep,
                                                 const int* __restrict__ gNon,
                                                 const float* __restrict__ gPnk,
                                                 const u16* __restrict__ gPb,
                                                 const u16* __restrict__ imgT,
                                                 const u16* __restrict__ Qbb,
                                                 const float* __restrict__ temp_p,
                                                 float* __restrict__ out) {
    int i = blockIdx.x, b = blockIdx.y, t = threadIdx.x;
    int pair = b * NCAP + i;
    int lane = t & 63, wu = t >> 6;
    int l15 = lane & 15, quad = lane >> 4;

    __shared__ __align__(16) u16 TnBuf[51 * 520];   // 53,040 B; aliases Pf(64x232) then ULDS(96x52 f32)
    __shared__ float rowsq[4][64];
    __shared__ float invn[64];
    __shared__ float colM[51], colZ[51], rowM[32], rowZ[32], redw[8];

    u16*   Pf   = TnBuf;            // 64*232 = 14,848 u16
    float* ULDS = (float*)TnBuf;    // 96*52 floats = 19,968 B

    // ---- build Pfull in LDS (zero + scatter)
    {
        u32* Pfu = (u32*)Pf;
        for (int f = t; f < 64 * 232 / 2; f += 512) Pfu[f] = 0;
    }
    __syncthreads();
    {
        const int*   keep = gKeep + pair * NKEEP;
        const int*   nonk = gNon + pair * NKEEP;
        const float* pnk  = gPnk + pair * NKEEP;
        const u16*   Pg   = gPb + (size_t)pair * NKEEP * 52;
        if (t == 0) Pf[0] = 0x3F80;                       // cls one-hot (1.0)
        for (int f = t; f < NKEEP * KEEPED; f += 512) {
            int j = f / KEEPED, k = f - j * KEEPED;
            Pf[(1 + k) * 232 + 1 + keep[j]] = Pg[j * 52 + k];
        }
        if (t < NKEEP) Pf[50 * 232 + 1 + nonk[t]] = f2bf(pnk[t]);
    }
    __syncthreads();

    // ---- phase 1: wave w handles mi in {2mp,2mp+1}, ni in [8nq,8nq+8)
    int mp = wu >> 2, nq = wu & 3;
    const u16* imgTb = imgT + (size_t)b * 512 * 224;
    f32x4 acc[2][8];
#pragma unroll
    for (int a = 0; a < 2; ++a)
#pragma unroll
        for (int n = 0; n < 8; ++n) acc[a][n] = (f32x4){0.f, 0.f, 0.f, 0.f};

    for (int ks = 0; ks < 7; ++ks) {
        bf16x8 A0 = ld_bf8(Pf + (mp * 32 + l15) * 232 + ks * 32 + quad * 8);
        bf16x8 A1 = ld_bf8(Pf + (mp * 32 + 16 + l15) * 232 + ks * 32 + quad * 8);
#pragma unroll
        for (int nn = 0; nn < 8; ++nn) {
            int c = (nq * 8 + nn) * 16 + l15;
            bf16x8 Bf = ld_bf8(imgTb + (size_t)c * 224 + ks * 32 + quad * 8);
            acc[0][nn] = __builtin_amdgcn_mfma_f32_16x16x32_bf16(A0, Bf, acc[0][nn], 0, 0, 0);
            acc[1][nn] = __builtin_amdgcn_mfma_f32_16x16x32_bf16(A1, Bf, acc[1][nn], 0, 0, 0);
        }
    }

    // ---- row sums of squares (rows = l of T)
#pragma unroll
    for (int a = 0; a < 2; ++a)
#pragma unroll
        for (int r = 0; r < 4; ++r) {
            float s = 0.f;
#pragma unroll
            for (int nn = 0; nn < 8; ++nn) { float v = acc[a][nn][r]; s += v * v; }
            s += __shfl_down(s, 8); s += __shfl_down(s, 4);
            s += __shfl_down(s, 2); s += __shfl_down(s, 1);
            if (l15 == 0) rowsq[nq][mp * 32 + a * 16 + quad * 4 + r] = s;
        }
    __syncthreads();   // also: all Pf reads complete
    if (t < 64) {
        float s = rowsq[0][t] + rowsq[1][t] + rowsq[2][t] + rowsq[3][t];
        invn[t] = 1.f / fmaxf(sqrtf(s), 1e-12f);
    }
    __syncthreads();

    // ---- write normalized Tn (bf16) into TnBuf (Pf region dead)
#pragma unroll
    for (int a = 0; a < 2; ++a)
#pragma unroll
        for (int r = 0; r < 4; ++r) {
            int row = mp * 32 + a * 16 + quad * 4 + r;
            if (row < 51) {
                float iv = invn[row];
#pragma unroll
                for (int nn = 0; nn < 8; ++nn)
                    TnBuf[row * 520 + (nq * 8 + nn) * 16 + l15] = f2bf(acc[a][nn][r] * iv);
            }
        }
    __syncthreads();

    // ---- phase 2: 24 tiles (6 mi x 4 ni), wave w owns tiles 3w..3w+2
    const u16* Qb = Qbb + (size_t)i * 96 * 512;
    int tt0 = 3 * wu;
    f32x4 ua[3];
    int miA[3], rowB[3], niA[3];
#pragma unroll
    for (int e = 0; e < 3; ++e) {
        ua[e] = (f32x4){0.f, 0.f, 0.f, 0.f};
        int tt = tt0 + e;
        miA[e] = tt >> 2; niA[e] = tt & 3;
        int rb = niA[e] * 16 + l15;
        rowB[e] = rb > 50 ? 50 : rb;    // clamp: cols l>50 become copies, ignored
    }
    for (int ks = 0; ks < 16; ++ks) {
#pragma unroll
        for (int e = 0; e < 3; ++e) {
            bf16x8 Af = ld_bf8(Qb + (size_t)(miA[e] * 16 + l15) * 512 + ks * 32 + quad * 8);
            bf16x8 Bf = ld_bf8(TnBuf + rowB[e] * 520 + ks * 32 + quad * 8);
            ua[e] = __builtin_amdgcn_mfma_f32_16x16x32_bf16(Af, Bf, ua[e], 0, 0, 0);
        }
    }
    __syncthreads();   // all Tn reads done before U overwrites the buffer

    // ---- write U (96 x 51) into ULDS
#pragma unroll
    for (int e = 0; e < 3; ++e) {
        int l = niA[e] * 16 + l15;
        if (l < 51) {
            int q0 = miA[e] * 16 + quad * 4;
#pragma unroll
            for (int r = 0; r < 4; ++r) ULDS[(q0 + r) * 52 + l] = ua[e][r];
        }
    }
    __syncthreads();

    // ---- softmax stats
    float invT = 1.f / temp_p[0];
    if (t < 51) {
        float mm = -1e30f;
        for (int u = 0; u < LT; ++u) mm = fmaxf(mm, ULDS[(32 + u) * 52 + t] * invT);
        float z = 0.f;
        for (int u = 0; u < LT; ++u) z += expf(ULDS[(32 + u) * 52 + t] * invT - mm);
        colM[t] = mm; colZ[t] = 1.f / z;
    }
    if (t >= 64 && t < 96) {
        int u = t - 64;
        float mm = -1e30f;
        for (int l = 0; l < 51; ++l) mm = fmaxf(mm, ULDS[(64 + u) * 52 + l] * invT);
        float z = 0.f;
        for (int l = 0; l < 51; ++l) z += expf(ULDS[(64 + u) * 52 + l] * invT - mm);
        rowM[u] = mm; rowZ[u] = 1.f / z;
    }
    __syncthreads();

    // ---- final reduction
    float part = 0.f;
    for (int f = t; f < LT * 51; f += 512) {
        int u = f / 51, l = f - u * 51;
        float u0 = ULDS[u * 52 + l];
        float c2 = (u0 > 0.f) ? u0 : 0.1f * u0;
        float av = expf(ULDS[(32 + u) * 52 + l] * invT - colM[l]) * colZ[l];
        float bv = expf(ULDS[(64 + u) * 52 + l] * invT - rowM[u]) * rowZ[u];
        part += c2 * (av * (1.f / 51.f) + bv * (1.f / 32.f));
    }
    for (int o = 32; o > 0; o >>= 1) part += __shfl_down(part, o);
    if (lane == 0) redw[wu] = part;
    __syncthreads();
    if (t == 0) {
        float s = 0.f;
#pragma unroll
        for (int w2 = 0; w2 < 8; ++w2) s += redw[w2];
        out[b * NCAP + i] = s;
    }
}

extern "C" void kernel_launch(void* const* d_in, const int* in_sizes, int n_in,
                              void* d_out, int out_size, void* d_ws, size_t ws_size,
                              hipStream_t stream) {
    const float* img        = (const float*)d_in[0];
    const float* cap        = (const float*)d_in[1];
    const float* gamw       = (const float*)d_in[3];
    const float* betw       = (const float*)d_in[4];
    const float* w1         = (const float*)d_in[5];
    const float* b1         = (const float*)d_in[6];
    const float* w2         = (const float*)d_in[7];
    const float* b2         = (const float*)d_in[8];
    const float* aggr_scale = (const float*)d_in[9];
    const float* wi2t       = (const float*)d_in[10];
    const float* bi2t       = (const float*)d_in[11];
    const float* wt2i       = (const float*)d_in[12];
    const float* bt2i       = (const float*)d_in[13];
    const float* temp       = (const float*)d_in[14];
    float* out = (float*)d_out;

    float* ws      = (float*)d_ws;
    float* inv_img = ws + OFF_INV;
    float* attn_x  = ws + OFF_ATTNX;
    float* WsM     = ws + OFF_WSMAT;
    float* capn    = ws + OFF_CAPN;
    float* gloT    = ws + OFF_GLOT;
    float* attn_y  = ws + OFF_ATTNY;
    int*   gKeep   = (int*)(ws + OFF_KEEP);
    int*   gNon    = (int*)(ws + OFF_NON);
    float* gPnk    = ws + OFF_PNK;
    u16*   gPb     = (u16*)(ws + OFF_GPB);
    u16*   imgT    = (u16*)(ws + OFF_IMGT);
    u16*   Qbb     = (u16*)(ws + OFF_QBB);

    k_img_norm<<<dim3(B * LV), dim3(64), 0, stream>>>(img, inv_img);
    k_imgt<<<dim3(B, 8), dim3(256), 0, stream>>>(img, imgT);
    k_cap_norm<<<dim3(NCAP, LT), dim3(64), 0, stream>>>(cap, capn, gloT, Qbb);
    k_qproj<<<dim3(NCAP, 4), dim3(256), 0, stream>>>(capn, wi2t, bi2t, wt2i, bt2i, Qbb);
    k_img_row<<<dim3(B, 25), dim3(256), 0, stream>>>(img, inv_img, gamw, betw, w1, b1, w2, b2,
                                                     aggr_scale, attn_x, WsM);
    k_attn_y<<<dim3(B, 25), dim3(64), 0, stream>>>(img, inv_img, gloT, attn_y);
    k_prep<<<dim3(NCAP, B), dim3(256), 0, stream>>>(attn_x, attn_y, WsM, gKeep, gNon, gPnk, gPb);
    k_main<<<dim3(NCAP, B), dim3(512), 0, stream>>>(gKeep, gNon, gPnk, gPb, imgT, Qbb, temp, out);
}

// Round 7
// 701.544 us; speedup vs baseline: 3.3394x; 1.0619x over previous
//
#include <hip/hip_runtime.h>
#include <math.h>

#define B     64
#define NCAP  64
#define LV    197
#define LT    32
#define C     512
#define NSP   196
#define NKEEP 98
#define HID   102
#define KEEPED 49

// Workspace layout (float element offsets). Total 19,407,680 floats = 77.6 MB.
#define OFF_INV     0                         // B*LV
#define OFF_ATTNX   12608                     // B*NSP
#define OFF_WSMAT   25152                     // B*NSP*KEEPED
#define OFF_WT      639808                    // u16 2*512*512 (bf16 wi2t^T / wt2i^T) in old capn slot
#define OFF_GLOT    1688384                   // C*NCAP
#define OFF_ATTNY   1721152                   // B*NSP*NCAP
#define OFF_KEEP    2523968                   // 4096*98 ints
#define OFF_NON     2925376                   // 4096*98 ints
#define OFF_PNK     3326784                   // 4096*98 floats
#define OFF_GPB     3728192                   // ushort 4096*98*52 (bf16 P, stride 52)
#define OFF_IMGT    14164800                  // ushort 64*512*224 (bf16 img^T, s-padded)
#define OFF_QBB     17834816                  // ushort 64*96*512 (bf16 [capn;qi2t;qt2i])

typedef unsigned int u32;
typedef unsigned short u16;
typedef __bf16 bf16x8 __attribute__((ext_vector_type(8)));
typedef float f32x4 __attribute__((ext_vector_type(4)));
typedef unsigned int uint4v __attribute__((ext_vector_type(4)));

__device__ __forceinline__ u16 f2bf(float f) {
    u32 u = __builtin_bit_cast(u32, f);
    return (u16)((u + 0x7FFFu + ((u >> 16) & 1u)) >> 16);
}
__device__ __forceinline__ bf16x8 ld_bf8(const u16* p) {
    uint4v v = *reinterpret_cast<const uint4v*>(p);
    return __builtin_bit_cast(bf16x8, v);
}

__device__ __forceinline__ float gelu_exact(float x) {
    return 0.5f * x * (1.f + erff(x * 0.70710678118654752f));
}

// ---------------------------------------------------------------- img row norms
__global__ __launch_bounds__(64) void k_img_norm(const float* __restrict__ img,
                                                 float* __restrict__ inv_img) {
    int r = blockIdx.x, t = threadIdx.x;
    const float* row = img + (size_t)r * C;
    float ss = 0.f;
    for (int c = t; c < C; c += 64) { float v = row[c]; ss += v * v; }
    for (int o = 32; o > 0; o >>= 1) ss += __shfl_down(ss, o);
    if (t == 0) inv_img[r] = 1.f / fmaxf(sqrtf(ss), 1e-12f);
}

// ---------------------------------------------------------------- img^T bf16 (s-padded to 224)
__global__ __launch_bounds__(256) void k_imgt(const float* __restrict__ img,
                                              u16* __restrict__ imgT) {
    int b = blockIdx.x, cg = blockIdx.y, t = threadIdx.x;
    __shared__ u16 Tl[64 * 224];
    for (int f = t; f < 64 * 27; f += 256) Tl[(f / 27) * 224 + 197 + (f % 27)] = 0;
    int cc = t & 63;
    for (int sb = t >> 6; sb < 197; sb += 4) {
        float v = img[((size_t)b * LV + sb) * C + cg * 64 + cc];
        Tl[cc * 224 + sb] = f2bf(v);
    }
    __syncthreads();
    const u32* Tu = (const u32*)Tl;
    u32* outp = (u32*)(imgT + ((size_t)b * 512 + cg * 64) * 224);
    for (int f = t; f < 64 * 112; f += 256) outp[f] = Tu[f];
}

// ---------------------------------------------------------------- caption norms (+ Qbb rows 0..31, gloT)
__global__ __launch_bounds__(64) void k_cap_norm(const float* __restrict__ cap,
                                                 float* __restrict__ gloT,
                                                 u16* __restrict__ Qbb) {
    int i = blockIdx.x, tt = blockIdx.y, t = threadIdx.x;
    const float* row = cap + ((size_t)i * LT + tt) * C;
    float v[8]; float ss = 0.f;
#pragma unroll
    for (int q = 0; q < 8; ++q) { v[q] = row[t + 64 * q]; ss += v[q] * v[q]; }
    for (int o = 32; o > 0; o >>= 1) ss += __shfl_down(ss, o);
    ss = __shfl(ss, 0);
    float inv = 1.f / fmaxf(sqrtf(ss), 1e-12f);
    u16* qrow = Qbb + ((size_t)i * 96 + tt) * C;
#pragma unroll
    for (int q = 0; q < 8; ++q) {
        float n = v[q] * inv;
        qrow[t + 64 * q] = f2bf(n);
        if (tt == 0) gloT[(t + 64 * q) * NCAP + i] = n;
    }
}

// ---------------------------------------------------------------- transpose wi2t/wt2i -> bf16 [j][c]
__global__ __launch_bounds__(256) void k_wt(const float* __restrict__ wi2t,
                                            const float* __restrict__ wt2i,
                                            u16* __restrict__ wT) {
    int mat = blockIdx.x, jg = blockIdx.y, t = threadIdx.x;
    const float* W = mat ? wt2i : wi2t;
    __shared__ u16 tile[64][65];
    for (int cg = 0; cg < 8; ++cg) {
        for (int f = t; f < 4096; f += 256) {
            int cc = f >> 6, jj = f & 63;
            tile[jj][cc] = f2bf(W[(size_t)(cg * 64 + cc) * 512 + jg * 64 + jj]);
        }
        __syncthreads();
        for (int f = t; f < 4096; f += 256) {
            int jj = f >> 6, cc = f & 63;
            wT[((size_t)mat * 512 + jg * 64 + jj) * 512 + cg * 64 + cc] = tile[jj][cc];
        }
        __syncthreads();
    }
}

// ---------------------------------------------------------------- qi2t/qt2i via MFMA -> Qbb rows 32..95
// wave wu: mat=wu>>2, mi=(wu>>1)&1, ni0=(wu&1)*16; 1 A-tile x 16 B-tiles.
__global__ __launch_bounds__(512) void k_qproj_mfma(const u16* __restrict__ wT,
                                                    const float* __restrict__ bi2t,
                                                    const float* __restrict__ bt2i,
                                                    u16* __restrict__ Qbb) {
    int i = blockIdx.x, t = threadIdx.x;
    int lane = t & 63, wu = t >> 6;
    int l15 = lane & 15, quad = lane >> 4;
    int mat = wu >> 2;
    int mi  = (wu >> 1) & 1;
    int ni0 = (wu & 1) * 16;
    const u16* Arow = Qbb + ((size_t)i * 96 + mi * 16 + l15) * 512;
    const u16* Wm   = wT + (size_t)mat * 512 * 512;
    f32x4 acc[16];
#pragma unroll
    for (int n = 0; n < 16; ++n) acc[n] = (f32x4){0.f, 0.f, 0.f, 0.f};
    for (int ks = 0; ks < 16; ++ks) {
        bf16x8 A = ld_bf8(Arow + ks * 32 + quad * 8);
#pragma unroll
        for (int n = 0; n < 16; ++n) {
            bf16x8 Bf = ld_bf8(Wm + (size_t)((ni0 + n) * 16 + l15) * 512 + ks * 32 + quad * 8);
            acc[n] = __builtin_amdgcn_mfma_f32_16x16x32_bf16(A, Bf, acc[n], 0, 0, 0);
        }
    }
    const float* bias = mat ? bt2i : bi2t;
#pragma unroll
    for (int n = 0; n < 16; ++n) {
        int j = (ni0 + n) * 16 + l15;
        float bj = bias[j];
        int row0 = i * 96 + 32 + mat * 32 + mi * 16 + quad * 4;
#pragma unroll
        for (int r = 0; r < 4; ++r)
            Qbb[(size_t)(row0 + r) * 512 + j] = f2bf(acc[n][r] + bj);
    }
}

// ---------------------------------------------------------------- LN -> w1 -> gelu -> w2 + attn_x
__global__ __launch_bounds__(256) void k_img_row(const float* __restrict__ img,
                                                 const float* __restrict__ inv_img,
                                                 const float* __restrict__ gamw,
                                                 const float* __restrict__ betw,
                                                 const float* __restrict__ w1,
                                                 const float* __restrict__ b1,
                                                 const float* __restrict__ w2,
                                                 const float* __restrict__ b2,
                                                 const float* __restrict__ scale_p,
                                                 float* __restrict__ attn_x,
                                                 float* __restrict__ WsM) {
    int b = blockIdx.x, s0 = blockIdx.y * 8, t = threadIdx.x;
    int R = NSP - s0; if (R > 8) R = 8;
    __shared__ __align__(16) float lnr[8][C];
    __shared__ float HH[8][HID + 2];
    __shared__ float redm[8][3];

    int g = t >> 5, lane = t & 31;
    if (g < R) {
        const float* row = img + ((size_t)b * LV + 1 + s0 + g) * C;
        const float* cls = img + (size_t)b * LV * C;
        float sm = 0.f, ss = 0.f, dd = 0.f;
        for (int c = lane; c < C; c += 32) {
            float v = row[c];
            sm += v; ss += v * v; dd += v * cls[c];
            lnr[g][c] = v;
        }
        for (int o = 16; o > 0; o >>= 1) {
            sm += __shfl_down(sm, o, 32);
            ss += __shfl_down(ss, o, 32);
            dd += __shfl_down(dd, o, 32);
        }
        if (lane == 0) { redm[g][0] = sm; redm[g][1] = ss; redm[g][2] = dd; }
    }
    __syncthreads();
    for (int f = t; f < R * C; f += 256) {
        int rr = f >> 9, c = f & 511;
        float mean = redm[rr][0] * (1.f / C);
        float var  = redm[rr][1] * (1.f / C) - mean * mean;
        float rstd = 1.f / sqrtf(var + 1e-5f);
        lnr[rr][c] = (lnr[rr][c] - mean) * rstd * gamw[c] + betw[c];
    }
    if (t < R) {
        float inv0 = inv_img[b * LV];
        float invs = inv_img[b * LV + 1 + s0 + t];
        attn_x[b * NSP + s0 + t] = redm[t][2] * inv0 * invs;
    }
    __syncthreads();
    if (t < HID) {
        float acc[8];
#pragma unroll
        for (int r = 0; r < 8; ++r) acc[r] = b1[t];
        for (int c = 0; c < C; ++c) {
            float w = w1[c * HID + t];
#pragma unroll
            for (int r = 0; r < 8; ++r) acc[r] += lnr[r][c] * w;
        }
#pragma unroll
        for (int r = 0; r < 8; ++r) HH[r][t] = gelu_exact(acc[r]);
    }
    __syncthreads();
    float scale = scale_p[0];
    if (t < 196) {
        int k = t % 49, rh = t / 49;
        for (int rr = rh; rr < 8; rr += 4) {
            if (rr < R) {
                float a = b2[k];
                for (int h = 0; h < HID; ++h) a += HH[rr][h] * w2[h * 49 + k];
                WsM[((size_t)b * NSP + s0 + rr) * 49 + k] = a * scale;
            }
        }
    }
}

// ---------------------------------------------------------------- attn_y (fp32 — keep score precision)
__global__ __launch_bounds__(64) void k_attn_y(const float* __restrict__ img,
                                               const float* __restrict__ inv_img,
                                               const float* __restrict__ gloT,
                                               float* __restrict__ attn_y) {
    int b = blockIdx.x, s0 = blockIdx.y * 8, t = threadIdx.x;
    int R = NSP - s0; if (R > 8) R = 8;
    __shared__ __align__(16) float xr[8][C];
    for (int rr = 0; rr < R; ++rr) {
        float inv = inv_img[b * LV + 1 + s0 + rr];
        const float* row = img + ((size_t)b * LV + 1 + s0 + rr) * C;
        for (int c = t; c < C; c += 64) xr[rr][c] = row[c] * inv;
    }
    __syncthreads();
    float acc[8] = {0, 0, 0, 0, 0, 0, 0, 0};
    for (int c4 = 0; c4 < C / 4; ++c4) {
        float g0 = gloT[(c4 * 4 + 0) * NCAP + t];
        float g1 = gloT[(c4 * 4 + 1) * NCAP + t];
        float g2 = gloT[(c4 * 4 + 2) * NCAP + t];
        float g3 = gloT[(c4 * 4 + 3) * NCAP + t];
#pragma unroll
        for (int r = 0; r < 8; ++r) {
            float4 xv = ((const float4*)xr[r])[c4];
            acc[r] += xv.x * g0 + xv.y * g1 + xv.z * g2 + xv.w * g3;
        }
    }
    for (int rr = 0; rr < R; ++rr)
        attn_y[((size_t)b * NSP + s0 + rr) * NCAP + t] = acc[rr];
}

// ---------------------------------------------------------------- per-pair prep (bf16 P; no max-sub: scale-invariant)
__global__ __launch_bounds__(256) void k_prep(const float* __restrict__ attn_x,
                                              const float* __restrict__ attn_y,
                                              const float* __restrict__ WsM,
                                              int* __restrict__ gKeep,
                                              int* __restrict__ gNon,
                                              float* __restrict__ gPnk,
                                              u16* __restrict__ gPb) {
    int lin = blockIdx.x + NCAP * blockIdx.y;
    int b = (lin & 7) * 8 + ((lin >> 3) & 7);
    int i = lin >> 6;
    int t = threadIdx.x;
    int pair = b * NCAP + i;
    __shared__ float scoreS[NSP];
    __shared__ int   keepL[NKEEP];
    __shared__ int   nonL[NKEEP];
    __shared__ float snon[NKEEP];

    if (t < NSP) scoreS[t] = attn_x[b * NSP + t] + attn_y[(size_t)(b * NSP + t) * NCAP + i];
    __syncthreads();
    if (t < NSP) {
        float sv = scoreS[t];
        int r = 0;
        for (int u = 0; u < NSP; ++u) {
            float o = scoreS[u];
            r += (o > sv) || (o == sv && u < t);
        }
        if (r < NKEEP) keepL[r] = t;
        else { nonL[r - NKEEP] = t; snon[r - NKEEP] = sv; }
    }
    __syncthreads();
    if (t < NKEEP) {
        gKeep[pair * NKEEP + t] = keepL[t];
        gNon[pair * NKEEP + t]  = nonL[t];
        gPnk[pair * NKEEP + t]  = expf(snon[t]);   // unnormalized; invE absorbs scale
    }
    u16* Pm = gPb + (size_t)pair * NKEEP * 52;
    for (int f = t; f < NKEEP * KEEPED; f += 256) {
        int j = f / KEEPED, k = f - j * KEEPED;
        Pm[j * 52 + k] = f2bf(expf(WsM[((size_t)b * NSP + keepL[j]) * KEEPED + k]));
    }
}

// ---------------------------------------------------------------- main per-pair kernel: two MFMA GEMMs
__global__ __launch_bounds__(512, 4) void k_main(const int* __restrict__ gKeep,
                                                 const int* __restrict__ gNon,
                                                 const float* __restrict__ gPnk,
                                                 const u16* __restrict__ gPb,
                                                 const u16* __restrict__ imgT,
                                                 const u16* __restrict__ Qbb,
                                                 const float* __restrict__ temp_p,
                                                 float* __restrict__ out) {
    int lin = blockIdx.x + NCAP * blockIdx.y;     // XCD swizzle: lin%8 selects b-octet
    int b = (lin & 7) * 8 + ((lin >> 3) & 7);
    int i = lin >> 6;
    int t = threadIdx.x;
    int pair = b * NCAP + i;
    int lane = t & 63, wu = t >> 6;
    int l15 = lane & 15, quad = lane >> 4;

    __shared__ __align__(16) u16 TnBuf[51 * 520];   // aliases Pf(64x232) then ULDS(96x52 f32)
    __shared__ float rowsq[4][64];
    __shared__ float invn[64];
    __shared__ float colM[51], colZ[51], rowM[32], rowZ[32], redw[8];

    u16*   Pf   = TnBuf;
    float* ULDS = (float*)TnBuf;

    // ---- build Pfull rows 0..50 in LDS (zero + scatter)
    {
        u32* Pfu = (u32*)Pf;
        for (int f = t; f < 51 * 116; f += 512) Pfu[f] = 0;
    }
    __syncthreads();
    {
        const int*   keep = gKeep + pair * NKEEP;
        const int*   nonk = gNon + pair * NKEEP;
        const float* pnk  = gPnk + pair * NKEEP;
        const u16*   Pg   = gPb + (size_t)pair * NKEEP * 52;
        if (t == 0) Pf[0] = 0x3F80;                       // cls one-hot (1.0)
        for (int f = t; f < NKEEP * KEEPED; f += 512) {
            int j = f / KEEPED, k = f - j * KEEPED;
            Pf[(1 + k) * 232 + 1 + keep[j]] = Pg[j * 52 + k];
        }
        if (t < NKEEP) Pf[50 * 232 + 1 + nonk[t]] = f2bf(pnk[t]);
    }
    __syncthreads();

    // ---- phase 1: T(51x512) = Pfull @ imgT ; wave = (mp, nq)
    int mp = wu >> 2, nq = wu & 3;
    const u16* imgTb = imgT + (size_t)b * 512 * 224;
    f32x4 acc[2][8];
#pragma unroll
    for (int a = 0; a < 2; ++a)
#pragma unroll
        for (int n = 0; n < 8; ++n) acc[a][n] = (f32x4){0.f, 0.f, 0.f, 0.f};

    for (int ks = 0; ks < 7; ++ks) {
        bf16x8 A0 = ld_bf8(Pf + (mp * 32 + l15) * 232 + ks * 32 + quad * 8);
        bf16x8 A1 = ld_bf8(Pf + (mp * 32 + 16 + l15) * 232 + ks * 32 + quad * 8);
#pragma unroll
        for (int nn = 0; nn < 8; ++nn) {
            int c = (nq * 8 + nn) * 16 + l15;
            bf16x8 Bf = ld_bf8(imgTb + (size_t)c * 224 + ks * 32 + quad * 8);
            acc[0][nn] = __builtin_amdgcn_mfma_f32_16x16x32_bf16(A0, Bf, acc[0][nn], 0, 0, 0);
            acc[1][nn] = __builtin_amdgcn_mfma_f32_16x16x32_bf16(A1, Bf, acc[1][nn], 0, 0, 0);
        }
    }

    // ---- row sums of squares
#pragma unroll
    for (int a = 0; a < 2; ++a)
#pragma unroll
        for (int r = 0; r < 4; ++r) {
            float s = 0.f;
#pragma unroll
            for (int nn = 0; nn < 8; ++nn) { float v = acc[a][nn][r]; s += v * v; }
            s += __shfl_down(s, 8); s += __shfl_down(s, 4);
            s += __shfl_down(s, 2); s += __shfl_down(s, 1);
            if (l15 == 0) rowsq[nq][mp * 32 + a * 16 + quad * 4 + r] = s;
        }
    __syncthreads();
    if (t < 64) {
        float s = rowsq[0][t] + rowsq[1][t] + rowsq[2][t] + rowsq[3][t];
        invn[t] = 1.f / fmaxf(sqrtf(s), 1e-12f);
    }
    __syncthreads();

    // ---- write normalized Tn bf16 (Pf region dead)
#pragma unroll
    for (int a = 0; a < 2; ++a)
#pragma unroll
        for (int r = 0; r < 4; ++r) {
            int row = mp * 32 + a * 16 + quad * 4 + r;
            if (row < 51) {
                float iv = invn[row];
#pragma unroll
                for (int nn = 0; nn < 8; ++nn)
                    TnBuf[row * 520 + (nq * 8 + nn) * 16 + l15] = f2bf(acc[a][nn][r] * iv);
            }
        }
    __syncthreads();

    // ---- phase 2: U = Qbb @ Tn^T ; 24 tiles, wave owns 3; next-ks A prefetch
    const u16* Qb = Qbb + (size_t)i * 96 * 512;
    int tt0 = 3 * wu;
    f32x4 ua[3];
    int miA[3], rowB[3], niA[3];
#pragma unroll
    for (int e = 0; e < 3; ++e) {
        ua[e] = (f32x4){0.f, 0.f, 0.f, 0.f};
        int tt = tt0 + e;
        miA[e] = tt >> 2; niA[e] = tt & 3;
        int rb = niA[e] * 16 + l15;
        rowB[e] = rb > 50 ? 50 : rb;
    }
    bf16x8 Af[3];
#pragma unroll
    for (int e = 0; e < 3; ++e)
        Af[e] = ld_bf8(Qb + (size_t)(miA[e] * 16 + l15) * 512 + quad * 8);
    for (int ks = 0; ks < 16; ++ks) {
        bf16x8 An[3];
        if (ks < 15) {
#pragma unroll
            for (int e = 0; e < 3; ++e)
                An[e] = ld_bf8(Qb + (size_t)(miA[e] * 16 + l15) * 512 + (ks + 1) * 32 + quad * 8);
        }
#pragma unroll
        for (int e = 0; e < 3; ++e) {
            bf16x8 Bf = ld_bf8(TnBuf + rowB[e] * 520 + ks * 32 + quad * 8);
            ua[e] = __builtin_amdgcn_mfma_f32_16x16x32_bf16(Af[e], Bf, ua[e], 0, 0, 0);
        }
#pragma unroll
        for (int e = 0; e < 3; ++e) Af[e] = An[e];
    }
    __syncthreads();   // Tn reads done before U overwrites

    // ---- write U (96 x 51)
#pragma unroll
    for (int e = 0; e < 3; ++e) {
        int l = niA[e] * 16 + l15;
        if (l < 51) {
            int q0 = miA[e] * 16 + quad * 4;
#pragma unroll
            for (int r = 0; r < 4; ++r) ULDS[(q0 + r) * 52 + l] = ua[e][r];
        }
    }
    __syncthreads();

    // ---- softmax stats
    float invT = 1.f / temp_p[0];
    if (t < 51) {
        float mm = -1e30f;
        for (int u = 0; u < LT; ++u) mm = fmaxf(mm, ULDS[(32 + u) * 52 + t] * invT);
        float z = 0.f;
        for (int u = 0; u < LT; ++u) z += expf(ULDS[(32 + u) * 52 + t] * invT - mm);
        colM[t] = mm; colZ[t] = 1.f / z;
    }
    if (t >= 64 && t < 96) {
        int u = t - 64;
        float mm = -1e30f;
        for (int l = 0; l < 51; ++l) mm = fmaxf(mm, ULDS[(64 + u) * 52 + l] * invT);
        float z = 0.f;
        for (int l = 0; l < 51; ++l) z += expf(ULDS[(64 + u) * 52 + l] * invT - mm);
        rowM[u] = mm; rowZ[u] = 1.f / z;
    }
    __syncthreads();

    // ---- final reduction
    float part = 0.f;
    for (int f = t; f < LT * 51; f += 512) {
        int u = f / 51, l = f - u * 51;
        float u0 = ULDS[u * 52 + l];
        float c2 = (u0 > 0.f) ? u0 : 0.1f * u0;
        float av = expf(ULDS[(32 + u) * 52 + l] * invT - colM[l]) * colZ[l];
        float bv = expf(ULDS[(64 + u) * 52 + l] * invT - rowM[u]) * rowZ[u];
        part += c2 * (av * (1.f / 51.f) + bv * (1.f / 32.f));
    }
    for (int o = 32; o > 0; o >>= 1) part += __shfl_down(part, o);
    if (lane == 0) redw[wu] = part;
    __syncthreads();
    if (t == 0) {
        float s = 0.f;
#pragma unroll
        for (int w2 = 0; w2 < 8; ++w2) s += redw[w2];
        out[b * NCAP + i] = s;
    }
}

extern "C" void kernel_launch(void* const* d_in, const int* in_sizes, int n_in,
                              void* d_out, int out_size, void* d_ws, size_t ws_size,
                              hipStream_t stream) {
    const float* img        = (const float*)d_in[0];
    const float* cap        = (const float*)d_in[1];
    const float* gamw       = (const float*)d_in[3];
    const float* betw       = (const float*)d_in[4];
    const float* w1         = (const float*)d_in[5];
    const float* b1         = (const float*)d_in[6];
    const float* w2         = (const float*)d_in[7];
    const float* b2         = (const float*)d_in[8];
    const float* aggr_scale = (const float*)d_in[9];
    const float* wi2t       = (const float*)d_in[10];
    const float* bi2t       = (const float*)d_in[11];
    const float* wt2i       = (const float*)d_in[12];
    const float* bt2i       = (const float*)d_in[13];
    const float* temp       = (const float*)d_in[14];
    float* out = (float*)d_out;

    float* ws      = (float*)d_ws;
    float* inv_img = ws + OFF_INV;
    float* attn_x  = ws + OFF_ATTNX;
    float* WsM     = ws + OFF_WSMAT;
    u16*   wT      = (u16*)(ws + OFF_WT);
    float* gloT    = ws + OFF_GLOT;
    float* attn_y  = ws + OFF_ATTNY;
    int*   gKeep   = (int*)(ws + OFF_KEEP);
    int*   gNon    = (int*)(ws + OFF_NON);
    float* gPnk    = ws + OFF_PNK;
    u16*   gPb     = (u16*)(ws + OFF_GPB);
    u16*   imgT    = (u16*)(ws + OFF_IMGT);
    u16*   Qbb     = (u16*)(ws + OFF_QBB);

    k_img_norm<<<dim3(B * LV), dim3(64), 0, stream>>>(img, inv_img);
    k_imgt<<<dim3(B, 8), dim3(256), 0, stream>>>(img, imgT);
    k_cap_norm<<<dim3(NCAP, LT), dim3(64), 0, stream>>>(cap, gloT, Qbb);
    k_wt<<<dim3(2, 8), dim3(256), 0, stream>>>(wi2t, wt2i, wT);
    k_qproj_mfma<<<dim3(NCAP), dim3(512), 0, stream>>>(wT, bi2t, bt2i, Qbb);
    k_img_row<<<dim3(B, 25), dim3(256), 0, stream>>>(img, inv_img, gamw, betw, w1, b1, w2, b2,
                                                     aggr_scale, attn_x, WsM);
    k_attn_y<<<dim3(B, 25), dim3(64), 0, stream>>>(img, inv_img, gloT, attn_y);
    k_prep<<<dim3(NCAP, B), dim3(256), 0, stream>>>(attn_x, attn_y, WsM, gKeep, gNon, gPnk, gPb);
    k_main<<<dim3(NCAP, B), dim3(512), 0, stream>>>(gKeep, gNon, gPnk, gPb, imgT, Qbb, temp, out);
}

// Round 8
// 509.757 us; speedup vs baseline: 4.5958x; 1.3762x over previous
//
#include <hip/hip_runtime.h>
#include <math.h>

#define B     64
#define NCAP  64
#define LV    197
#define LT    32
#define C     512
#define NSP   196
#define NKEEP 98
#define HID   102
#define KEEPED 49

// Workspace layout (float element offsets). Total 19,407,680 floats = 77.6 MB.
#define OFF_INV     0                         // B*LV
#define OFF_ATTNX   12608                     // B*NSP
#define OFF_WSMAT   25152                     // B*NSP*KEEPED
#define OFF_WT      639808                    // u16 2*512*512 (bf16 wi2t^T / wt2i^T)
#define OFF_GLOT    1688384                   // C*NCAP
#define OFF_ATTNY   1721152                   // B*NSP*NCAP
#define OFF_KEEP    2523968                   // 4096*98 ints
#define OFF_NON     2925376                   // 4096*98 ints
#define OFF_PNK     3326784                   // 4096*98 floats
#define OFF_GPB     3728192                   // ushort 4096*98*52 (bf16 P, stride 52)
#define OFF_IMGT    14164800                  // ushort 64*512*224 (bf16 img^T, s-padded)
#define OFF_QBB     17834816                  // ushort 64*96*512 (bf16 [capn;qi2t;qt2i])

typedef unsigned int u32;
typedef unsigned short u16;
typedef __bf16 bf16x8 __attribute__((ext_vector_type(8)));
typedef float f32x4 __attribute__((ext_vector_type(4)));
typedef unsigned int uint4v __attribute__((ext_vector_type(4)));

__device__ __forceinline__ u16 f2bf(float f) {
    u32 u = __builtin_bit_cast(u32, f);
    return (u16)((u + 0x7FFFu + ((u >> 16) & 1u)) >> 16);
}
__device__ __forceinline__ bf16x8 ld_bf8(const u16* p) {
    uint4v v = *reinterpret_cast<const uint4v*>(p);
    return __builtin_bit_cast(bf16x8, v);
}

__device__ __forceinline__ float gelu_exact(float x) {
    return 0.5f * x * (1.f + erff(x * 0.70710678118654752f));
}

// ---------------------------------------------------------------- img row norms
__global__ __launch_bounds__(64) void k_img_norm(const float* __restrict__ img,
                                                 float* __restrict__ inv_img) {
    int r = blockIdx.x, t = threadIdx.x;
    const float* row = img + (size_t)r * C;
    float ss = 0.f;
    for (int c = t; c < C; c += 64) { float v = row[c]; ss += v * v; }
    for (int o = 32; o > 0; o >>= 1) ss += __shfl_down(ss, o);
    if (t == 0) inv_img[r] = 1.f / fmaxf(sqrtf(ss), 1e-12f);
}

// ---------------------------------------------------------------- img^T bf16 (s-padded to 224)
__global__ __launch_bounds__(256) void k_imgt(const float* __restrict__ img,
                                              u16* __restrict__ imgT) {
    int b = blockIdx.x, cg = blockIdx.y, t = threadIdx.x;
    __shared__ u16 Tl[64 * 224];
    for (int f = t; f < 64 * 27; f += 256) Tl[(f / 27) * 224 + 197 + (f % 27)] = 0;
    int cc = t & 63;
    for (int sb = t >> 6; sb < 197; sb += 4) {
        float v = img[((size_t)b * LV + sb) * C + cg * 64 + cc];
        Tl[cc * 224 + sb] = f2bf(v);
    }
    __syncthreads();
    const u32* Tu = (const u32*)Tl;
    u32* outp = (u32*)(imgT + ((size_t)b * 512 + cg * 64) * 224);
    for (int f = t; f < 64 * 112; f += 256) outp[f] = Tu[f];
}

// ---------------------------------------------------------------- caption norms (+ Qbb rows 0..31, gloT)
__global__ __launch_bounds__(64) void k_cap_norm(const float* __restrict__ cap,
                                                 float* __restrict__ gloT,
                                                 u16* __restrict__ Qbb) {
    int i = blockIdx.x, tt = blockIdx.y, t = threadIdx.x;
    const float* row = cap + ((size_t)i * LT + tt) * C;
    float v[8]; float ss = 0.f;
#pragma unroll
    for (int q = 0; q < 8; ++q) { v[q] = row[t + 64 * q]; ss += v[q] * v[q]; }
    for (int o = 32; o > 0; o >>= 1) ss += __shfl_down(ss, o);
    ss = __shfl(ss, 0);
    float inv = 1.f / fmaxf(sqrtf(ss), 1e-12f);
    u16* qrow = Qbb + ((size_t)i * 96 + tt) * C;
#pragma unroll
    for (int q = 0; q < 8; ++q) {
        float n = v[q] * inv;
        qrow[t + 64 * q] = f2bf(n);
        if (tt == 0) gloT[(t + 64 * q) * NCAP + i] = n;
    }
}

// ---------------------------------------------------------------- transpose wi2t/wt2i -> bf16 [j][c]
__global__ __launch_bounds__(256) void k_wt(const float* __restrict__ wi2t,
                                            const float* __restrict__ wt2i,
                                            u16* __restrict__ wT) {
    int mat = blockIdx.x, jg = blockIdx.y, t = threadIdx.x;
    const float* W = mat ? wt2i : wi2t;
    __shared__ u16 tile[64][65];
    for (int cg = 0; cg < 8; ++cg) {
        for (int f = t; f < 4096; f += 256) {
            int cc = f >> 6, jj = f & 63;
            tile[jj][cc] = f2bf(W[(size_t)(cg * 64 + cc) * 512 + jg * 64 + jj]);
        }
        __syncthreads();
        for (int f = t; f < 4096; f += 256) {
            int jj = f >> 6, cc = f & 63;
            wT[((size_t)mat * 512 + jg * 64 + jj) * 512 + cg * 64 + cc] = tile[jj][cc];
        }
        __syncthreads();
    }
}

// ---------------------------------------------------------------- qi2t/qt2i via MFMA -> Qbb rows 32..95
// grid (i, part 0..3); wave: mat=wu>>2, mi=(wu>>1)&1, nh=wu&1; 4 N-tiles per wave.
__global__ __launch_bounds__(512) void k_qproj_mfma(const u16* __restrict__ wT,
                                                    const float* __restrict__ bi2t,
                                                    const float* __restrict__ bt2i,
                                                    u16* __restrict__ Qbb) {
    int i = blockIdx.x, p = blockIdx.y, t = threadIdx.x;
    int lane = t & 63, wu = t >> 6;
    int l15 = lane & 15, quad = lane >> 4;
    int mat = wu >> 2;
    int mi  = (wu >> 1) & 1;
    int nh  = wu & 1;
    int ni0 = p * 8 + nh * 4;
    const u16* Arow = Qbb + ((size_t)i * 96 + mi * 16 + l15) * 512;
    const u16* Wm   = wT + (size_t)mat * 512 * 512;
    f32x4 acc[4];
#pragma unroll
    for (int n = 0; n < 4; ++n) acc[n] = (f32x4){0.f, 0.f, 0.f, 0.f};
    for (int ks = 0; ks < 16; ++ks) {
        bf16x8 A = ld_bf8(Arow + ks * 32 + quad * 8);
#pragma unroll
        for (int n = 0; n < 4; ++n) {
            bf16x8 Bf = ld_bf8(Wm + (size_t)((ni0 + n) * 16 + l15) * 512 + ks * 32 + quad * 8);
            acc[n] = __builtin_amdgcn_mfma_f32_16x16x32_bf16(A, Bf, acc[n], 0, 0, 0);
        }
    }
    const float* bias = mat ? bt2i : bi2t;
#pragma unroll
    for (int n = 0; n < 4; ++n) {
        int j = (ni0 + n) * 16 + l15;
        float bj = bias[j];
        int row0 = i * 96 + 32 + mat * 32 + mi * 16 + quad * 4;
#pragma unroll
        for (int r = 0; r < 4; ++r)
            Qbb[(size_t)(row0 + r) * 512 + j] = f2bf(acc[n][r] + bj);
    }
}

// ---------------------------------------------------------------- LN -> w1 -> gelu -> w2 + attn_x
__global__ __launch_bounds__(256) void k_img_row(const float* __restrict__ img,
                                                 const float* __restrict__ inv_img,
                                                 const float* __restrict__ gamw,
                                                 const float* __restrict__ betw,
                                                 const float* __restrict__ w1,
                                                 const float* __restrict__ b1,
                                                 const float* __restrict__ w2,
                                                 const float* __restrict__ b2,
                                                 const float* __restrict__ scale_p,
                                                 float* __restrict__ attn_x,
                                                 float* __restrict__ WsM) {
    int b = blockIdx.x, s0 = blockIdx.y * 8, t = threadIdx.x;
    int R = NSP - s0; if (R > 8) R = 8;
    __shared__ __align__(16) float lnr[8][C];
    __shared__ float HH[8][HID + 2];
    __shared__ float redm[8][3];

    int g = t >> 5, lane = t & 31;
    if (g < R) {
        const float* row = img + ((size_t)b * LV + 1 + s0 + g) * C;
        const float* cls = img + (size_t)b * LV * C;
        float sm = 0.f, ss = 0.f, dd = 0.f;
        for (int c = lane; c < C; c += 32) {
            float v = row[c];
            sm += v; ss += v * v; dd += v * cls[c];
            lnr[g][c] = v;
        }
        for (int o = 16; o > 0; o >>= 1) {
            sm += __shfl_down(sm, o, 32);
            ss += __shfl_down(ss, o, 32);
            dd += __shfl_down(dd, o, 32);
        }
        if (lane == 0) { redm[g][0] = sm; redm[g][1] = ss; redm[g][2] = dd; }
    }
    __syncthreads();
    for (int f = t; f < R * C; f += 256) {
        int rr = f >> 9, c = f & 511;
        float mean = redm[rr][0] * (1.f / C);
        float var  = redm[rr][1] * (1.f / C) - mean * mean;
        float rstd = 1.f / sqrtf(var + 1e-5f);
        lnr[rr][c] = (lnr[rr][c] - mean) * rstd * gamw[c] + betw[c];
    }
    if (t < R) {
        float inv0 = inv_img[b * LV];
        float invs = inv_img[b * LV + 1 + s0 + t];
        attn_x[b * NSP + s0 + t] = redm[t][2] * inv0 * invs;
    }
    __syncthreads();
    // h = gelu(ln @ w1 + b1): 204 threads, each 4 rows
    if (t < 204) {
        int rr2 = (t >= 102) ? 1 : 0;
        int j = t - 102 * rr2;
        float a4[4];
#pragma unroll
        for (int r = 0; r < 4; ++r) a4[r] = b1[j];
        for (int c = 0; c < C; ++c) {
            float wv = w1[c * HID + j];
#pragma unroll
            for (int r = 0; r < 4; ++r) a4[r] += lnr[rr2 * 4 + r][c] * wv;
        }
#pragma unroll
        for (int r = 0; r < 4; ++r) {
            int rw = rr2 * 4 + r;
            if (rw < R) HH[rw][j] = gelu_exact(a4[r]);
        }
    }
    __syncthreads();
    float scale = scale_p[0];
    if (t < 196) {
        int k = t % 49, rh = t / 49;
        for (int rr = rh; rr < 8; rr += 4) {
            if (rr < R) {
                float a = b2[k];
                for (int h = 0; h < HID; ++h) a += HH[rr][h] * w2[h * 49 + k];
                WsM[((size_t)b * NSP + s0 + rr) * 49 + k] = a * scale;
            }
        }
    }
}

// ---------------------------------------------------------------- attn_y (fp32 — keep score precision)
__global__ __launch_bounds__(64) void k_attn_y(const float* __restrict__ img,
                                               const float* __restrict__ inv_img,
                                               const float* __restrict__ gloT,
                                               float* __restrict__ attn_y) {
    int b = blockIdx.x, s0 = blockIdx.y * 8, t = threadIdx.x;
    int R = NSP - s0; if (R > 8) R = 8;
    __shared__ __align__(16) float xr[8][C];
    for (int rr = 0; rr < R; ++rr) {
        float inv = inv_img[b * LV + 1 + s0 + rr];
        const float* row = img + ((size_t)b * LV + 1 + s0 + rr) * C;
        for (int c = t; c < C; c += 64) xr[rr][c] = row[c] * inv;
    }
    __syncthreads();
    float acc[8] = {0, 0, 0, 0, 0, 0, 0, 0};
    for (int c4 = 0; c4 < C / 4; ++c4) {
        float g0 = gloT[(c4 * 4 + 0) * NCAP + t];
        float g1 = gloT[(c4 * 4 + 1) * NCAP + t];
        float g2 = gloT[(c4 * 4 + 2) * NCAP + t];
        float g3 = gloT[(c4 * 4 + 3) * NCAP + t];
#pragma unroll
        for (int r = 0; r < 8; ++r) {
            float4 xv = ((const float4*)xr[r])[c4];
            acc[r] += xv.x * g0 + xv.y * g1 + xv.z * g2 + xv.w * g3;
        }
    }
    for (int rr = 0; rr < R; ++rr)
        attn_y[((size_t)b * NSP + s0 + rr) * NCAP + t] = acc[rr];
}

// ---------------------------------------------------------------- per-pair prep (bf16 P; no max-sub: scale-invariant)
__global__ __launch_bounds__(256) void k_prep(const float* __restrict__ attn_x,
                                              const float* __restrict__ attn_y,
                                              const float* __restrict__ WsM,
                                              int* __restrict__ gKeep,
                                              int* __restrict__ gNon,
                                              float* __restrict__ gPnk,
                                              u16* __restrict__ gPb) {
    int lin = blockIdx.x + NCAP * blockIdx.y;
    int b = (lin & 7) * 8 + ((lin >> 3) & 7);
    int i = lin >> 6;
    int t = threadIdx.x;
    int pair = b * NCAP + i;
    __shared__ float scoreS[NSP];
    __shared__ int   keepL[NKEEP];
    __shared__ int   nonL[NKEEP];
    __shared__ float snon[NKEEP];

    if (t < NSP) scoreS[t] = attn_x[b * NSP + t] + attn_y[(size_t)(b * NSP + t) * NCAP + i];
    __syncthreads();
    if (t < NSP) {
        float sv = scoreS[t];
        int r = 0;
        for (int u = 0; u < NSP; ++u) {
            float o = scoreS[u];
            r += (o > sv) || (o == sv && u < t);
        }
        if (r < NKEEP) keepL[r] = t;
        else { nonL[r - NKEEP] = t; snon[r - NKEEP] = sv; }
    }
    __syncthreads();
    if (t < NKEEP) {
        gKeep[pair * NKEEP + t] = keepL[t];
        gNon[pair * NKEEP + t]  = nonL[t];
        gPnk[pair * NKEEP + t]  = expf(snon[t]);   // unnormalized; renorm absorbs scale
    }
    u16* Pm = gPb + (size_t)pair * NKEEP * 52;
    for (int f = t; f < NKEEP * KEEPED; f += 256) {
        int j = f / KEEPED, k = f - j * KEEPED;
        Pm[j * 52 + k] = f2bf(expf(WsM[((size_t)b * NSP + keepL[j]) * KEEPED + k]));
    }
}

// ---------------------------------------------------------------- main per-pair kernel: two MFMA GEMMs
// Phase 1: wave w owns c-range [64w,64w+64) x all 4 M-tiles (each B-frag loaded once per block).
// Phase 2: waves 0-5 own one mi (ni 0-2); waves 6-7 cover ni=3 column.
__global__ __launch_bounds__(512, 4) void k_main(const int* __restrict__ gKeep,
                                                 const int* __restrict__ gNon,
                                                 const float* __restrict__ gPnk,
                                                 const u16* __restrict__ gPb,
                                                 const u16* __restrict__ imgT,
                                                 const u16* __restrict__ Qbb,
                                                 const float* __restrict__ temp_p,
                                                 float* __restrict__ out) {
    int lin = blockIdx.x + NCAP * blockIdx.y;     // XCD swizzle: lin%8 selects b-octet
    int b = (lin & 7) * 8 + ((lin >> 3) & 7);
    int i = lin >> 6;
    int t = threadIdx.x;
    int pair = b * NCAP + i;
    int lane = t & 63, wu = t >> 6;
    int l15 = lane & 15, quad = lane >> 4;

    __shared__ __align__(16) u16 TnBuf[51 * 520];   // aliases Pf(64x232) then ULDS(96x52 f32)
    __shared__ float rowsq[8][64];
    __shared__ float invn[64];
    __shared__ float colM[51], colZ[51], rowM[32], rowZ[32], redw[8];

    u16*   Pf   = TnBuf;
    float* ULDS = (float*)TnBuf;

    // ---- build Pfull rows 0..50 in LDS (zero + scatter)
    {
        u32* Pfu = (u32*)Pf;
        for (int f = t; f < 51 * 116; f += 512) Pfu[f] = 0;
    }
    __syncthreads();
    {
        const int*   keep = gKeep + pair * NKEEP;
        const int*   nonk = gNon + pair * NKEEP;
        const float* pnk  = gPnk + pair * NKEEP;
        const u16*   Pg   = gPb + (size_t)pair * NKEEP * 52;
        if (t == 0) Pf[0] = 0x3F80;                       // cls one-hot (1.0)
        for (int f = t; f < NKEEP * KEEPED; f += 512) {
            int j = f / KEEPED, k = f - j * KEEPED;
            Pf[(1 + k) * 232 + 1 + keep[j]] = Pg[j * 52 + k];
        }
        if (t < NKEEP) Pf[50 * 232 + 1 + nonk[t]] = f2bf(pnk[t]);
    }
    __syncthreads();

    // ---- phase 1: T(51x512) = Pfull @ imgT
    const u16* imgTb = imgT + (size_t)b * 512 * 224;
    f32x4 acc[4][4];
#pragma unroll
    for (int mi = 0; mi < 4; ++mi)
#pragma unroll
        for (int nj = 0; nj < 4; ++nj) acc[mi][nj] = (f32x4){0.f, 0.f, 0.f, 0.f};

    for (int ks = 0; ks < 7; ++ks) {
        bf16x8 Afr[4];
#pragma unroll
        for (int mi = 0; mi < 4; ++mi)
            Afr[mi] = ld_bf8(Pf + (mi * 16 + l15) * 232 + ks * 32 + quad * 8);
#pragma unroll
        for (int nj = 0; nj < 4; ++nj) {
            int c = (wu * 4 + nj) * 16 + l15;
            bf16x8 Bf = ld_bf8(imgTb + (size_t)c * 224 + ks * 32 + quad * 8);
#pragma unroll
            for (int mi = 0; mi < 4; ++mi)
                acc[mi][nj] = __builtin_amdgcn_mfma_f32_16x16x32_bf16(Afr[mi], Bf, acc[mi][nj], 0, 0, 0);
        }
    }

    // ---- row sums of squares (per-wave partial over its 64 c)
#pragma unroll
    for (int mi = 0; mi < 4; ++mi)
#pragma unroll
        for (int r = 0; r < 4; ++r) {
            float s = acc[mi][0][r] * acc[mi][0][r] + acc[mi][1][r] * acc[mi][1][r]
                    + acc[mi][2][r] * acc[mi][2][r] + acc[mi][3][r] * acc[mi][3][r];
            s += __shfl_down(s, 8); s += __shfl_down(s, 4);
            s += __shfl_down(s, 2); s += __shfl_down(s, 1);
            if (l15 == 0) rowsq[wu][mi * 16 + quad * 4 + r] = s;
        }
    __syncthreads();
    if (t < 64) {
        float s = 0.f;
#pragma unroll
        for (int w2 = 0; w2 < 8; ++w2) s += rowsq[w2][t];
        invn[t] = 1.f / fmaxf(sqrtf(s), 1e-12f);
    }
    __syncthreads();

    // ---- write normalized Tn bf16 (Pf region dead)
#pragma unroll
    for (int mi = 0; mi < 4; ++mi)
#pragma unroll
        for (int r = 0; r < 4; ++r) {
            int row = mi * 16 + quad * 4 + r;
            if (row < 51) {
                float iv = invn[row];
#pragma unroll
                for (int nj = 0; nj < 4; ++nj)
                    TnBuf[row * 520 + (wu * 4 + nj) * 16 + l15] = f2bf(acc[mi][nj][r] * iv);
            }
        }
    __syncthreads();

    // ---- phase 2: U = Qbb @ Tn^T
    const u16* Qb = Qbb + (size_t)i * 96 * 512;
    f32x4 ua[3];
#pragma unroll
    for (int e = 0; e < 3; ++e) ua[e] = (f32x4){0.f, 0.f, 0.f, 0.f};

    if (wu < 6) {
        int mi = wu;
        const u16* Ar = Qb + (size_t)(mi * 16 + l15) * 512;
        bf16x8 Af = ld_bf8(Ar + quad * 8);
        for (int ks = 0; ks < 16; ++ks) {
            bf16x8 An;
            if (ks < 15) An = ld_bf8(Ar + (ks + 1) * 32 + quad * 8);
#pragma unroll
            for (int e = 0; e < 3; ++e) {
                bf16x8 Bf = ld_bf8(TnBuf + (e * 16 + l15) * 520 + ks * 32 + quad * 8);
                ua[e] = __builtin_amdgcn_mfma_f32_16x16x32_bf16(Af, Bf, ua[e], 0, 0, 0);
            }
            Af = An;
        }
    } else {
        int w2 = wu - 6;
        int rowB = 48 + l15; if (rowB > 50) rowB = 50;
        const u16* Ar0 = Qb + (size_t)((3 * w2 + 0) * 16 + l15) * 512;
        const u16* Ar1 = Qb + (size_t)((3 * w2 + 1) * 16 + l15) * 512;
        const u16* Ar2 = Qb + (size_t)((3 * w2 + 2) * 16 + l15) * 512;
        bf16x8 Af0 = ld_bf8(Ar0 + quad * 8);
        bf16x8 Af1 = ld_bf8(Ar1 + quad * 8);
        bf16x8 Af2 = ld_bf8(Ar2 + quad * 8);
        for (int ks = 0; ks < 16; ++ks) {
            bf16x8 An0, An1, An2;
            if (ks < 15) {
                An0 = ld_bf8(Ar0 + (ks + 1) * 32 + quad * 8);
                An1 = ld_bf8(Ar1 + (ks + 1) * 32 + quad * 8);
                An2 = ld_bf8(Ar2 + (ks + 1) * 32 + quad * 8);
            }
            bf16x8 Bf = ld_bf8(TnBuf + rowB * 520 + ks * 32 + quad * 8);
            ua[0] = __builtin_amdgcn_mfma_f32_16x16x32_bf16(Af0, Bf, ua[0], 0, 0, 0);
            ua[1] = __builtin_amdgcn_mfma_f32_16x16x32_bf16(Af1, Bf, ua[1], 0, 0, 0);
            ua[2] = __builtin_amdgcn_mfma_f32_16x16x32_bf16(Af2, Bf, ua[2], 0, 0, 0);
            Af0 = An0; Af1 = An1; Af2 = An2;
        }
    }
    __syncthreads();   // Tn reads done before U overwrites

    // ---- write U (96 x 51)
    if (wu < 6) {
#pragma unroll
        for (int e = 0; e < 3; ++e) {
            int l = e * 16 + l15;                 // < 48
            int q0 = wu * 16 + quad * 4;
#pragma unroll
            for (int r = 0; r < 4; ++r) ULDS[(q0 + r) * 52 + l] = ua[e][r];
        }
    } else {
        int l = 48 + l15;
        if (l < 51) {
            int w2 = wu - 6;
#pragma unroll
            for (int e = 0; e < 3; ++e) {
                int q0 = (3 * w2 + e) * 16 + quad * 4;
#pragma unroll
                for (int r = 0; r < 4; ++r) ULDS[(q0 + r) * 52 + l] = ua[e][r];
            }
        }
    }
    __syncthreads();

    // ---- softmax stats
    float invT = 1.f / temp_p[0];
    if (t < 51) {
        float mm = -1e30f;
        for (int u = 0; u < LT; ++u) mm = fmaxf(mm, ULDS[(32 + u) * 52 + t] * invT);
        float z = 0.f;
        for (int u = 0; u < LT; ++u) z += expf(ULDS[(32 + u) * 52 + t] * invT - mm);
        colM[t] = mm; colZ[t] = 1.f / z;
    }
    if (t >= 64 && t < 96) {
        int u = t - 64;
        float mm = -1e30f;
        for (int l = 0; l < 51; ++l) mm = fmaxf(mm, ULDS[(64 + u) * 52 + l] * invT);
        float z = 0.f;
        for (int l = 0; l < 51; ++l) z += expf(ULDS[(64 + u) * 52 + l] * invT - mm);
        rowM[u] = mm; rowZ[u] = 1.f / z;
    }
    __syncthreads();

    // ---- final reduction
    float part = 0.f;
    for (int f = t; f < LT * 51; f += 512) {
        int u = f / 51, l = f - u * 51;
        float u0 = ULDS[u * 52 + l];
        float c2 = (u0 > 0.f) ? u0 : 0.1f * u0;
        float av = expf(ULDS[(32 + u) * 52 + l] * invT - colM[l]) * colZ[l];
        float bv = expf(ULDS[(64 + u) * 52 + l] * invT - rowM[u]) * rowZ[u];
        part += c2 * (av * (1.f / 51.f) + bv * (1.f / 32.f));
    }
    for (int o = 32; o > 0; o >>= 1) part += __shfl_down(part, o);
    if (lane == 0) redw[wu] = part;
    __syncthreads();
    if (t == 0) {
        float s = 0.f;
#pragma unroll
        for (int w2 = 0; w2 < 8; ++w2) s += redw[w2];
        out[b * NCAP + i] = s;
    }
}

extern "C" void kernel_launch(void* const* d_in, const int* in_sizes, int n_in,
                              void* d_out, int out_size, void* d_ws, size_t ws_size,
                              hipStream_t stream) {
    const float* img        = (const float*)d_in[0];
    const float* cap        = (const float*)d_in[1];
    const float* gamw       = (const float*)d_in[3];
    const float* betw       = (const float*)d_in[4];
    const float* w1         = (const float*)d_in[5];
    const float* b1         = (const float*)d_in[6];
    const float* w2         = (const float*)d_in[7];
    const float* b2         = (const float*)d_in[8];
    const float* aggr_scale = (const float*)d_in[9];
    const float* wi2t       = (const float*)d_in[10];
    const float* bi2t       = (const float*)d_in[11];
    const float* wt2i       = (const float*)d_in[12];
    const float* bt2i       = (const float*)d_in[13];
    const float* temp       = (const float*)d_in[14];
    float* out = (float*)d_out;

    float* ws      = (float*)d_ws;
    float* inv_img = ws + OFF_INV;
    float* attn_x  = ws + OFF_ATTNX;
    float* WsM     = ws + OFF_WSMAT;
    u16*   wT      = (u16*)(ws + OFF_WT);
    float* gloT    = ws + OFF_GLOT;
    float* attn_y  = ws + OFF_ATTNY;
    int*   gKeep   = (int*)(ws + OFF_KEEP);
    int*   gNon    = (int*)(ws + OFF_NON);
    float* gPnk    = ws + OFF_PNK;
    u16*   gPb     = (u16*)(ws + OFF_GPB);
    u16*   imgT    = (u16*)(ws + OFF_IMGT);
    u16*   Qbb     = (u16*)(ws + OFF_QBB);

    k_img_norm<<<dim3(B * LV), dim3(64), 0, stream>>>(img, inv_img);
    k_imgt<<<dim3(B, 8), dim3(256), 0, stream>>>(img, imgT);
    k_cap_norm<<<dim3(NCAP, LT), dim3(64), 0, stream>>>(cap, gloT, Qbb);
    k_wt<<<dim3(2, 8), dim3(256), 0, stream>>>(wi2t, wt2i, wT);
    k_qproj_mfma<<<dim3(NCAP, 4), dim3(512), 0, stream>>>(wT, bi2t, bt2i, Qbb);
    k_img_row<<<dim3(B, 25), dim3(256), 0, stream>>>(img, inv_img, gamw, betw, w1, b1, w2, b2,
                                                     aggr_scale, attn_x, WsM);
    k_attn_y<<<dim3(B, 25), dim3(64), 0, stream>>>(img, inv_img, gloT, attn_y);
    k_prep<<<dim3(NCAP, B), dim3(256), 0, stream>>>(attn_x, attn_y, WsM, gKeep, gNon, gPnk, gPb);
    k_main<<<dim3(NCAP, B), dim3(512), 0, stream>>>(gKeep, gNon, gPnk, gPb, imgT, Qbb, temp, out);
}

// Round 9
// 499.926 us; speedup vs baseline: 4.6861x; 1.0197x over previous
//
#include <hip/hip_runtime.h>
#include <math.h>

#define B     64
#define NCAP  64
#define LV    197
#define LT    32
#define C     512
#define NSP   196
#define NKEEP 98
#define HID   102
#define KEEPED 49

// Workspace layout (float element offsets). Total 19,407,680 floats = 77.6 MB (proven OK).
#define OFF_INV     0                         // B*LV
#define OFF_ATTNX   12608                     // B*NSP
#define OFF_WSMAT   25152                     // B*NSP*KEEPED
#define OFF_WT      639808                    // u16 2*512*512 (bf16 wi2t^T / wt2i^T)
#define OFF_GLOT    1688384                   // C*NCAP
#define OFF_ATTNYT  1721152                   // 4096*196 floats (transposed [b][i][s])
#define OFF_IMGT    14164800                  // u16 64*512*224 (bf16 img^T, s-padded)
#define OFF_QBB     17834816                  // u16 64*96*512 (bf16 [capn;qi2t;qt2i])

typedef unsigned int u32;
typedef unsigned short u16;
typedef __bf16 bf16x8 __attribute__((ext_vector_type(8)));
typedef float f32x4 __attribute__((ext_vector_type(4)));
typedef unsigned int uint4v __attribute__((ext_vector_type(4)));

__device__ __forceinline__ u16 f2bf(float f) {
    u32 u = __builtin_bit_cast(u32, f);
    return (u16)((u + 0x7FFFu + ((u >> 16) & 1u)) >> 16);
}
__device__ __forceinline__ bf16x8 ld_bf8(const u16* p) {
    uint4v v = *reinterpret_cast<const uint4v*>(p);
    return __builtin_bit_cast(bf16x8, v);
}

__device__ __forceinline__ float gelu_exact(float x) {
    return 0.5f * x * (1.f + erff(x * 0.70710678118654752f));
}

// ---------------------------------------------------------------- img row norms
__global__ __launch_bounds__(64) void k_img_norm(const float* __restrict__ img,
                                                 float* __restrict__ inv_img) {
    int r = blockIdx.x, t = threadIdx.x;
    const float* row = img + (size_t)r * C;
    float ss = 0.f;
    for (int c = t; c < C; c += 64) { float v = row[c]; ss += v * v; }
    for (int o = 32; o > 0; o >>= 1) ss += __shfl_down(ss, o);
    if (t == 0) inv_img[r] = 1.f / fmaxf(sqrtf(ss), 1e-12f);
}

// ---------------------------------------------------------------- img^T bf16 (s-padded to 224)
__global__ __launch_bounds__(256) void k_imgt(const float* __restrict__ img,
                                              u16* __restrict__ imgT) {
    int b = blockIdx.x, cg = blockIdx.y, t = threadIdx.x;
    __shared__ u16 Tl[64 * 224];
    for (int f = t; f < 64 * 27; f += 256) Tl[(f / 27) * 224 + 197 + (f % 27)] = 0;
    int cc = t & 63;
    for (int sb = t >> 6; sb < 197; sb += 4) {
        float v = img[((size_t)b * LV + sb) * C + cg * 64 + cc];
        Tl[cc * 224 + sb] = f2bf(v);
    }
    __syncthreads();
    const u32* Tu = (const u32*)Tl;
    u32* outp = (u32*)(imgT + ((size_t)b * 512 + cg * 64) * 224);
    for (int f = t; f < 64 * 112; f += 256) outp[f] = Tu[f];
}

// ---------------------------------------------------------------- caption norms (+ Qbb rows 0..31, gloT)
__global__ __launch_bounds__(64) void k_cap_norm(const float* __restrict__ cap,
                                                 float* __restrict__ gloT,
                                                 u16* __restrict__ Qbb) {
    int i = blockIdx.x, tt = blockIdx.y, t = threadIdx.x;
    const float* row = cap + ((size_t)i * LT + tt) * C;
    float v[8]; float ss = 0.f;
#pragma unroll
    for (int q = 0; q < 8; ++q) { v[q] = row[t + 64 * q]; ss += v[q] * v[q]; }
    for (int o = 32; o > 0; o >>= 1) ss += __shfl_down(ss, o);
    ss = __shfl(ss, 0);
    float inv = 1.f / fmaxf(sqrtf(ss), 1e-12f);
    u16* qrow = Qbb + ((size_t)i * 96 + tt) * C;
#pragma unroll
    for (int q = 0; q < 8; ++q) {
        float n = v[q] * inv;
        qrow[t + 64 * q] = f2bf(n);
        if (tt == 0) gloT[(t + 64 * q) * NCAP + i] = n;
    }
}

// ---------------------------------------------------------------- transpose wi2t/wt2i -> bf16 [j][c]
__global__ __launch_bounds__(256) void k_wt(const float* __restrict__ wi2t,
                                            const float* __restrict__ wt2i,
                                            u16* __restrict__ wT) {
    int mat = blockIdx.x, jg = blockIdx.y, t = threadIdx.x;
    const float* W = mat ? wt2i : wi2t;
    __shared__ u16 tile[64][65];
    for (int cg = 0; cg < 8; ++cg) {
        for (int f = t; f < 4096; f += 256) {
            int cc = f >> 6, jj = f & 63;
            tile[jj][cc] = f2bf(W[(size_t)(cg * 64 + cc) * 512 + jg * 64 + jj]);
        }
        __syncthreads();
        for (int f = t; f < 4096; f += 256) {
            int jj = f >> 6, cc = f & 63;
            wT[((size_t)mat * 512 + jg * 64 + jj) * 512 + cg * 64 + cc] = tile[jj][cc];
        }
        __syncthreads();
    }
}

// ---------------------------------------------------------------- qi2t/qt2i via MFMA (A/B prefetch)
__global__ __launch_bounds__(512) void k_qproj_mfma(const u16* __restrict__ wT,
                                                    const float* __restrict__ bi2t,
                                                    const float* __restrict__ bt2i,
                                                    u16* __restrict__ Qbb) {
    int i = blockIdx.x, p = blockIdx.y, t = threadIdx.x;
    int lane = t & 63, wu = t >> 6;
    int l15 = lane & 15, quad = lane >> 4;
    int mat = wu >> 2;
    int mi  = (wu >> 1) & 1;
    int nh  = wu & 1;
    int ni0 = p * 8 + nh * 4;
    const u16* Arow = Qbb + ((size_t)i * 96 + mi * 16 + l15) * 512;
    const u16* Wm   = wT + (size_t)mat * 512 * 512;
    f32x4 acc[4];
#pragma unroll
    for (int n = 0; n < 4; ++n) acc[n] = (f32x4){0.f, 0.f, 0.f, 0.f};
    bf16x8 A = ld_bf8(Arow + quad * 8);
    bf16x8 Bf[4];
#pragma unroll
    for (int n = 0; n < 4; ++n)
        Bf[n] = ld_bf8(Wm + (size_t)((ni0 + n) * 16 + l15) * 512 + quad * 8);
    for (int ks = 0; ks < 16; ++ks) {
        bf16x8 An; bf16x8 Bn[4];
        if (ks < 15) {
            An = ld_bf8(Arow + (ks + 1) * 32 + quad * 8);
#pragma unroll
            for (int n = 0; n < 4; ++n)
                Bn[n] = ld_bf8(Wm + (size_t)((ni0 + n) * 16 + l15) * 512 + (ks + 1) * 32 + quad * 8);
        }
#pragma unroll
        for (int n = 0; n < 4; ++n)
            acc[n] = __builtin_amdgcn_mfma_f32_16x16x32_bf16(A, Bf[n], acc[n], 0, 0, 0);
        A = An;
#pragma unroll
        for (int n = 0; n < 4; ++n) Bf[n] = Bn[n];
    }
    const float* bias = mat ? bt2i : bi2t;
#pragma unroll
    for (int n = 0; n < 4; ++n) {
        int j = (ni0 + n) * 16 + l15;
        float bj = bias[j];
        int row0 = i * 96 + 32 + mat * 32 + mi * 16 + quad * 4;
#pragma unroll
        for (int r = 0; r < 4; ++r)
            Qbb[(size_t)(row0 + r) * 512 + j] = f2bf(acc[n][r] + bj);
    }
}

// ---------------------------------------------------------------- LN -> w1 -> gelu -> w2 + attn_x (4 rows/block)
__global__ __launch_bounds__(256) void k_img_row(const float* __restrict__ img,
                                                 const float* __restrict__ inv_img,
                                                 const float* __restrict__ gamw,
                                                 const float* __restrict__ betw,
                                                 const float* __restrict__ w1,
                                                 const float* __restrict__ b1,
                                                 const float* __restrict__ w2,
                                                 const float* __restrict__ b2,
                                                 const float* __restrict__ scale_p,
                                                 float* __restrict__ attn_x,
                                                 float* __restrict__ WsM) {
    int b = blockIdx.x, s0 = blockIdx.y * 4, t = threadIdx.x;
    __shared__ __align__(16) float lnr[4][C];
    __shared__ float HH[4][HID + 2];
    __shared__ float redm[4][3];

    int g = t >> 6, lane = t & 63;
    {
        const float* row = img + ((size_t)b * LV + 1 + s0 + g) * C;
        const float* cls = img + (size_t)b * LV * C;
        float sm = 0.f, ss = 0.f, dd = 0.f;
        for (int c = lane; c < C; c += 64) {
            float v = row[c];
            sm += v; ss += v * v; dd += v * cls[c];
            lnr[g][c] = v;
        }
        for (int o = 32; o > 0; o >>= 1) {
            sm += __shfl_down(sm, o);
            ss += __shfl_down(ss, o);
            dd += __shfl_down(dd, o);
        }
        if (lane == 0) { redm[g][0] = sm; redm[g][1] = ss; redm[g][2] = dd; }
    }
    __syncthreads();
    for (int f = t; f < 4 * C; f += 256) {
        int rr = f >> 9, c = f & 511;
        float mean = redm[rr][0] * (1.f / C);
        float var  = redm[rr][1] * (1.f / C) - mean * mean;
        float rstd = 1.f / sqrtf(var + 1e-5f);
        lnr[rr][c] = (lnr[rr][c] - mean) * rstd * gamw[c] + betw[c];
    }
    if (t < 4) {
        float inv0 = inv_img[b * LV];
        float invs = inv_img[b * LV + 1 + s0 + t];
        attn_x[b * NSP + s0 + t] = redm[t][2] * inv0 * invs;
    }
    __syncthreads();
    // h = gelu(ln @ w1 + b1): 204 threads, each 2 rows
    if (t < 204) {
        int rr2 = (t >= 102) ? 1 : 0;
        int j = t - 102 * rr2;
        float a2[2];
        a2[0] = b1[j]; a2[1] = b1[j];
        for (int c = 0; c < C; ++c) {
            float wv = w1[c * HID + j];
            a2[0] += lnr[rr2 * 2 + 0][c] * wv;
            a2[1] += lnr[rr2 * 2 + 1][c] * wv;
        }
        HH[rr2 * 2 + 0][j] = gelu_exact(a2[0]);
        HH[rr2 * 2 + 1][j] = gelu_exact(a2[1]);
    }
    __syncthreads();
    float scale = scale_p[0];
    if (t < 196) {
        int k = t % 49, rh = t / 49;
        float a = b2[k];
        for (int h = 0; h < HID; ++h) a += HH[rh][h] * w2[h * 49 + k];
        WsM[((size_t)b * NSP + s0 + rh) * 49 + k] = a * scale;
    }
}

// ---------------------------------------------------------------- attn_y transposed: [b][i][s]; 256 thr
__global__ __launch_bounds__(256) void k_attn_y(const float* __restrict__ img,
                                                const float* __restrict__ inv_img,
                                                const float* __restrict__ gloT,
                                                float* __restrict__ attn_yT) {
    int b = blockIdx.x, s0 = blockIdx.y * 8, t = threadIdx.x;
    int R = NSP - s0; if (R > 8) R = 8;
    __shared__ __align__(16) float xr[8][C];
    for (int f = t; f < R * C; f += 256) {
        int rr = f >> 9, c = f & 511;
        float inv = inv_img[b * LV + 1 + s0 + rr];
        xr[rr][c] = img[((size_t)b * LV + 1 + s0 + rr) * C + c] * inv;
    }
    __syncthreads();
    int i = t & 63, w = t >> 6;      // wave w owns rows 2w, 2w+1
    float a0 = 0.f, a1 = 0.f;
    int r0 = 2 * w, r1 = 2 * w + 1;
    for (int c4 = 0; c4 < C / 4; ++c4) {
        float g0 = gloT[(c4 * 4 + 0) * NCAP + i];
        float g1 = gloT[(c4 * 4 + 1) * NCAP + i];
        float g2 = gloT[(c4 * 4 + 2) * NCAP + i];
        float g3 = gloT[(c4 * 4 + 3) * NCAP + i];
        float4 x0 = ((const float4*)xr[r0])[c4];
        float4 x1 = ((const float4*)xr[r1])[c4];
        a0 += x0.x * g0 + x0.y * g1 + x0.z * g2 + x0.w * g3;
        a1 += x1.x * g0 + x1.y * g1 + x1.z * g2 + x1.w * g3;
    }
    float* dst = attn_yT + ((size_t)b * NCAP + i) * NSP;
    if (r0 < R) dst[s0 + r0] = a0;
    if (r1 < R) dst[s0 + r1] = a1;
}

// ---------------------------------------------------------------- main per-pair kernel: rank + two MFMA GEMMs
__global__ __launch_bounds__(512, 4) void k_main(const float* __restrict__ attn_x,
                                                 const float* __restrict__ attn_yT,
                                                 const float* __restrict__ WsM,
                                                 const u16* __restrict__ imgT,
                                                 const u16* __restrict__ Qbb,
                                                 const float* __restrict__ temp_p,
                                                 float* __restrict__ out) {
    int lin = blockIdx.x + NCAP * blockIdx.y;     // XCD swizzle: lin%8 selects b-octet
    int b = (lin & 7) * 8 + ((lin >> 3) & 7);
    int i = lin >> 6;
    int t = threadIdx.x;
    int lane = t & 63, wu = t >> 6;
    int l15 = lane & 15, quad = lane >> 4;

    __shared__ __align__(16) u16 TnBuf[51 * 520];   // aliases Pf(64x232) then ULDS(96x52 f32)
    __shared__ float rowsq[8][64];
    __shared__ float invn[64];
    __shared__ float colM[51], colZ[51], rowM[32], rowZ[32], redw[8];
    __shared__ float scoreS[NSP];
    __shared__ int   keepL[NKEEP];
    __shared__ int   nonL[NKEEP];
    __shared__ float snon[NKEEP];

    u16*   Pf   = TnBuf;
    float* ULDS = (float*)TnBuf;

    // ---- 1. zero Pf rows 0..50 + load scores
    {
        u32* Pfu = (u32*)Pf;
        for (int f = t; f < 51 * 116; f += 512) Pfu[f] = 0;
    }
    if (t < NSP)
        scoreS[t] = attn_x[b * NSP + t] + attn_yT[((size_t)b * NCAP + i) * NSP + t];
    __syncthreads();
    // ---- 2. stable-descending rank -> top-98 partition
    if (t < NSP) {
        float sv = scoreS[t];
        int r = 0;
        for (int u = 0; u < NSP; ++u) {
            float o = scoreS[u];
            r += (o > sv) || (o == sv && u < t);
        }
        if (r < NKEEP) keepL[r] = t;
        else { nonL[r - NKEEP] = t; snon[r - NKEEP] = sv; }
    }
    __syncthreads();
    // ---- 3. scatter P into Pf (WsM gather + exp; scale-invariant, no max-sub)
    if (t == 0) Pf[0] = 0x3F80;                       // cls one-hot (1.0)
    for (int f = t; f < NKEEP * KEEPED; f += 512) {
        int j = f / KEEPED, k = f - j * KEEPED;
        int s = keepL[j];
        Pf[(1 + k) * 232 + 1 + s] = f2bf(expf(WsM[((size_t)b * NSP + s) * KEEPED + k]));
    }
    if (t < NKEEP) Pf[50 * 232 + 1 + nonL[t]] = f2bf(expf(snon[t]));
    __syncthreads();

    // ---- phase 1: T(51x512) = Pfull @ imgT ; wave w owns c-range [64w,64w+64)
    const u16* imgTb = imgT + (size_t)b * 512 * 224;
    f32x4 acc[4][4];
#pragma unroll
    for (int mi = 0; mi < 4; ++mi)
#pragma unroll
        for (int nj = 0; nj < 4; ++nj) acc[mi][nj] = (f32x4){0.f, 0.f, 0.f, 0.f};

    for (int ks = 0; ks < 7; ++ks) {
        bf16x8 Afr[4];
#pragma unroll
        for (int mi = 0; mi < 4; ++mi)
            Afr[mi] = ld_bf8(Pf + (mi * 16 + l15) * 232 + ks * 32 + quad * 8);
#pragma unroll
        for (int nj = 0; nj < 4; ++nj) {
            int c = (wu * 4 + nj) * 16 + l15;
            bf16x8 Bf = ld_bf8(imgTb + (size_t)c * 224 + ks * 32 + quad * 8);
#pragma unroll
            for (int mi = 0; mi < 4; ++mi)
                acc[mi][nj] = __builtin_amdgcn_mfma_f32_16x16x32_bf16(Afr[mi], Bf, acc[mi][nj], 0, 0, 0);
        }
    }

    // ---- row sums of squares
#pragma unroll
    for (int mi = 0; mi < 4; ++mi)
#pragma unroll
        for (int r = 0; r < 4; ++r) {
            float s = acc[mi][0][r] * acc[mi][0][r] + acc[mi][1][r] * acc[mi][1][r]
                    + acc[mi][2][r] * acc[mi][2][r] + acc[mi][3][r] * acc[mi][3][r];
            s += __shfl_down(s, 8); s += __shfl_down(s, 4);
            s += __shfl_down(s, 2); s += __shfl_down(s, 1);
            if (l15 == 0) rowsq[wu][mi * 16 + quad * 4 + r] = s;
        }
    __syncthreads();
    if (t < 64) {
        float s = 0.f;
#pragma unroll
        for (int w2 = 0; w2 < 8; ++w2) s += rowsq[w2][t];
        invn[t] = 1.f / fmaxf(sqrtf(s), 1e-12f);
    }
    __syncthreads();

    // ---- write normalized Tn bf16 (Pf region dead)
#pragma unroll
    for (int mi = 0; mi < 4; ++mi)
#pragma unroll
        for (int r = 0; r < 4; ++r) {
            int row = mi * 16 + quad * 4 + r;
            if (row < 51) {
                float iv = invn[row];
#pragma unroll
                for (int nj = 0; nj < 4; ++nj)
                    TnBuf[row * 520 + (wu * 4 + nj) * 16 + l15] = f2bf(acc[mi][nj][r] * iv);
            }
        }
    __syncthreads();

    // ---- phase 2: U = Qbb @ Tn^T
    const u16* Qb = Qbb + (size_t)i * 96 * 512;
    f32x4 ua[3];
#pragma unroll
    for (int e = 0; e < 3; ++e) ua[e] = (f32x4){0.f, 0.f, 0.f, 0.f};

    if (wu < 6) {
        int mi = wu;
        const u16* Ar = Qb + (size_t)(mi * 16 + l15) * 512;
        bf16x8 Af = ld_bf8(Ar + quad * 8);
        for (int ks = 0; ks < 16; ++ks) {
            bf16x8 An;
            if (ks < 15) An = ld_bf8(Ar + (ks + 1) * 32 + quad * 8);
#pragma unroll
            for (int e = 0; e < 3; ++e) {
                bf16x8 Bf = ld_bf8(TnBuf + (e * 16 + l15) * 520 + ks * 32 + quad * 8);
                ua[e] = __builtin_amdgcn_mfma_f32_16x16x32_bf16(Af, Bf, ua[e], 0, 0, 0);
            }
            Af = An;
        }
    } else {
        int w2 = wu - 6;
        int rowB = 48 + l15; if (rowB > 50) rowB = 50;
        const u16* Ar0 = Qb + (size_t)((3 * w2 + 0) * 16 + l15) * 512;
        const u16* Ar1 = Qb + (size_t)((3 * w2 + 1) * 16 + l15) * 512;
        const u16* Ar2 = Qb + (size_t)((3 * w2 + 2) * 16 + l15) * 512;
        bf16x8 Af0 = ld_bf8(Ar0 + quad * 8);
        bf16x8 Af1 = ld_bf8(Ar1 + quad * 8);
        bf16x8 Af2 = ld_bf8(Ar2 + quad * 8);
        for (int ks = 0; ks < 16; ++ks) {
            bf16x8 An0, An1, An2;
            if (ks < 15) {
                An0 = ld_bf8(Ar0 + (ks + 1) * 32 + quad * 8);
                An1 = ld_bf8(Ar1 + (ks + 1) * 32 + quad * 8);
                An2 = ld_bf8(Ar2 + (ks + 1) * 32 + quad * 8);
            }
            bf16x8 Bf = ld_bf8(TnBuf + rowB * 520 + ks * 32 + quad * 8);
            ua[0] = __builtin_amdgcn_mfma_f32_16x16x32_bf16(Af0, Bf, ua[0], 0, 0, 0);
            ua[1] = __builtin_amdgcn_mfma_f32_16x16x32_bf16(Af1, Bf, ua[1], 0, 0, 0);
            ua[2] = __builtin_amdgcn_mfma_f32_16x16x32_bf16(Af2, Bf, ua[2], 0, 0, 0);
            Af0 = An0; Af1 = An1; Af2 = An2;
        }
    }
    __syncthreads();   // Tn reads done before U overwrites

    // ---- write U (96 x 51)
    if (wu < 6) {
#pragma unroll
        for (int e = 0; e < 3; ++e) {
            int l = e * 16 + l15;
            int q0 = wu * 16 + quad * 4;
#pragma unroll
            for (int r = 0; r < 4; ++r) ULDS[(q0 + r) * 52 + l] = ua[e][r];
        }
    } else {
        int l = 48 + l15;
        if (l < 51) {
            int w2 = wu - 6;
#pragma unroll
            for (int e = 0; e < 3; ++e) {
                int q0 = (3 * w2 + e) * 16 + quad * 4;
#pragma unroll
                for (int r = 0; r < 4; ++r) ULDS[(q0 + r) * 52 + l] = ua[e][r];
            }
        }
    }
    __syncthreads();

    // ---- softmax stats
    float invT = 1.f / temp_p[0];
    if (t < 51) {
        float mm = -1e30f;
        for (int u = 0; u < LT; ++u) mm = fmaxf(mm, ULDS[(32 + u) * 52 + t] * invT);
        float z = 0.f;
        for (int u = 0; u < LT; ++u) z += expf(ULDS[(32 + u) * 52 + t] * invT - mm);
        colM[t] = mm; colZ[t] = 1.f / z;
    }
    if (t >= 64 && t < 96) {
        int u = t - 64;
        float mm = -1e30f;
        for (int l = 0; l < 51; ++l) mm = fmaxf(mm, ULDS[(64 + u) * 52 + l] * invT);
        float z = 0.f;
        for (int l = 0; l < 51; ++l) z += expf(ULDS[(64 + u) * 52 + l] * invT - mm);
        rowM[u] = mm; rowZ[u] = 1.f / z;
    }
    __syncthreads();

    // ---- final reduction
    float part = 0.f;
    for (int f = t; f < LT * 51; f += 512) {
        int u = f / 51, l = f - u * 51;
        float u0 = ULDS[u * 52 + l];
        float c2 = (u0 > 0.f) ? u0 : 0.1f * u0;
        float av = expf(ULDS[(32 + u) * 52 + l] * invT - colM[l]) * colZ[l];
        float bv = expf(ULDS[(64 + u) * 52 + l] * invT - rowM[u]) * rowZ[u];
        part += c2 * (av * (1.f / 51.f) + bv * (1.f / 32.f));
    }
    for (int o = 32; o > 0; o >>= 1) part += __shfl_down(part, o);
    if (lane == 0) redw[wu] = part;
    __syncthreads();
    if (t == 0) {
        float s = 0.f;
#pragma unroll
        for (int w2 = 0; w2 < 8; ++w2) s += redw[w2];
        out[b * NCAP + i] = s;
    }
}

extern "C" void kernel_launch(void* const* d_in, const int* in_sizes, int n_in,
                              void* d_out, int out_size, void* d_ws, size_t ws_size,
                              hipStream_t stream) {
    const float* img        = (const float*)d_in[0];
    const float* cap        = (const float*)d_in[1];
    const float* gamw       = (const float*)d_in[3];
    const float* betw       = (const float*)d_in[4];
    const float* w1         = (const float*)d_in[5];
    const float* b1         = (const float*)d_in[6];
    const float* w2         = (const float*)d_in[7];
    const float* b2         = (const float*)d_in[8];
    const float* aggr_scale = (const float*)d_in[9];
    const float* wi2t       = (const float*)d_in[10];
    const float* bi2t       = (const float*)d_in[11];
    const float* wt2i       = (const float*)d_in[12];
    const float* bt2i       = (const float*)d_in[13];
    const float* temp       = (const float*)d_in[14];
    float* out = (float*)d_out;

    float* ws      = (float*)d_ws;
    float* inv_img = ws + OFF_INV;
    float* attn_x  = ws + OFF_ATTNX;
    float* WsM     = ws + OFF_WSMAT;
    u16*   wT      = (u16*)(ws + OFF_WT);
    float* gloT    = ws + OFF_GLOT;
    float* attn_yT = ws + OFF_ATTNYT;
    u16*   imgT    = (u16*)(ws + OFF_IMGT);
    u16*   Qbb     = (u16*)(ws + OFF_QBB);

    k_img_norm<<<dim3(B * LV), dim3(64), 0, stream>>>(img, inv_img);
    k_imgt<<<dim3(B, 8), dim3(256), 0, stream>>>(img, imgT);
    k_cap_norm<<<dim3(NCAP, LT), dim3(64), 0, stream>>>(cap, gloT, Qbb);
    k_wt<<<dim3(2, 8), dim3(256), 0, stream>>>(wi2t, wt2i, wT);
    k_qproj_mfma<<<dim3(NCAP, 4), dim3(512), 0, stream>>>(wT, bi2t, bt2i, Qbb);
    k_img_row<<<dim3(B, 49), dim3(256), 0, stream>>>(img, inv_img, gamw, betw, w1, b1, w2, b2,
                                                     aggr_scale, attn_x, WsM);
    k_attn_y<<<dim3(B, 25), dim3(256), 0, stream>>>(img, inv_img, gloT, attn_yT);
    k_main<<<dim3(NCAP, B), dim3(512), 0, stream>>>(attn_x, attn_yT, WsM, imgT, Qbb, temp, out);
}

// Round 10
// 481.682 us; speedup vs baseline: 4.8636x; 1.0379x over previous
//
#include <hip/hip_runtime.h>
#include <math.h>

#define B     64
#define NCAP  64
#define LV    197
#define LT    32
#define C     512
#define NSP   196
#define NKEEP 98
#define HID   102
#define KEEPED 49

// Workspace layout (float element offsets). Total 19,407,680 floats = 77.6 MB (proven OK).
#define OFF_ATTNX   12608                     // B*NSP
#define OFF_WSMAT   25152                     // B*NSP*KEEPED
#define OFF_WT      639808                    // u16 2*512*512 (bf16 wi2t^T / wt2i^T)
#define OFF_GLOT    1688384                   // C*NCAP
#define OFF_ATTNYT  1721152                   // 4096*196 floats (transposed [b][i][s])
#define OFF_IMGT    14164800                  // u16 64*512*224 (bf16 img^T, s-padded)
#define OFF_QBB     17834816                  // u16 64*96*512 (bf16 [capn;qi2t;qt2i])

typedef unsigned int u32;
typedef unsigned short u16;
typedef __bf16 bf16x8 __attribute__((ext_vector_type(8)));
typedef float f32x4 __attribute__((ext_vector_type(4)));
typedef unsigned int uint4v __attribute__((ext_vector_type(4)));

__device__ __forceinline__ u16 f2bf(float f) {
    u32 u = __builtin_bit_cast(u32, f);
    return (u16)((u + 0x7FFFu + ((u >> 16) & 1u)) >> 16);
}
__device__ __forceinline__ bf16x8 ld_bf8(const u16* p) {
    uint4v v = *reinterpret_cast<const uint4v*>(p);
    return __builtin_bit_cast(bf16x8, v);
}

__device__ __forceinline__ float gelu_exact(float x) {
    return 0.5f * x * (1.f + erff(x * 0.70710678118654752f));
}

// ---------------------------------------------------------------- img^T bf16 (s-padded to 224)
__global__ __launch_bounds__(256) void k_imgt(const float* __restrict__ img,
                                              u16* __restrict__ imgT) {
    int b = blockIdx.x, cg = blockIdx.y, t = threadIdx.x;
    __shared__ u16 Tl[64 * 224];
    for (int f = t; f < 64 * 27; f += 256) Tl[(f / 27) * 224 + 197 + (f % 27)] = 0;
    int cc = t & 63;
    for (int sb = t >> 6; sb < 197; sb += 4) {
        float v = img[((size_t)b * LV + sb) * C + cg * 64 + cc];
        Tl[cc * 224 + sb] = f2bf(v);
    }
    __syncthreads();
    const u32* Tu = (const u32*)Tl;
    u32* outp = (u32*)(imgT + ((size_t)b * 512 + cg * 64) * 224);
    for (int f = t; f < 64 * 112; f += 256) outp[f] = Tu[f];
}

// ---------------------------------------------------------------- caption norms (+ Qbb rows 0..31, gloT)
__global__ __launch_bounds__(64) void k_cap_norm(const float* __restrict__ cap,
                                                 float* __restrict__ gloT,
                                                 u16* __restrict__ Qbb) {
    int i = blockIdx.x, tt = blockIdx.y, t = threadIdx.x;
    const float* row = cap + ((size_t)i * LT + tt) * C;
    float v[8]; float ss = 0.f;
#pragma unroll
    for (int q = 0; q < 8; ++q) { v[q] = row[t + 64 * q]; ss += v[q] * v[q]; }
    for (int o = 32; o > 0; o >>= 1) ss += __shfl_down(ss, o);
    ss = __shfl(ss, 0);
    float inv = 1.f / fmaxf(sqrtf(ss), 1e-12f);
    u16* qrow = Qbb + ((size_t)i * 96 + tt) * C;
#pragma unroll
    for (int q = 0; q < 8; ++q) {
        float n = v[q] * inv;
        qrow[t + 64 * q] = f2bf(n);
        if (tt == 0) gloT[(t + 64 * q) * NCAP + i] = n;
    }
}

// ---------------------------------------------------------------- transpose wi2t/wt2i -> bf16 [j][c], 128 blocks
__global__ __launch_bounds__(256) void k_wt(const float* __restrict__ wi2t,
                                            const float* __restrict__ wt2i,
                                            u16* __restrict__ wT) {
    int mat = blockIdx.x, ty = blockIdx.y, t = threadIdx.x;
    int jg = ty >> 3, cg = ty & 7;
    const float* W = mat ? wt2i : wi2t;
    __shared__ u16 tile[64][65];
    for (int f = t; f < 4096; f += 256) {
        int cc = f >> 6, jj = f & 63;
        tile[jj][cc] = f2bf(W[(size_t)(cg * 64 + cc) * 512 + jg * 64 + jj]);
    }
    __syncthreads();
    for (int f = t; f < 4096; f += 256) {
        int jj = f >> 6, cc = f & 63;
        wT[((size_t)mat * 512 + jg * 64 + jj) * 512 + cg * 64 + cc] = tile[jj][cc];
    }
}

// ---------------------------------------------------------------- qi2t/qt2i via MFMA (A/B prefetch)
__global__ __launch_bounds__(512) void k_qproj_mfma(const u16* __restrict__ wT,
                                                    const float* __restrict__ bi2t,
                                                    const float* __restrict__ bt2i,
                                                    u16* __restrict__ Qbb) {
    int i = blockIdx.x, p = blockIdx.y, t = threadIdx.x;
    int lane = t & 63, wu = t >> 6;
    int l15 = lane & 15, quad = lane >> 4;
    int mat = wu >> 2;
    int mi  = (wu >> 1) & 1;
    int nh  = wu & 1;
    int ni0 = p * 8 + nh * 4;
    const u16* Arow = Qbb + ((size_t)i * 96 + mi * 16 + l15) * 512;
    const u16* Wm   = wT + (size_t)mat * 512 * 512;
    f32x4 acc[4];
#pragma unroll
    for (int n = 0; n < 4; ++n) acc[n] = (f32x4){0.f, 0.f, 0.f, 0.f};
    bf16x8 A = ld_bf8(Arow + quad * 8);
    bf16x8 Bf[4];
#pragma unroll
    for (int n = 0; n < 4; ++n)
        Bf[n] = ld_bf8(Wm + (size_t)((ni0 + n) * 16 + l15) * 512 + quad * 8);
    for (int ks = 0; ks < 16; ++ks) {
        bf16x8 An; bf16x8 Bn[4];
        if (ks < 15) {
            An = ld_bf8(Arow + (ks + 1) * 32 + quad * 8);
#pragma unroll
            for (int n = 0; n < 4; ++n)
                Bn[n] = ld_bf8(Wm + (size_t)((ni0 + n) * 16 + l15) * 512 + (ks + 1) * 32 + quad * 8);
        }
#pragma unroll
        for (int n = 0; n < 4; ++n)
            acc[n] = __builtin_amdgcn_mfma_f32_16x16x32_bf16(A, Bf[n], acc[n], 0, 0, 0);
        A = An;
#pragma unroll
        for (int n = 0; n < 4; ++n) Bf[n] = Bn[n];
    }
    const float* bias = mat ? bt2i : bi2t;
#pragma unroll
    for (int n = 0; n < 4; ++n) {
        int j = (ni0 + n) * 16 + l15;
        float bj = bias[j];
        int row0 = i * 96 + 32 + mat * 32 + mi * 16 + quad * 4;
#pragma unroll
        for (int r = 0; r < 4; ++r)
            Qbb[(size_t)(row0 + r) * 512 + j] = f2bf(acc[n][r] + bj);
    }
}

// ---------------------------------------------------------------- LN -> w1 -> gelu -> w2 + attn_x (norms inline)
__global__ __launch_bounds__(256) void k_img_row(const float* __restrict__ img,
                                                 const float* __restrict__ gamw,
                                                 const float* __restrict__ betw,
                                                 const float* __restrict__ w1,
                                                 const float* __restrict__ b1,
                                                 const float* __restrict__ w2,
                                                 const float* __restrict__ b2,
                                                 const float* __restrict__ scale_p,
                                                 float* __restrict__ attn_x,
                                                 float* __restrict__ WsM) {
    int b = blockIdx.x, s0 = blockIdx.y * 4, t = threadIdx.x;
    __shared__ __align__(16) float lnr[4][C];
    __shared__ float HH[4][HID + 2];
    __shared__ float redm[4][4];

    int g = t >> 6, lane = t & 63;
    {
        const float* row = img + ((size_t)b * LV + 1 + s0 + g) * C;
        const float* cls = img + (size_t)b * LV * C;
        float sm = 0.f, ss = 0.f, dd = 0.f, sc = 0.f;
        for (int c = lane; c < C; c += 64) {
            float v = row[c];
            float cv = cls[c];
            sm += v; ss += v * v; dd += v * cv; sc += cv * cv;
            lnr[g][c] = v;
        }
        for (int o = 32; o > 0; o >>= 1) {
            sm += __shfl_down(sm, o);
            ss += __shfl_down(ss, o);
            dd += __shfl_down(dd, o);
            sc += __shfl_down(sc, o);
        }
        if (lane == 0) { redm[g][0] = sm; redm[g][1] = ss; redm[g][2] = dd; redm[g][3] = sc; }
    }
    __syncthreads();
    for (int f = t; f < 4 * C; f += 256) {
        int rr = f >> 9, c = f & 511;
        float mean = redm[rr][0] * (1.f / C);
        float var  = redm[rr][1] * (1.f / C) - mean * mean;
        float rstd = 1.f / sqrtf(var + 1e-5f);
        lnr[rr][c] = (lnr[rr][c] - mean) * rstd * gamw[c] + betw[c];
    }
    if (t < 4) {
        float inv0 = 1.f / fmaxf(sqrtf(redm[t][3]), 1e-12f);
        float invs = 1.f / fmaxf(sqrtf(redm[t][1]), 1e-12f);
        attn_x[b * NSP + s0 + t] = redm[t][2] * inv0 * invs;
    }
    __syncthreads();
    // h = gelu(ln @ w1 + b1): 204 threads, each 2 rows
    if (t < 204) {
        int rr2 = (t >= 102) ? 1 : 0;
        int j = t - 102 * rr2;
        float a2[2];
        a2[0] = b1[j]; a2[1] = b1[j];
        for (int c = 0; c < C; ++c) {
            float wv = w1[c * HID + j];
            a2[0] += lnr[rr2 * 2 + 0][c] * wv;
            a2[1] += lnr[rr2 * 2 + 1][c] * wv;
        }
        HH[rr2 * 2 + 0][j] = gelu_exact(a2[0]);
        HH[rr2 * 2 + 1][j] = gelu_exact(a2[1]);
    }
    __syncthreads();
    float scale = scale_p[0];
    if (t < 196) {
        int k = t % 49, rh = t / 49;
        float a = b2[k];
        for (int h = 0; h < HID; ++h) a += HH[rh][h] * w2[h * 49 + k];
        WsM[((size_t)b * NSP + s0 + rh) * 49 + k] = a * scale;
    }
}

// ---------------------------------------------------------------- attn_y transposed: [b][i][s]; norms inline
__global__ __launch_bounds__(256) void k_attn_y(const float* __restrict__ img,
                                                const float* __restrict__ gloT,
                                                float* __restrict__ attn_yT) {
    int b = blockIdx.x, s0 = blockIdx.y * 8, t = threadIdx.x;
    int R = NSP - s0; if (R > 8) R = 8;
    __shared__ __align__(16) float xr[8][C];
    __shared__ float rnorm[8];
    for (int f = t; f < R * C; f += 256) {
        int rr = f >> 9, c = f & 511;
        xr[rr][c] = img[((size_t)b * LV + 1 + s0 + rr) * C + c];
    }
    __syncthreads();
    {
        int row = t >> 5, l32 = t & 31;
        if (row < R) {
            float ss = 0.f;
            for (int c = l32; c < C; c += 32) { float v = xr[row][c]; ss += v * v; }
            for (int o = 16; o > 0; o >>= 1) ss += __shfl_down(ss, o, 32);
            if (l32 == 0) rnorm[row] = 1.f / fmaxf(sqrtf(ss), 1e-12f);
        }
    }
    __syncthreads();
    for (int f = t; f < R * C; f += 256) {
        int rr = f >> 9, c = f & 511;
        xr[rr][c] *= rnorm[rr];
    }
    __syncthreads();
    int i = t & 63, w = t >> 6;      // wave w owns rows 2w, 2w+1
    float a0 = 0.f, a1 = 0.f;
    int r0 = 2 * w, r1 = 2 * w + 1;
    for (int c4 = 0; c4 < C / 4; ++c4) {
        float g0 = gloT[(c4 * 4 + 0) * NCAP + i];
        float g1 = gloT[(c4 * 4 + 1) * NCAP + i];
        float g2 = gloT[(c4 * 4 + 2) * NCAP + i];
        float g3 = gloT[(c4 * 4 + 3) * NCAP + i];
        float4 x0 = ((const float4*)xr[r0])[c4];
        float4 x1 = ((const float4*)xr[r1])[c4];
        a0 += x0.x * g0 + x0.y * g1 + x0.z * g2 + x0.w * g3;
        a1 += x1.x * g0 + x1.y * g1 + x1.z * g2 + x1.w * g3;
    }
    float* dst = attn_yT + ((size_t)b * NCAP + i) * NSP;
    if (r0 < R) dst[s0 + r0] = a0;
    if (r1 < R) dst[s0 + r1] = a1;
}

// ---------------------------------------------------------------- main per-pair kernel: rank + two MFMA GEMMs
__global__ __launch_bounds__(512, 4) void k_main(const float* __restrict__ attn_x,
                                                 const float* __restrict__ attn_yT,
                                                 const float* __restrict__ WsM,
                                                 const u16* __restrict__ imgT,
                                                 const u16* __restrict__ Qbb,
                                                 const float* __restrict__ temp_p,
                                                 float* __restrict__ out) {
    int lin = blockIdx.x + NCAP * blockIdx.y;     // XCD swizzle: lin%8 selects b-octet
    int b = (lin & 7) * 8 + ((lin >> 3) & 7);
    int i = lin >> 6;
    int t = threadIdx.x;
    int lane = t & 63, wu = t >> 6;
    int l15 = lane & 15, quad = lane >> 4;

    __shared__ __align__(16) u16 TnBuf[51 * 520];   // aliases Pf(64x232) then ULDS(96x52 f32)
    __shared__ float rowsq[8][64];
    __shared__ float invn[64];
    __shared__ float colM[51], colZ[51], rowM[32], rowZ[32], redw[8];
    __shared__ float scoreS[NSP];
    __shared__ int   keepL[NKEEP];
    __shared__ int   nonL[NKEEP];
    __shared__ float snon[NKEEP];
    __shared__ short rnkH[2][NSP];

    u16*   Pf   = TnBuf;
    float* ULDS = (float*)TnBuf;

    // ---- 1. zero Pf rows 0..50 + load scores
    {
        u32* Pfu = (u32*)Pf;
        for (int f = t; f < 51 * 116; f += 512) Pfu[f] = 0;
    }
    if (t < NSP)
        scoreS[t] = attn_x[b * NSP + t] + attn_yT[((size_t)b * NCAP + i) * NSP + t];
    __syncthreads();
    // ---- 2. stable-descending rank, split over 392 threads (2 half-ranges per s)
    if (t < 2 * NSP) {
        int half = (t >= NSP) ? 1 : 0;
        int s = t - half * NSP;
        float sv = scoreS[s];
        int u0 = half * 98, u1 = half ? NSP : 98;
        int r = 0;
        for (int u = u0; u < u1; ++u) {
            float o = scoreS[u];
            r += (o > sv) || (o == sv && u < s);
        }
        rnkH[half][s] = (short)r;
    }
    __syncthreads();
    if (t < NSP) {
        int r = rnkH[0][t] + rnkH[1][t];
        if (r < NKEEP) keepL[r] = t;
        else { nonL[r - NKEEP] = t; snon[r - NKEEP] = scoreS[t]; }
    }
    __syncthreads();
    // ---- 3. scatter P into Pf (WsM gather + exp; scale-invariant, no max-sub)
    if (t == 0) Pf[0] = 0x3F80;                       // cls one-hot (1.0)
    for (int f = t; f < NKEEP * KEEPED; f += 512) {
        int j = f / KEEPED, k = f - j * KEEPED;
        int s = keepL[j];
        Pf[(1 + k) * 232 + 1 + s] = f2bf(expf(WsM[((size_t)b * NSP + s) * KEEPED + k]));
    }
    if (t < NKEEP) Pf[50 * 232 + 1 + nonL[t]] = f2bf(expf(snon[t]));
    __syncthreads();

    // ---- phase 1: T(51x512) = Pfull @ imgT ; wave w owns c-range [64w,64w+64)
    const u16* imgTb = imgT + (size_t)b * 512 * 224;
    f32x4 acc[4][4];
#pragma unroll
    for (int mi = 0; mi < 4; ++mi)
#pragma unroll
        for (int nj = 0; nj < 4; ++nj) acc[mi][nj] = (f32x4){0.f, 0.f, 0.f, 0.f};

    for (int ks = 0; ks < 7; ++ks) {
        bf16x8 Afr[4];
#pragma unroll
        for (int mi = 0; mi < 4; ++mi)
            Afr[mi] = ld_bf8(Pf + (mi * 16 + l15) * 232 + ks * 32 + quad * 8);
#pragma unroll
        for (int nj = 0; nj < 4; ++nj) {
            int c = (wu * 4 + nj) * 16 + l15;
            bf16x8 Bf = ld_bf8(imgTb + (size_t)c * 224 + ks * 32 + quad * 8);
#pragma unroll
            for (int mi = 0; mi < 4; ++mi)
                acc[mi][nj] = __builtin_amdgcn_mfma_f32_16x16x32_bf16(Afr[mi], Bf, acc[mi][nj], 0, 0, 0);
        }
    }

    // ---- row sums of squares
#pragma unroll
    for (int mi = 0; mi < 4; ++mi)
#pragma unroll
        for (int r = 0; r < 4; ++r) {
            float s = acc[mi][0][r] * acc[mi][0][r] + acc[mi][1][r] * acc[mi][1][r]
                    + acc[mi][2][r] * acc[mi][2][r] + acc[mi][3][r] * acc[mi][3][r];
            s += __shfl_down(s, 8); s += __shfl_down(s, 4);
            s += __shfl_down(s, 2); s += __shfl_down(s, 1);
            if (l15 == 0) rowsq[wu][mi * 16 + quad * 4 + r] = s;
        }
    __syncthreads();
    if (t < 64) {
        float s = 0.f;
#pragma unroll
        for (int w2 = 0; w2 < 8; ++w2) s += rowsq[w2][t];
        invn[t] = 1.f / fmaxf(sqrtf(s), 1e-12f);
    }
    __syncthreads();

    // ---- write normalized Tn bf16 (Pf region dead)
#pragma unroll
    for (int mi = 0; mi < 4; ++mi)
#pragma unroll
        for (int r = 0; r < 4; ++r) {
            int row = mi * 16 + quad * 4 + r;
            if (row < 51) {
                float iv = invn[row];
#pragma unroll
                for (int nj = 0; nj < 4; ++nj)
                    TnBuf[row * 520 + (wu * 4 + nj) * 16 + l15] = f2bf(acc[mi][nj][r] * iv);
            }
        }
    __syncthreads();

    // ---- phase 2: U = Qbb @ Tn^T
    const u16* Qb = Qbb + (size_t)i * 96 * 512;
    f32x4 ua[3];
#pragma unroll
    for (int e = 0; e < 3; ++e) ua[e] = (f32x4){0.f, 0.f, 0.f, 0.f};

    if (wu < 6) {
        int mi = wu;
        const u16* Ar = Qb + (size_t)(mi * 16 + l15) * 512;
        bf16x8 Af = ld_bf8(Ar + quad * 8);
        for (int ks = 0; ks < 16; ++ks) {
            bf16x8 An;
            if (ks < 15) An = ld_bf8(Ar + (ks + 1) * 32 + quad * 8);
#pragma unroll
            for (int e = 0; e < 3; ++e) {
                bf16x8 Bf = ld_bf8(TnBuf + (e * 16 + l15) * 520 + ks * 32 + quad * 8);
                ua[e] = __builtin_amdgcn_mfma_f32_16x16x32_bf16(Af, Bf, ua[e], 0, 0, 0);
            }
            Af = An;
        }
    } else {
        int w2 = wu - 6;
        int rowB = 48 + l15; if (rowB > 50) rowB = 50;
        const u16* Ar0 = Qb + (size_t)((3 * w2 + 0) * 16 + l15) * 512;
        const u16* Ar1 = Qb + (size_t)((3 * w2 + 1) * 16 + l15) * 512;
        const u16* Ar2 = Qb + (size_t)((3 * w2 + 2) * 16 + l15) * 512;
        bf16x8 Af0 = ld_bf8(Ar0 + quad * 8);
        bf16x8 Af1 = ld_bf8(Ar1 + quad * 8);
        bf16x8 Af2 = ld_bf8(Ar2 + quad * 8);
        for (int ks = 0; ks < 16; ++ks) {
            bf16x8 An0, An1, An2;
            if (ks < 15) {
                An0 = ld_bf8(Ar0 + (ks + 1) * 32 + quad * 8);
                An1 = ld_bf8(Ar1 + (ks + 1) * 32 + quad * 8);
                An2 = ld_bf8(Ar2 + (ks + 1) * 32 + quad * 8);
            }
            bf16x8 Bf = ld_bf8(TnBuf + rowB * 520 + ks * 32 + quad * 8);
            ua[0] = __builtin_amdgcn_mfma_f32_16x16x32_bf16(Af0, Bf, ua[0], 0, 0, 0);
            ua[1] = __builtin_amdgcn_mfma_f32_16x16x32_bf16(Af1, Bf, ua[1], 0, 0, 0);
            ua[2] = __builtin_amdgcn_mfma_f32_16x16x32_bf16(Af2, Bf, ua[2], 0, 0, 0);
            Af0 = An0; Af1 = An1; Af2 = An2;
        }
    }
    __syncthreads();   // Tn reads done before U overwrites

    // ---- write U (96 x 51)
    if (wu < 6) {
#pragma unroll
        for (int e = 0; e < 3; ++e) {
            int l = e * 16 + l15;
            int q0 = wu * 16 + quad * 4;
#pragma unroll
            for (int r = 0; r < 4; ++r) ULDS[(q0 + r) * 52 + l] = ua[e][r];
        }
    } else {
        int l = 48 + l15;
        if (l < 51) {
            int w2 = wu - 6;
#pragma unroll
            for (int e = 0; e < 3; ++e) {
                int q0 = (3 * w2 + e) * 16 + quad * 4;
#pragma unroll
                for (int r = 0; r < 4; ++r) ULDS[(q0 + r) * 52 + l] = ua[e][r];
            }
        }
    }
    __syncthreads();

    // ---- softmax stats
    float invT = 1.f / temp_p[0];
    if (t < 51) {
        float mm = -1e30f;
        for (int u = 0; u < LT; ++u) mm = fmaxf(mm, ULDS[(32 + u) * 52 + t] * invT);
        float z = 0.f;
        for (int u = 0; u < LT; ++u) z += expf(ULDS[(32 + u) * 52 + t] * invT - mm);
        colM[t] = mm; colZ[t] = 1.f / z;
    }
    if (t >= 64 && t < 96) {
        int u = t - 64;
        float mm = -1e30f;
        for (int l = 0; l < 51; ++l) mm = fmaxf(mm, ULDS[(64 + u) * 52 + l] * invT);
        float z = 0.f;
        for (int l = 0; l < 51; ++l) z += expf(ULDS[(64 + u) * 52 + l] * invT - mm);
        rowM[u] = mm; rowZ[u] = 1.f / z;
    }
    __syncthreads();

    // ---- final reduction
    float part = 0.f;
    for (int f = t; f < LT * 51; f += 512) {
        int u = f / 51, l = f - u * 51;
        float u0 = ULDS[u * 52 + l];
        float c2 = (u0 > 0.f) ? u0 : 0.1f * u0;
        float av = expf(ULDS[(32 + u) * 52 + l] * invT - colM[l]) * colZ[l];
        float bv = expf(ULDS[(64 + u) * 52 + l] * invT - rowM[u]) * rowZ[u];
        part += c2 * (av * (1.f / 51.f) + bv * (1.f / 32.f));
    }
    for (int o = 32; o > 0; o >>= 1) part += __shfl_down(part, o);
    if (lane == 0) redw[wu] = part;
    __syncthreads();
    if (t == 0) {
        float s = 0.f;
#pragma unroll
        for (int w2 = 0; w2 < 8; ++w2) s += redw[w2];
        out[b * NCAP + i] = s;
    }
}

extern "C" void kernel_launch(void* const* d_in, const int* in_sizes, int n_in,
                              void* d_out, int out_size, void* d_ws, size_t ws_size,
                              hipStream_t stream) {
    const float* img        = (const float*)d_in[0];
    const float* cap        = (const float*)d_in[1];
    const float* gamw       = (const float*)d_in[3];
    const float* betw       = (const float*)d_in[4];
    const float* w1         = (const float*)d_in[5];
    const float* b1         = (const float*)d_in[6];
    const float* w2         = (const float*)d_in[7];
    const float* b2         = (const float*)d_in[8];
    const float* aggr_scale = (const float*)d_in[9];
    const float* wi2t       = (const float*)d_in[10];
    const float* bi2t       = (const float*)d_in[11];
    const float* wt2i       = (const float*)d_in[12];
    const float* bt2i       = (const float*)d_in[13];
    const float* temp       = (const float*)d_in[14];
    float* out = (float*)d_out;

    float* ws      = (float*)d_ws;
    float* attn_x  = ws + OFF_ATTNX;
    float* WsM     = ws + OFF_WSMAT;
    u16*   wT      = (u16*)(ws + OFF_WT);
    float* gloT    = ws + OFF_GLOT;
    float* attn_yT = ws + OFF_ATTNYT;
    u16*   imgT    = (u16*)(ws + OFF_IMGT);
    u16*   Qbb     = (u16*)(ws + OFF_QBB);

    k_imgt<<<dim3(B, 8), dim3(256), 0, stream>>>(img, imgT);
    k_cap_norm<<<dim3(NCAP, LT), dim3(64), 0, stream>>>(cap, gloT, Qbb);
    k_wt<<<dim3(2, 64), dim3(256), 0, stream>>>(wi2t, wt2i, wT);
    k_qproj_mfma<<<dim3(NCAP, 4), dim3(512), 0, stream>>>(wT, bi2t, bt2i, Qbb);
    k_img_row<<<dim3(B, 49), dim3(256), 0, stream>>>(img, gamw, betw, w1, b1, w2, b2,
                                                     aggr_scale, attn_x, WsM);
    k_attn_y<<<dim3(B, 25), dim3(256), 0, stream>>>(img, gloT, attn_yT);
    k_main<<<dim3(NCAP, B), dim3(512), 0, stream>>>(attn_x, attn_yT, WsM, imgT, Qbb, temp, out);
}

// Round 11
// 480.732 us; speedup vs baseline: 4.8732x; 1.0020x over previous
//
#include <hip/hip_runtime.h>
#include <math.h>

#define B     64
#define NCAP  64
#define LV    197
#define LT    32
#define C     512
#define NSP   196
#define NKEEP 98
#define HID   102
#define KEEPED 49

// Workspace layout (float element offsets). Total 19,407,680 floats = 77.6 MB (proven OK).
#define OFF_ATTNX   12608                     // B*NSP
#define OFF_WSMAT   25152                     // B*NSP*KEEPED
#define OFF_WT      639808                    // u16 2*512*512 (bf16 wi2t^T / wt2i^T)
#define OFF_GLOT    1688384                   // C*NCAP
#define OFF_ATTNYT  1721152                   // 4096*196 floats (transposed [b][i][s])
#define OFF_IMGT    14164800                  // u16 64*512*224 (bf16 img^T, s-padded)
#define OFF_QBB     17834816                  // u16 64*96*512 (bf16 [capn;qi2t;qt2i])

typedef unsigned int u32;
typedef unsigned short u16;
typedef __bf16 bf16x8 __attribute__((ext_vector_type(8)));
typedef float f32x4 __attribute__((ext_vector_type(4)));
typedef unsigned int uint4v __attribute__((ext_vector_type(4)));

__device__ __forceinline__ u16 f2bf(float f) {
    u32 u = __builtin_bit_cast(u32, f);
    return (u16)((u + 0x7FFFu + ((u >> 16) & 1u)) >> 16);
}
__device__ __forceinline__ bf16x8 ld_bf8(const u16* p) {
    uint4v v = *reinterpret_cast<const uint4v*>(p);
    return __builtin_bit_cast(bf16x8, v);
}

__device__ __forceinline__ float gelu_exact(float x) {
    return 0.5f * x * (1.f + erff(x * 0.70710678118654752f));
}

// ---------------------------------------------------------------- k_pre: imgt (0..511) | cap_norm (512..1023) | wt (1024..1151)
__global__ __launch_bounds__(256) void k_pre(const float* __restrict__ img,
                                             const float* __restrict__ cap,
                                             const float* __restrict__ wi2t,
                                             const float* __restrict__ wt2i,
                                             u16* __restrict__ imgT,
                                             float* __restrict__ gloT,
                                             u16* __restrict__ Qbb,
                                             u16* __restrict__ wT) {
    int idx = blockIdx.x, t = threadIdx.x;
    __shared__ __align__(16) u16 shb[64 * 224];    // 28 KB union

    if (idx < 512) {
        // ---- img^T bf16 (s-padded to 224)
        int b = idx >> 3, cg = idx & 7;
        for (int f = t; f < 64 * 27; f += 256) shb[(f / 27) * 224 + 197 + (f % 27)] = 0;
        int cc = t & 63;
        for (int sb = t >> 6; sb < 197; sb += 4) {
            float v = img[((size_t)b * LV + sb) * C + cg * 64 + cc];
            shb[cc * 224 + sb] = f2bf(v);
        }
        __syncthreads();
        const u32* Tu = (const u32*)shb;
        u32* outp = (u32*)(imgT + ((size_t)b * 512 + cg * 64) * 224);
        for (int f = t; f < 64 * 112; f += 256) outp[f] = Tu[f];
    } else if (idx < 1024) {
        // ---- caption norms, 4 rows/block (wave w owns row tg*4+w)
        int e = idx - 512, i = e >> 3, tg = e & 7;
        int lane = t & 63, wv = t >> 6;
        int tt = tg * 4 + wv;
        const float* row = cap + ((size_t)i * LT + tt) * C;
        float v[8]; float ss = 0.f;
#pragma unroll
        for (int q = 0; q < 8; ++q) { v[q] = row[lane + 64 * q]; ss += v[q] * v[q]; }
        for (int o = 32; o > 0; o >>= 1) ss += __shfl_down(ss, o);
        ss = __shfl(ss, 0);
        float inv = 1.f / fmaxf(sqrtf(ss), 1e-12f);
        u16* qrow = Qbb + ((size_t)i * 96 + tt) * C;
#pragma unroll
        for (int q = 0; q < 8; ++q) {
            float n = v[q] * inv;
            qrow[lane + 64 * q] = f2bf(n);
            if (tt == 0) gloT[(lane + 64 * q) * NCAP + i] = n;
        }
    } else {
        // ---- transpose wi2t/wt2i -> bf16 [j][c], one 64x64 tile per block
        int e = idx - 1024;
        int mat = e >> 6, ty = e & 63, jg = ty >> 3, cg = ty & 7;
        const float* W = mat ? wt2i : wi2t;
        u16 (*tile)[65] = (u16(*)[65])shb;
        for (int f = t; f < 4096; f += 256) {
            int cc = f >> 6, jj = f & 63;
            tile[jj][cc] = f2bf(W[(size_t)(cg * 64 + cc) * 512 + jg * 64 + jj]);
        }
        __syncthreads();
        for (int f = t; f < 4096; f += 256) {
            int jj = f >> 6, cc = f & 63;
            wT[((size_t)mat * 512 + jg * 64 + jj) * 512 + cg * 64 + cc] = tile[jj][cc];
        }
    }
}

// ---------------------------------------------------------------- k_mid: qproj (0..255) | img_row (256..1855) | attn_y (1856..3455)
__global__ __launch_bounds__(512) void k_mid(const float* __restrict__ img,
                                             const u16* __restrict__ wT,
                                             const float* __restrict__ bi2t,
                                             const float* __restrict__ bt2i,
                                             u16* __restrict__ Qbb,
                                             const float* __restrict__ gamw,
                                             const float* __restrict__ betw,
                                             const float* __restrict__ w1,
                                             const float* __restrict__ b1,
                                             const float* __restrict__ w2,
                                             const float* __restrict__ b2,
                                             const float* __restrict__ scale_p,
                                             const float* __restrict__ gloT,
                                             float* __restrict__ attn_x,
                                             float* __restrict__ WsM,
                                             float* __restrict__ attn_yT) {
    int idx = blockIdx.x, t = threadIdx.x;
    __shared__ __align__(16) float shm[4960 + 16];   // ~19.9 KB union

    if (idx < 256) {
        // ---- qi2t/qt2i via MFMA (A/B prefetch); i=idx&63, p=idx>>6
        int i = idx & 63, p = idx >> 6;
        int lane = t & 63, wu = t >> 6;
        int l15 = lane & 15, quad = lane >> 4;
        int mat = wu >> 2;
        int mi  = (wu >> 1) & 1;
        int nh  = wu & 1;
        int ni0 = p * 8 + nh * 4;
        const u16* Arow = Qbb + ((size_t)i * 96 + mi * 16 + l15) * 512;
        const u16* Wm   = wT + (size_t)mat * 512 * 512;
        f32x4 acc[4];
#pragma unroll
        for (int n = 0; n < 4; ++n) acc[n] = (f32x4){0.f, 0.f, 0.f, 0.f};
        bf16x8 A = ld_bf8(Arow + quad * 8);
        bf16x8 Bf[4];
#pragma unroll
        for (int n = 0; n < 4; ++n)
            Bf[n] = ld_bf8(Wm + (size_t)((ni0 + n) * 16 + l15) * 512 + quad * 8);
        for (int ks = 0; ks < 16; ++ks) {
            bf16x8 An; bf16x8 Bn[4];
            if (ks < 15) {
                An = ld_bf8(Arow + (ks + 1) * 32 + quad * 8);
#pragma unroll
                for (int n = 0; n < 4; ++n)
                    Bn[n] = ld_bf8(Wm + (size_t)((ni0 + n) * 16 + l15) * 512 + (ks + 1) * 32 + quad * 8);
            }
#pragma unroll
            for (int n = 0; n < 4; ++n)
                acc[n] = __builtin_amdgcn_mfma_f32_16x16x32_bf16(A, Bf[n], acc[n], 0, 0, 0);
            A = An;
#pragma unroll
            for (int n = 0; n < 4; ++n) Bf[n] = Bn[n];
        }
        const float* bias = mat ? bt2i : bi2t;
#pragma unroll
        for (int n = 0; n < 4; ++n) {
            int j = (ni0 + n) * 16 + l15;
            float bj = bias[j];
            int row0 = i * 96 + 32 + mat * 32 + mi * 16 + quad * 4;
#pragma unroll
            for (int r = 0; r < 4; ++r)
                Qbb[(size_t)(row0 + r) * 512 + j] = f2bf(acc[n][r] + bj);
        }
    } else if (idx < 1856) {
        // ---- LN -> w1 -> gelu -> w2 + attn_x, 8 rows/block
        int e = idx - 256;
        int b = e / 25, sg = e - b * 25;
        int s0 = sg * 8;
        int R = NSP - s0; if (R > 8) R = 8;
        float (*lnr)[C]   = (float(*)[C])shm;            // 8x512
        float (*HH)[104]  = (float(*)[104])(shm + 4096); // 8x104
        float (*redm)[4]  = (float(*)[4])(shm + 4928);   // 8x4

        int g = t >> 6, lane = t & 63;
        if (g < R) {
            const float* row = img + ((size_t)b * LV + 1 + s0 + g) * C;
            const float* cls = img + (size_t)b * LV * C;
            float sm = 0.f, ss = 0.f, dd = 0.f, sc = 0.f;
            for (int c = lane; c < C; c += 64) {
                float v = row[c];
                float cv = cls[c];
                sm += v; ss += v * v; dd += v * cv; sc += cv * cv;
                lnr[g][c] = v;
            }
            for (int o = 32; o > 0; o >>= 1) {
                sm += __shfl_down(sm, o);
                ss += __shfl_down(ss, o);
                dd += __shfl_down(dd, o);
                sc += __shfl_down(sc, o);
            }
            if (lane == 0) { redm[g][0] = sm; redm[g][1] = ss; redm[g][2] = dd; redm[g][3] = sc; }
        }
        __syncthreads();
        for (int f = t; f < R * C; f += 512) {
            int rr = f >> 9, c = f & 511;
            float mean = redm[rr][0] * (1.f / C);
            float var  = redm[rr][1] * (1.f / C) - mean * mean;
            float rstd = 1.f / sqrtf(var + 1e-5f);
            lnr[rr][c] = (lnr[rr][c] - mean) * rstd * gamw[c] + betw[c];
        }
        if (t < R) {
            float inv0 = 1.f / fmaxf(sqrtf(redm[t][3]), 1e-12f);
            float invs = 1.f / fmaxf(sqrtf(redm[t][1]), 1e-12f);
            attn_x[b * NSP + s0 + t] = redm[t][2] * inv0 * invs;
        }
        __syncthreads();
        // h = gelu(ln @ w1 + b1): 408 threads, each 2 rows
        if (t < 408) {
            int rr2 = t / 102;                 // 0..3
            int j = t - rr2 * 102;
            int rw0 = rr2 * 2, rw1 = rr2 * 2 + 1;
            float a0 = b1[j], a1 = b1[j];
            for (int c = 0; c < C; ++c) {
                float wv = w1[c * HID + j];
                a0 += lnr[rw0][c] * wv;
                a1 += lnr[rw1][c] * wv;
            }
            if (rw0 < R) HH[rw0][j] = gelu_exact(a0);
            if (rw1 < R) HH[rw1][j] = gelu_exact(a1);
        }
        __syncthreads();
        float scale = scale_p[0];
        if (t < 392) {
            int k = t % 49, rh = t / 49;       // rh 0..7
            if (rh < R) {
                float a = b2[k];
                for (int h = 0; h < HID; ++h) a += HH[rh][h] * w2[h * 49 + k];
                WsM[((size_t)b * NSP + s0 + rh) * 49 + k] = a * scale;
            }
        }
    } else {
        // ---- attn_y transposed, 8 rows/block, wave w owns row w
        int e = idx - 1856;
        int b = e / 25;
        int s0 = (e - b * 25) * 8;
        int R = NSP - s0; if (R > 8) R = 8;
        float (*xr)[C] = (float(*)[C])shm;     // 8x512
        float* rnorm = shm + 4096;

        for (int f = t; f < R * C; f += 512) {
            int rr = f >> 9, c = f & 511;
            xr[rr][c] = img[((size_t)b * LV + 1 + s0 + rr) * C + c];
        }
        __syncthreads();
        {
            int row = t >> 6, l = t & 63;
            if (row < R) {
                float ss = 0.f;
                for (int c = l; c < C; c += 64) { float v = xr[row][c]; ss += v * v; }
                for (int o = 32; o > 0; o >>= 1) ss += __shfl_down(ss, o);
                if (l == 0) rnorm[row] = 1.f / fmaxf(sqrtf(ss), 1e-12f);
            }
        }
        __syncthreads();
        for (int f = t; f < R * C; f += 512) {
            int rr = f >> 9, c = f & 511;
            xr[rr][c] *= rnorm[rr];
        }
        __syncthreads();
        int i = t & 63, w = t >> 6;
        if (w < R) {
            float a0 = 0.f;
            for (int c4 = 0; c4 < C / 4; ++c4) {
                float g0 = gloT[(c4 * 4 + 0) * NCAP + i];
                float g1 = gloT[(c4 * 4 + 1) * NCAP + i];
                float g2 = gloT[(c4 * 4 + 2) * NCAP + i];
                float g3 = gloT[(c4 * 4 + 3) * NCAP + i];
                float4 x0 = ((const float4*)xr[w])[c4];
                a0 += x0.x * g0 + x0.y * g1 + x0.z * g2 + x0.w * g3;
            }
            attn_yT[((size_t)b * NCAP + i) * NSP + s0 + w] = a0;
        }
    }
}

// ---------------------------------------------------------------- main per-pair kernel: rank + two MFMA GEMMs
__global__ __launch_bounds__(512, 4) void k_main(const float* __restrict__ attn_x,
                                                 const float* __restrict__ attn_yT,
                                                 const float* __restrict__ WsM,
                                                 const u16* __restrict__ imgT,
                                                 const u16* __restrict__ Qbb,
                                                 const float* __restrict__ temp_p,
                                                 float* __restrict__ out) {
    int lin = blockIdx.x + NCAP * blockIdx.y;     // XCD swizzle: lin%8 selects b-octet
    int b = (lin & 7) * 8 + ((lin >> 3) & 7);
    int i = lin >> 6;
    int t = threadIdx.x;
    int lane = t & 63, wu = t >> 6;
    int l15 = lane & 15, quad = lane >> 4;

    __shared__ __align__(16) u16 TnBuf[51 * 520];   // aliases Pf(64x232) then ULDS(96x52 f32)
    __shared__ float rowsq[8][64];
    __shared__ float invn[64];
    __shared__ float colM[51], colZ[51], rowM[32], rowZ[32], redw[8];
    __shared__ float scoreS[NSP];
    __shared__ int   keepL[NKEEP];
    __shared__ int   nonL[NKEEP];
    __shared__ float snon[NKEEP];
    __shared__ short rnkH[2][NSP];

    u16*   Pf   = TnBuf;
    float* ULDS = (float*)TnBuf;

    // ---- 1. zero Pf rows 0..50 + load scores
    {
        u32* Pfu = (u32*)Pf;
        for (int f = t; f < 51 * 116; f += 512) Pfu[f] = 0;
    }
    if (t < NSP)
        scoreS[t] = attn_x[b * NSP + t] + attn_yT[((size_t)b * NCAP + i) * NSP + t];
    __syncthreads();
    // ---- 2. stable-descending rank, split over 392 threads (2 half-ranges per s)
    if (t < 2 * NSP) {
        int half = (t >= NSP) ? 1 : 0;
        int s = t - half * NSP;
        float sv = scoreS[s];
        int u0 = half * 98, u1 = half ? NSP : 98;
        int r = 0;
        for (int u = u0; u < u1; ++u) {
            float o = scoreS[u];
            r += (o > sv) || (o == sv && u < s);
        }
        rnkH[half][s] = (short)r;
    }
    __syncthreads();
    if (t < NSP) {
        int r = rnkH[0][t] + rnkH[1][t];
        if (r < NKEEP) keepL[r] = t;
        else { nonL[r - NKEEP] = t; snon[r - NKEEP] = scoreS[t]; }
    }
    __syncthreads();
    // ---- 3. scatter P into Pf (WsM gather + exp; scale-invariant, no max-sub)
    if (t == 0) Pf[0] = 0x3F80;                       // cls one-hot (1.0)
    for (int f = t; f < NKEEP * KEEPED; f += 512) {
        int j = f / KEEPED, k = f - j * KEEPED;
        int s = keepL[j];
        Pf[(1 + k) * 232 + 1 + s] = f2bf(expf(WsM[((size_t)b * NSP + s) * KEEPED + k]));
    }
    if (t < NKEEP) Pf[50 * 232 + 1 + nonL[t]] = f2bf(expf(snon[t]));
    __syncthreads();

    // ---- phase 1: T(51x512) = Pfull @ imgT ; wave w owns c-range [64w,64w+64)
    const u16* imgTb = imgT + (size_t)b * 512 * 224;
    f32x4 acc[4][4];
#pragma unroll
    for (int mi = 0; mi < 4; ++mi)
#pragma unroll
        for (int nj = 0; nj < 4; ++nj) acc[mi][nj] = (f32x4){0.f, 0.f, 0.f, 0.f};

    for (int ks = 0; ks < 7; ++ks) {
        bf16x8 Afr[4];
#pragma unroll
        for (int mi = 0; mi < 4; ++mi)
            Afr[mi] = ld_bf8(Pf + (mi * 16 + l15) * 232 + ks * 32 + quad * 8);
#pragma unroll
        for (int nj = 0; nj < 4; ++nj) {
            int c = (wu * 4 + nj) * 16 + l15;
            bf16x8 Bf = ld_bf8(imgTb + (size_t)c * 224 + ks * 32 + quad * 8);
#pragma unroll
            for (int mi = 0; mi < 4; ++mi)
                acc[mi][nj] = __builtin_amdgcn_mfma_f32_16x16x32_bf16(Afr[mi], Bf, acc[mi][nj], 0, 0, 0);
        }
    }

    // ---- row sums of squares
#pragma unroll
    for (int mi = 0; mi < 4; ++mi)
#pragma unroll
        for (int r = 0; r < 4; ++r) {
            float s = acc[mi][0][r] * acc[mi][0][r] + acc[mi][1][r] * acc[mi][1][r]
                    + acc[mi][2][r] * acc[mi][2][r] + acc[mi][3][r] * acc[mi][3][r];
            s += __shfl_down(s, 8); s += __shfl_down(s, 4);
            s += __shfl_down(s, 2); s += __shfl_down(s, 1);
            if (l15 == 0) rowsq[wu][mi * 16 + quad * 4 + r] = s;
        }
    __syncthreads();
    if (t < 64) {
        float s = 0.f;
#pragma unroll
        for (int w2 = 0; w2 < 8; ++w2) s += rowsq[w2][t];
        invn[t] = 1.f / fmaxf(sqrtf(s), 1e-12f);
    }
    __syncthreads();

    // ---- write normalized Tn bf16 (Pf region dead)
#pragma unroll
    for (int mi = 0; mi < 4; ++mi)
#pragma unroll
        for (int r = 0; r < 4; ++r) {
            int row = mi * 16 + quad * 4 + r;
            if (row < 51) {
                float iv = invn[row];
#pragma unroll
                for (int nj = 0; nj < 4; ++nj)
                    TnBuf[row * 520 + (wu * 4 + nj) * 16 + l15] = f2bf(acc[mi][nj][r] * iv);
            }
        }
    __syncthreads();

    // ---- phase 2: U = Qbb @ Tn^T
    const u16* Qb = Qbb + (size_t)i * 96 * 512;
    f32x4 ua[3];
#pragma unroll
    for (int e = 0; e < 3; ++e) ua[e] = (f32x4){0.f, 0.f, 0.f, 0.f};

    if (wu < 6) {
        int mi = wu;
        const u16* Ar = Qb + (size_t)(mi * 16 + l15) * 512;
        bf16x8 Af = ld_bf8(Ar + quad * 8);
        for (int ks = 0; ks < 16; ++ks) {
            bf16x8 An;
            if (ks < 15) An = ld_bf8(Ar + (ks + 1) * 32 + quad * 8);
#pragma unroll
            for (int e = 0; e < 3; ++e) {
                bf16x8 Bf = ld_bf8(TnBuf + (e * 16 + l15) * 520 + ks * 32 + quad * 8);
                ua[e] = __builtin_amdgcn_mfma_f32_16x16x32_bf16(Af, Bf, ua[e], 0, 0, 0);
            }
            Af = An;
        }
    } else {
        int w2 = wu - 6;
        int rowB = 48 + l15; if (rowB > 50) rowB = 50;
        const u16* Ar0 = Qb + (size_t)((3 * w2 + 0) * 16 + l15) * 512;
        const u16* Ar1 = Qb + (size_t)((3 * w2 + 1) * 16 + l15) * 512;
        const u16* Ar2 = Qb + (size_t)((3 * w2 + 2) * 16 + l15) * 512;
        bf16x8 Af0 = ld_bf8(Ar0 + quad * 8);
        bf16x8 Af1 = ld_bf8(Ar1 + quad * 8);
        bf16x8 Af2 = ld_bf8(Ar2 + quad * 8);
        for (int ks = 0; ks < 16; ++ks) {
            bf16x8 An0, An1, An2;
            if (ks < 15) {
                An0 = ld_bf8(Ar0 + (ks + 1) * 32 + quad * 8);
                An1 = ld_bf8(Ar1 + (ks + 1) * 32 + quad * 8);
                An2 = ld_bf8(Ar2 + (ks + 1) * 32 + quad * 8);
            }
            bf16x8 Bf = ld_bf8(TnBuf + rowB * 520 + ks * 32 + quad * 8);
            ua[0] = __builtin_amdgcn_mfma_f32_16x16x32_bf16(Af0, Bf, ua[0], 0, 0, 0);
            ua[1] = __builtin_amdgcn_mfma_f32_16x16x32_bf16(Af1, Bf, ua[1], 0, 0, 0);
            ua[2] = __builtin_amdgcn_mfma_f32_16x16x32_bf16(Af2, Bf, ua[2], 0, 0, 0);
            Af0 = An0; Af1 = An1; Af2 = An2;
        }
    }
    __syncthreads();   // Tn reads done before U overwrites

    // ---- write U (96 x 51)
    if (wu < 6) {
#pragma unroll
        for (int e = 0; e < 3; ++e) {
            int l = e * 16 + l15;
            int q0 = wu * 16 + quad * 4;
#pragma unroll
            for (int r = 0; r < 4; ++r) ULDS[(q0 + r) * 52 + l] = ua[e][r];
        }
    } else {
        int l = 48 + l15;
        if (l < 51) {
            int w2 = wu - 6;
#pragma unroll
            for (int e = 0; e < 3; ++e) {
                int q0 = (3 * w2 + e) * 16 + quad * 4;
#pragma unroll
                for (int r = 0; r < 4; ++r) ULDS[(q0 + r) * 52 + l] = ua[e][r];
            }
        }
    }
    __syncthreads();

    // ---- softmax stats
    float invT = 1.f / temp_p[0];
    if (t < 51) {
        float mm = -1e30f;
        for (int u = 0; u < LT; ++u) mm = fmaxf(mm, ULDS[(32 + u) * 52 + t] * invT);
        float z = 0.f;
        for (int u = 0; u < LT; ++u) z += expf(ULDS[(32 + u) * 52 + t] * invT - mm);
        colM[t] = mm; colZ[t] = 1.f / z;
    }
    if (t >= 64 && t < 96) {
        int u = t - 64;
        float mm = -1e30f;
        for (int l = 0; l < 51; ++l) mm = fmaxf(mm, ULDS[(64 + u) * 52 + l] * invT);
        float z = 0.f;
        for (int l = 0; l < 51; ++l) z += expf(ULDS[(64 + u) * 52 + l] * invT - mm);
        rowM[u] = mm; rowZ[u] = 1.f / z;
    }
    __syncthreads();

    // ---- final reduction
    float part = 0.f;
    for (int f = t; f < LT * 51; f += 512) {
        int u = f / 51, l = f - u * 51;
        float u0 = ULDS[u * 52 + l];
        float c2 = (u0 > 0.f) ? u0 : 0.1f * u0;
        float av = expf(ULDS[(32 + u) * 52 + l] * invT - colM[l]) * colZ[l];
        float bv = expf(ULDS[(64 + u) * 52 + l] * invT - rowM[u]) * rowZ[u];
        part += c2 * (av * (1.f / 51.f) + bv * (1.f / 32.f));
    }
    for (int o = 32; o > 0; o >>= 1) part += __shfl_down(part, o);
    if (lane == 0) redw[wu] = part;
    __syncthreads();
    if (t == 0) {
        float s = 0.f;
#pragma unroll
        for (int w2 = 0; w2 < 8; ++w2) s += redw[w2];
        out[b * NCAP + i] = s;
    }
}

extern "C" void kernel_launch(void* const* d_in, const int* in_sizes, int n_in,
                              void* d_out, int out_size, void* d_ws, size_t ws_size,
                              hipStream_t stream) {
    const float* img        = (const float*)d_in[0];
    const float* cap        = (const float*)d_in[1];
    const float* gamw       = (const float*)d_in[3];
    const float* betw       = (const float*)d_in[4];
    const float* w1         = (const float*)d_in[5];
    const float* b1         = (const float*)d_in[6];
    const float* w2         = (const float*)d_in[7];
    const float* b2         = (const float*)d_in[8];
    const float* aggr_scale = (const float*)d_in[9];
    const float* wi2t       = (const float*)d_in[10];
    const float* bi2t       = (const float*)d_in[11];
    const float* wt2i       = (const float*)d_in[12];
    const float* bt2i       = (const float*)d_in[13];
    const float* temp       = (const float*)d_in[14];
    float* out = (float*)d_out;

    float* ws      = (float*)d_ws;
    float* attn_x  = ws + OFF_ATTNX;
    float* WsM     = ws + OFF_WSMAT;
    u16*   wT      = (u16*)(ws + OFF_WT);
    float* gloT    = ws + OFF_GLOT;
    float* attn_yT = ws + OFF_ATTNYT;
    u16*   imgT    = (u16*)(ws + OFF_IMGT);
    u16*   Qbb     = (u16*)(ws + OFF_QBB);

    k_pre<<<dim3(1152), dim3(256), 0, stream>>>(img, cap, wi2t, wt2i, imgT, gloT, Qbb, wT);
    k_mid<<<dim3(3456), dim3(512), 0, stream>>>(img, wT, bi2t, bt2i, Qbb, gamw, betw,
                                                w1, b1, w2, b2, aggr_scale, gloT,
                                                attn_x, WsM, attn_yT);
    k_main<<<dim3(NCAP, B), dim3(512), 0, stream>>>(attn_x, attn_yT, WsM, imgT, Qbb, temp, out);
}

// Round 12
// 429.911 us; speedup vs baseline: 5.4493x; 1.1182x over previous
//
#include <hip/hip_runtime.h>
#include <math.h>

#define B     64
#define NCAP  64
#define LV    197
#define LT    32
#define C     512
#define NSP   196
#define NKEEP 98
#define HID   102
#define KEEPED 49

// Workspace layout (float element offsets). Total ~79.7 MB (< proven 106.8 MB).
#define OFF_ATTNX   12608                     // B*NSP
#define OFF_WSMAT   25152                     // B*NSP*KEEPED
#define OFF_WT      639808                    // u16 2*512*512 (bf16 wi2t^T / wt2i^T)
#define OFF_GLOT    1688384                   // C*NCAP
#define OFF_ATTNYT  1721152                   // 4096*196 floats (transposed [b][i][s])
#define OFF_IMGT    14164800                  // u16 64*7*32*512 fragment-major imgT
#define OFF_QBB     17834816                  // u16 64*6*16*512 fragment-major Qbb
#define OFF_QCAP    19407680                  // u16 64*32*512 row-major cap rows (qproj input)

typedef unsigned int u32;
typedef unsigned short u16;
typedef __bf16 bf16x8 __attribute__((ext_vector_type(8)));
typedef float f32x4 __attribute__((ext_vector_type(4)));
typedef unsigned int uint4v __attribute__((ext_vector_type(4)));

__device__ __forceinline__ u16 f2bf(float f) {
    u32 u = __builtin_bit_cast(u32, f);
    return (u16)((u + 0x7FFFu + ((u >> 16) & 1u)) >> 16);
}
__device__ __forceinline__ bf16x8 ld_bf8(const u16* p) {
    uint4v v = *reinterpret_cast<const uint4v*>(p);
    return __builtin_bit_cast(bf16x8, v);
}

__device__ __forceinline__ float gelu_exact(float x) {
    return 0.5f * x * (1.f + erff(x * 0.70710678118654752f));
}

// ---------------------------------------------------------------- k_pre: imgt-frag (0..511) | cap_norm (512..1023) | wt (1024..1151)
__global__ __launch_bounds__(256) void k_pre(const float* __restrict__ img,
                                             const float* __restrict__ cap,
                                             const float* __restrict__ wi2t,
                                             const float* __restrict__ wt2i,
                                             u16* __restrict__ imgTf,
                                             float* __restrict__ gloT,
                                             u16* __restrict__ Qbbf,
                                             u16* __restrict__ Qcap,
                                             u16* __restrict__ wT) {
    int idx = blockIdx.x, t = threadIdx.x;
    __shared__ __align__(16) u16 shb[64 * 224];    // 28 KB union

    if (idx < 512) {
        // ---- imgT fragment-major: tile (ks, ct) holds 1KB: value[lane*8+j] =
        //      bf16(img[b][s = ks*32 + (lane>>4)*8 + j][c = ct*16 + (lane&15)])
        int b = idx >> 3, cg = idx & 7;            // block covers ct in [cg*4, cg*4+4)
        for (int f = t; f < 64 * 27; f += 256) shb[(f / 27) * 224 + 197 + (f % 27)] = 0;
        int cc = t & 63;
        for (int sb = t >> 6; sb < 197; sb += 4) {
            float v = img[((size_t)b * LV + sb) * C + cg * 64 + cc];
            shb[cc * 224 + sb] = f2bf(v);
        }
        __syncthreads();
        const u32* Tu = (const u32*)shb;
        u32* outp = (u32*)imgTf + (size_t)b * 7 * 32 * 256;
        // f = (ks*4 + ctl)*256 + g ; g = lane_o*4 + j2
        for (int f = t; f < 7 * 4 * 256; f += 256) {
            int ks = f >> 10, rem = f & 1023;
            int ctl = rem >> 8, g = rem & 255;
            int lane_o = g >> 2, j2 = g & 3;
            int quad_o = lane_o >> 4, l15_o = lane_o & 15;
            int ccl = ctl * 16 + l15_o;
            int s = ks * 32 + quad_o * 8 + 2 * j2;
            u32 v = Tu[ccl * 112 + (s >> 1)];
            outp[(size_t)(ks * 32 + cg * 4 + ctl) * 256 + g] = v;
        }
    } else if (idx < 1024) {
        // ---- caption norms, 4 rows/block (wave w owns row tg*4+w)
        int e = idx - 512, i = e >> 3, tg = e & 7;
        int lane = t & 63, wv = t >> 6;
        int tt = tg * 4 + wv;
        const float* row = cap + ((size_t)i * LT + tt) * C;
        float v[8]; float ss = 0.f;
#pragma unroll
        for (int q = 0; q < 8; ++q) { v[q] = row[lane + 64 * q]; ss += v[q] * v[q]; }
        for (int o = 32; o > 0; o >>= 1) ss += __shfl_down(ss, o);
        ss = __shfl(ss, 0);
        float inv = 1.f / fmaxf(sqrtf(ss), 1e-12f);
        u16* qrow = Qcap + ((size_t)i * 32 + tt) * C;
        int mi = tt >> 4, l15f = tt & 15;
        u16* qfb = Qbbf + (size_t)(i * 6 + mi) * 16 * 512;
#pragma unroll
        for (int q = 0; q < 8; ++q) {
            float n = v[q] * inv;
            u16 nb = f2bf(n);
            int c = lane + 64 * q;
            qrow[c] = nb;
            int ks = c >> 5, quadf = (c >> 3) & 3, jf = c & 7;
            qfb[(size_t)ks * 512 + (quadf * 16 + l15f) * 8 + jf] = nb;
            if (tt == 0) gloT[c * NCAP + i] = n;
        }
    } else {
        // ---- transpose wi2t/wt2i -> bf16 [j][c], one 64x64 tile per block
        int e = idx - 1024;
        int mat = e >> 6, ty = e & 63, jg = ty >> 3, cg = ty & 7;
        const float* W = mat ? wt2i : wi2t;
        u16 (*tile)[65] = (u16(*)[65])shb;
        for (int f = t; f < 4096; f += 256) {
            int cc2 = f >> 6, jj = f & 63;
            tile[jj][cc2] = f2bf(W[(size_t)(cg * 64 + cc2) * 512 + jg * 64 + jj]);
        }
        __syncthreads();
        for (int f = t; f < 4096; f += 256) {
            int jj = f >> 6, cc2 = f & 63;
            wT[((size_t)mat * 512 + jg * 64 + jj) * 512 + cg * 64 + cc2] = tile[jj][cc2];
        }
    }
}

// ---------------------------------------------------------------- k_mid: qproj (0..255) | img_row (256..1855) | attn_y (1856..3455)
__global__ __launch_bounds__(512) void k_mid(const float* __restrict__ img,
                                             const u16* __restrict__ wT,
                                             const float* __restrict__ bi2t,
                                             const float* __restrict__ bt2i,
                                             const u16* __restrict__ Qcap,
                                             u16* __restrict__ Qbbf,
                                             const float* __restrict__ gamw,
                                             const float* __restrict__ betw,
                                             const float* __restrict__ w1,
                                             const float* __restrict__ b1,
                                             const float* __restrict__ w2,
                                             const float* __restrict__ b2,
                                             const float* __restrict__ scale_p,
                                             const float* __restrict__ gloT,
                                             float* __restrict__ attn_x,
                                             float* __restrict__ WsM,
                                             float* __restrict__ attn_yT) {
    int idx = blockIdx.x, t = threadIdx.x;
    __shared__ __align__(16) float shm[4960 + 16];   // ~19.9 KB union

    if (idx < 256) {
        // ---- qi2t/qt2i via MFMA (A/B prefetch); output into fragment-major Qbbf
        int i = idx & 63, p = idx >> 6;
        int lane = t & 63, wu = t >> 6;
        int l15 = lane & 15, quad = lane >> 4;
        int mat = wu >> 2;
        int miq = (wu >> 1) & 1;
        int nh  = wu & 1;
        int ni0 = p * 8 + nh * 4;
        const u16* Arow = Qcap + ((size_t)i * 32 + miq * 16 + l15) * 512;
        const u16* Wm   = wT + (size_t)mat * 512 * 512;
        f32x4 acc[4];
#pragma unroll
        for (int n = 0; n < 4; ++n) acc[n] = (f32x4){0.f, 0.f, 0.f, 0.f};
        bf16x8 A = ld_bf8(Arow + quad * 8);
        bf16x8 Bf[4];
#pragma unroll
        for (int n = 0; n < 4; ++n)
            Bf[n] = ld_bf8(Wm + (size_t)((ni0 + n) * 16 + l15) * 512 + quad * 8);
        for (int ks = 0; ks < 16; ++ks) {
            bf16x8 An; bf16x8 Bn[4];
            if (ks < 15) {
                An = ld_bf8(Arow + (ks + 1) * 32 + quad * 8);
#pragma unroll
                for (int n = 0; n < 4; ++n)
                    Bn[n] = ld_bf8(Wm + (size_t)((ni0 + n) * 16 + l15) * 512 + (ks + 1) * 32 + quad * 8);
            }
#pragma unroll
            for (int n = 0; n < 4; ++n)
                acc[n] = __builtin_amdgcn_mfma_f32_16x16x32_bf16(A, Bf[n], acc[n], 0, 0, 0);
            A = An;
#pragma unroll
            for (int n = 0; n < 4; ++n) Bf[n] = Bn[n];
        }
        const float* bias = mat ? bt2i : bi2t;
#pragma unroll
        for (int n = 0; n < 4; ++n) {
            int j = (ni0 + n) * 16 + l15;
            float bj = bias[j];
            int ksf = j >> 5, quadf = (j >> 3) & 3, jf = j & 7;
#pragma unroll
            for (int r = 0; r < 4; ++r) {
                int q = 32 + mat * 32 + miq * 16 + quad * 4 + r;
                int mi = q >> 4, l15f = q & 15;
                Qbbf[(size_t)((i * 6 + mi) * 16 + ksf) * 512 + (quadf * 16 + l15f) * 8 + jf]
                    = f2bf(acc[n][r] + bj);
            }
        }
    } else if (idx < 1856) {
        // ---- LN -> w1 -> gelu -> w2 + attn_x, 8 rows/block
        int e = idx - 256;
        int b = e / 25, sg = e - b * 25;
        int s0 = sg * 8;
        int R = NSP - s0; if (R > 8) R = 8;
        float (*lnr)[C]   = (float(*)[C])shm;            // 8x512
        float (*HH)[104]  = (float(*)[104])(shm + 4096); // 8x104
        float (*redm)[4]  = (float(*)[4])(shm + 4928);   // 8x4

        int g = t >> 6, lane = t & 63;
        if (g < R) {
            const float* row = img + ((size_t)b * LV + 1 + s0 + g) * C;
            const float* cls = img + (size_t)b * LV * C;
            float sm = 0.f, ss = 0.f, dd = 0.f, sc = 0.f;
            for (int c = lane; c < C; c += 64) {
                float v = row[c];
                float cv = cls[c];
                sm += v; ss += v * v; dd += v * cv; sc += cv * cv;
                lnr[g][c] = v;
            }
            for (int o = 32; o > 0; o >>= 1) {
                sm += __shfl_down(sm, o);
                ss += __shfl_down(ss, o);
                dd += __shfl_down(dd, o);
                sc += __shfl_down(sc, o);
            }
            if (lane == 0) { redm[g][0] = sm; redm[g][1] = ss; redm[g][2] = dd; redm[g][3] = sc; }
        }
        __syncthreads();
        for (int f = t; f < R * C; f += 512) {
            int rr = f >> 9, c = f & 511;
            float mean = redm[rr][0] * (1.f / C);
            float var  = redm[rr][1] * (1.f / C) - mean * mean;
            float rstd = 1.f / sqrtf(var + 1e-5f);
            lnr[rr][c] = (lnr[rr][c] - mean) * rstd * gamw[c] + betw[c];
        }
        if (t < R) {
            float inv0 = 1.f / fmaxf(sqrtf(redm[t][3]), 1e-12f);
            float invs = 1.f / fmaxf(sqrtf(redm[t][1]), 1e-12f);
            attn_x[b * NSP + s0 + t] = redm[t][2] * inv0 * invs;
        }
        __syncthreads();
        if (t < 408) {
            int rr2 = t / 102;
            int j = t - rr2 * 102;
            int rw0 = rr2 * 2, rw1 = rr2 * 2 + 1;
            float a0 = b1[j], a1 = b1[j];
            for (int c = 0; c < C; ++c) {
                float wv = w1[c * HID + j];
                a0 += lnr[rw0][c] * wv;
                a1 += lnr[rw1][c] * wv;
            }
            if (rw0 < R) HH[rw0][j] = gelu_exact(a0);
            if (rw1 < R) HH[rw1][j] = gelu_exact(a1);
        }
        __syncthreads();
        float scale = scale_p[0];
        if (t < 392) {
            int k = t % 49, rh = t / 49;
            if (rh < R) {
                float a = b2[k];
                for (int h = 0; h < HID; ++h) a += HH[rh][h] * w2[h * 49 + k];
                WsM[((size_t)b * NSP + s0 + rh) * 49 + k] = a * scale;
            }
        }
    } else {
        // ---- attn_y transposed, 8 rows/block, wave w owns row w
        int e = idx - 1856;
        int b = e / 25;
        int s0 = (e - b * 25) * 8;
        int R = NSP - s0; if (R > 8) R = 8;
        float (*xr)[C] = (float(*)[C])shm;
        float* rnorm = shm + 4096;

        for (int f = t; f < R * C; f += 512) {
            int rr = f >> 9, c = f & 511;
            xr[rr][c] = img[((size_t)b * LV + 1 + s0 + rr) * C + c];
        }
        __syncthreads();
        {
            int row = t >> 6, l = t & 63;
            if (row < R) {
                float ss = 0.f;
                for (int c = l; c < C; c += 64) { float v = xr[row][c]; ss += v * v; }
                for (int o = 32; o > 0; o >>= 1) ss += __shfl_down(ss, o);
                if (l == 0) rnorm[row] = 1.f / fmaxf(sqrtf(ss), 1e-12f);
            }
        }
        __syncthreads();
        for (int f = t; f < R * C; f += 512) {
            int rr = f >> 9, c = f & 511;
            xr[rr][c] *= rnorm[rr];
        }
        __syncthreads();
        int i = t & 63, w = t >> 6;
        if (w < R) {
            float a0 = 0.f;
            for (int c4 = 0; c4 < C / 4; ++c4) {
                float g0 = gloT[(c4 * 4 + 0) * NCAP + i];
                float g1 = gloT[(c4 * 4 + 1) * NCAP + i];
                float g2 = gloT[(c4 * 4 + 2) * NCAP + i];
                float g3 = gloT[(c4 * 4 + 3) * NCAP + i];
                float4 x0 = ((const float4*)xr[w])[c4];
                a0 += x0.x * g0 + x0.y * g1 + x0.z * g2 + x0.w * g3;
            }
            attn_yT[((size_t)b * NCAP + i) * NSP + s0 + w] = a0;
        }
    }
}

// ---------------------------------------------------------------- main per-pair kernel: rank + two MFMA GEMMs
// Fragment-major operands: every global MFMA load is one contiguous 1KB per wave.
__global__ __launch_bounds__(512, 4) void k_main(const float* __restrict__ attn_x,
                                                 const float* __restrict__ attn_yT,
                                                 const float* __restrict__ WsM,
                                                 const u16* __restrict__ imgTf,
                                                 const u16* __restrict__ Qbbf,
                                                 const float* __restrict__ temp_p,
                                                 float* __restrict__ out) {
    int lin = blockIdx.x + NCAP * blockIdx.y;     // XCD swizzle: lin%8 selects b-octet
    int b = (lin & 7) * 8 + ((lin >> 3) & 7);
    int i = lin >> 6;
    int t = threadIdx.x;
    int lane = t & 63, wu = t >> 6;
    int l15 = lane & 15, quad = lane >> 4;

    __shared__ __align__(16) u16 TnBuf[51 * 520];   // aliases Pf(64x232) then ULDS(96x52 f32)
    __shared__ float rowsq[8][64];
    __shared__ float invn[64];
    __shared__ float colM[51], colZ[51], rowM[32], rowZ[32], redw[8];
    __shared__ float scoreS[NSP];
    __shared__ int   keepL[NKEEP];
    __shared__ int   nonL[NKEEP];
    __shared__ float snon[NKEEP];
    __shared__ short rnkH[2][NSP];

    u16*   Pf   = TnBuf;
    float* ULDS = (float*)TnBuf;

    // ---- 1. zero Pf rows 0..50 + load scores
    {
        u32* Pfu = (u32*)Pf;
        for (int f = t; f < 51 * 116; f += 512) Pfu[f] = 0;
    }
    if (t < NSP)
        scoreS[t] = attn_x[b * NSP + t] + attn_yT[((size_t)b * NCAP + i) * NSP + t];
    __syncthreads();
    // ---- 2. stable-descending rank, split over 392 threads
    if (t < 2 * NSP) {
        int half = (t >= NSP) ? 1 : 0;
        int s = t - half * NSP;
        float sv = scoreS[s];
        int u0 = half * 98, u1 = half ? NSP : 98;
        int r = 0;
        for (int u = u0; u < u1; ++u) {
            float o = scoreS[u];
            r += (o > sv) || (o == sv && u < s);
        }
        rnkH[half][s] = (short)r;
    }
    __syncthreads();
    if (t < NSP) {
        int r = rnkH[0][t] + rnkH[1][t];
        if (r < NKEEP) keepL[r] = t;
        else { nonL[r - NKEEP] = t; snon[r - NKEEP] = scoreS[t]; }
    }
    __syncthreads();
    // ---- 3. scatter P into Pf
    if (t == 0) Pf[0] = 0x3F80;                       // cls one-hot (1.0)
    for (int f = t; f < NKEEP * KEEPED; f += 512) {
        int j = f / KEEPED, k = f - j * KEEPED;
        int s = keepL[j];
        Pf[(1 + k) * 232 + 1 + s] = f2bf(expf(WsM[((size_t)b * NSP + s) * KEEPED + k]));
    }
    if (t < NKEEP) Pf[50 * 232 + 1 + nonL[t]] = f2bf(expf(snon[t]));
    __syncthreads();

    // ---- phase 1: T(51x512) = Pfull @ imgT ; wave w owns ct range [4w, 4w+4)
    const u16* imgTb = imgTf + (size_t)b * 7 * 32 * 512;
    f32x4 acc[4][4];
#pragma unroll
    for (int mi = 0; mi < 4; ++mi)
#pragma unroll
        for (int nj = 0; nj < 4; ++nj) acc[mi][nj] = (f32x4){0.f, 0.f, 0.f, 0.f};

    for (int ks = 0; ks < 7; ++ks) {
        bf16x8 Afr[4];
#pragma unroll
        for (int mi = 0; mi < 4; ++mi)
            Afr[mi] = ld_bf8(Pf + (mi * 16 + l15) * 232 + ks * 32 + quad * 8);
#pragma unroll
        for (int nj = 0; nj < 4; ++nj) {
            bf16x8 Bf = ld_bf8(imgTb + (size_t)(ks * 32 + wu * 4 + nj) * 512 + lane * 8);
#pragma unroll
            for (int mi = 0; mi < 4; ++mi)
                acc[mi][nj] = __builtin_amdgcn_mfma_f32_16x16x32_bf16(Afr[mi], Bf, acc[mi][nj], 0, 0, 0);
        }
    }

    // ---- row sums of squares
#pragma unroll
    for (int mi = 0; mi < 4; ++mi)
#pragma unroll
        for (int r = 0; r < 4; ++r) {
            float s = acc[mi][0][r] * acc[mi][0][r] + acc[mi][1][r] * acc[mi][1][r]
                    + acc[mi][2][r] * acc[mi][2][r] + acc[mi][3][r] * acc[mi][3][r];
            s += __shfl_down(s, 8); s += __shfl_down(s, 4);
            s += __shfl_down(s, 2); s += __shfl_down(s, 1);
            if (l15 == 0) rowsq[wu][mi * 16 + quad * 4 + r] = s;
        }
    __syncthreads();
    if (t < 64) {
        float s = 0.f;
#pragma unroll
        for (int w2 = 0; w2 < 8; ++w2) s += rowsq[w2][t];
        invn[t] = 1.f / fmaxf(sqrtf(s), 1e-12f);
    }
    __syncthreads();

    // ---- write normalized Tn bf16 (Pf region dead)
#pragma unroll
    for (int mi = 0; mi < 4; ++mi)
#pragma unroll
        for (int r = 0; r < 4; ++r) {
            int row = mi * 16 + quad * 4 + r;
            if (row < 51) {
                float iv = invn[row];
#pragma unroll
                for (int nj = 0; nj < 4; ++nj)
                    TnBuf[row * 520 + (wu * 4 + nj) * 16 + l15] = f2bf(acc[mi][nj][r] * iv);
            }
        }
    __syncthreads();

    // ---- phase 2: U = Qbb @ Tn^T (A fragments contiguous 1KB)
    const u16* Qbf = Qbbf + (size_t)i * 6 * 16 * 512;
    f32x4 ua[3];
#pragma unroll
    for (int e = 0; e < 3; ++e) ua[e] = (f32x4){0.f, 0.f, 0.f, 0.f};

    if (wu < 6) {
        int mi = wu;
        const u16* Ar = Qbf + (size_t)mi * 16 * 512 + lane * 8;
        bf16x8 Af = ld_bf8(Ar);
        for (int ks = 0; ks < 16; ++ks) {
            bf16x8 An;
            if (ks < 15) An = ld_bf8(Ar + (ks + 1) * 512);
#pragma unroll
            for (int e = 0; e < 3; ++e) {
                bf16x8 Bf = ld_bf8(TnBuf + (e * 16 + l15) * 520 + ks * 32 + quad * 8);
                ua[e] = __builtin_amdgcn_mfma_f32_16x16x32_bf16(Af, Bf, ua[e], 0, 0, 0);
            }
            Af = An;
        }
    } else {
        int w2 = wu - 6;
        int rowB = 48 + l15; if (rowB > 50) rowB = 50;
        const u16* Ar0 = Qbf + (size_t)(3 * w2 + 0) * 16 * 512 + lane * 8;
        const u16* Ar1 = Qbf + (size_t)(3 * w2 + 1) * 16 * 512 + lane * 8;
        const u16* Ar2 = Qbf + (size_t)(3 * w2 + 2) * 16 * 512 + lane * 8;
        bf16x8 Af0 = ld_bf8(Ar0);
        bf16x8 Af1 = ld_bf8(Ar1);
        bf16x8 Af2 = ld_bf8(Ar2);
        for (int ks = 0; ks < 16; ++ks) {
            bf16x8 An0, An1, An2;
            if (ks < 15) {
                An0 = ld_bf8(Ar0 + (ks + 1) * 512);
                An1 = ld_bf8(Ar1 + (ks + 1) * 512);
                An2 = ld_bf8(Ar2 + (ks + 1) * 512);
            }
            bf16x8 Bf = ld_bf8(TnBuf + rowB * 520 + ks * 32 + quad * 8);
            ua[0] = __builtin_amdgcn_mfma_f32_16x16x32_bf16(Af0, Bf, ua[0], 0, 0, 0);
            ua[1] = __builtin_amdgcn_mfma_f32_16x16x32_bf16(Af1, Bf, ua[1], 0, 0, 0);
            ua[2] = __builtin_amdgcn_mfma_f32_16x16x32_bf16(Af2, Bf, ua[2], 0, 0, 0);
            Af0 = An0; Af1 = An1; Af2 = An2;
        }
    }
    __syncthreads();   // Tn reads done before U overwrites

    // ---- write U (96 x 51)
    if (wu < 6) {
#pragma unroll
        for (int e = 0; e < 3; ++e) {
            int l = e * 16 + l15;
            int q0 = wu * 16 + quad * 4;
#pragma unroll
            for (int r = 0; r < 4; ++r) ULDS[(q0 + r) * 52 + l] = ua[e][r];
        }
    } else {
        int l = 48 + l15;
        if (l < 51) {
            int w2 = wu - 6;
#pragma unroll
            for (int e = 0; e < 3; ++e) {
                int q0 = (3 * w2 + e) * 16 + quad * 4;
#pragma unroll
                for (int r = 0; r < 4; ++r) ULDS[(q0 + r) * 52 + l] = ua[e][r];
            }
        }
    }
    __syncthreads();

    // ---- softmax stats
    float invT = 1.f / temp_p[0];
    if (t < 51) {
        float mm = -1e30f;
        for (int u = 0; u < LT; ++u) mm = fmaxf(mm, ULDS[(32 + u) * 52 + t] * invT);
        float z = 0.f;
        for (int u = 0; u < LT; ++u) z += expf(ULDS[(32 + u) * 52 + t] * invT - mm);
        colM[t] = mm; colZ[t] = 1.f / z;
    }
    if (t >= 64 && t < 96) {
        int u = t - 64;
        float mm = -1e30f;
        for (int l = 0; l < 51; ++l) mm = fmaxf(mm, ULDS[(64 + u) * 52 + l] * invT);
        float z = 0.f;
        for (int l = 0; l < 51; ++l) z += expf(ULDS[(64 + u) * 52 + l] * invT - mm);
        rowM[u] = mm; rowZ[u] = 1.f / z;
    }
    __syncthreads();

    // ---- final reduction
    float part = 0.f;
    for (int f = t; f < LT * 51; f += 512) {
        int u = f / 51, l = f - u * 51;
        float u0 = ULDS[u * 52 + l];
        float c2 = (u0 > 0.f) ? u0 : 0.1f * u0;
        float av = expf(ULDS[(32 + u) * 52 + l] * invT - colM[l]) * colZ[l];
        float bv = expf(ULDS[(64 + u) * 52 + l] * invT - rowM[u]) * rowZ[u];
        part += c2 * (av * (1.f / 51.f) + bv * (1.f / 32.f));
    }
    for (int o = 32; o > 0; o >>= 1) part += __shfl_down(part, o);
    if (lane == 0) redw[wu] = part;
    __syncthreads();
    if (t == 0) {
        float s = 0.f;
#pragma unroll
        for (int w2 = 0; w2 < 8; ++w2) s += redw[w2];
        out[b * NCAP + i] = s;
    }
}

extern "C" void kernel_launch(void* const* d_in, const int* in_sizes, int n_in,
                              void* d_out, int out_size, void* d_ws, size_t ws_size,
                              hipStream_t stream) {
    const float* img        = (const float*)d_in[0];
    const float* cap        = (const float*)d_in[1];
    const float* gamw       = (const float*)d_in[3];
    const float* betw       = (const float*)d_in[4];
    const float* w1         = (const float*)d_in[5];
    const float* b1         = (const float*)d_in[6];
    const float* w2         = (const float*)d_in[7];
    const float* b2         = (const float*)d_in[8];
    const float* aggr_scale = (const float*)d_in[9];
    const float* wi2t       = (const float*)d_in[10];
    const float* bi2t       = (const float*)d_in[11];
    const float* wt2i       = (const float*)d_in[12];
    const float* bt2i       = (const float*)d_in[13];
    const float* temp       = (const float*)d_in[14];
    float* out = (float*)d_out;

    float* ws      = (float*)d_ws;
    float* attn_x  = ws + OFF_ATTNX;
    float* WsM     = ws + OFF_WSMAT;
    u16*   wT      = (u16*)(ws + OFF_WT);
    float* gloT    = ws + OFF_GLOT;
    float* attn_yT = ws + OFF_ATTNYT;
    u16*   imgTf   = (u16*)(ws + OFF_IMGT);
    u16*   Qbbf    = (u16*)(ws + OFF_QBB);
    u16*   Qcap    = (u16*)(ws + OFF_QCAP);

    k_pre<<<dim3(1152), dim3(256), 0, stream>>>(img, cap, wi2t, wt2i, imgTf, gloT, Qbbf, Qcap, wT);
    k_mid<<<dim3(3456), dim3(512), 0, stream>>>(img, wT, bi2t, bt2i, Qcap, Qbbf, gamw, betw,
                                                w1, b1, w2, b2, aggr_scale, gloT,
                                                attn_x, WsM, attn_yT);
    k_main<<<dim3(NCAP, B), dim3(512), 0, stream>>>(attn_x, attn_yT, WsM, imgTf, Qbbf, temp, out);
}